// Round 15
// baseline (2197.059 us; speedup 1.0000x reference)
//
#include <hip/hip_runtime.h>
#include <hip/hip_bf16.h>

// DecoderIGCN forward. Round 15: round 14's conv2-fused channel-LN with the
// edge-kernel LDS overflow fixed (SMEM sized for the 128x114 lnbuf reuse).
// N=512, D=768, RDIM=100, R=8, L=2.

static constexpr long NNpix = 512L * 512L; // 262144

typedef __attribute__((ext_vector_type(8))) short short8v;
typedef __attribute__((ext_vector_type(4))) float f32x4;

__device__ inline float bf2f(short s) {
    unsigned u = ((unsigned)(unsigned short)s) << 16;
    float f; __builtin_memcpy(&f, &u, 4);
    return f;
}
__device__ inline short f2bf(float f) {
    unsigned u; __builtin_memcpy(&u, &f, 4);
    u += 0x7fff + ((u >> 16) & 1);   // RNE
    return (short)(u >> 16);
}
__device__ inline void gload_lds16(const short* g, short* l) {
    __builtin_amdgcn_global_load_lds(
        (const __attribute__((address_space(1))) unsigned int*)g,
        (__attribute__((address_space(3))) unsigned int*)l, 16, 0, 0);
}

// Bijective XCD swizzle of the flattened block index (requires total%8==0;
// identity otherwise). Consecutive swizzled ids share an XCD's L2.
__device__ inline void xcd_block3(int& bx, int& by, int& bz) {
    const long gx = gridDim.x, gy = gridDim.y;
    const long total = gx * gy * (long)gridDim.z;
    long lin = blockIdx.x + gx * (blockIdx.y + gy * (long)blockIdx.z);
    if ((total & 7) == 0)
        lin = (lin & 7) * (total >> 3) + (lin >> 3);
    const long gxy = gx * gy;
    bz = (int)(lin / gxy);
    const int rem = (int)(lin - (long)bz * gxy);
    by = rem / (int)gx;
    bx = rem - by * (int)gx;
}

// ---------------------------------------------------------------------------
// bf16 MFMA GEMM: D[M][N] = (relu?)(X[M][K] . Y[N][K]^T), all bf16 (shorts).
// 128x128 tile, BK=32, 256 threads (4 waves, 2x2), 16x16x32 MFMA.
// ---------------------------------------------------------------------------
template <bool RELU>
__global__ __launch_bounds__(256) void bgemm_xyt(
    const short* __restrict__ X, long sX,
    const short* __restrict__ Y, long sY,
    short* __restrict__ D, long sD,
    int M, int N, int K)
{
    int bx, by, bz;
    xcd_block3(bx, by, bz);
    X += (long)bz * sX;
    Y += (long)bz * sY;
    D += (long)bz * sD;

    __shared__ short Xs[128 * 32];
    __shared__ short Ys[128 * 32];

    const int tid = threadIdx.x, wv = tid >> 6, ln = tid & 63;
    const int wr = wv >> 1, wc = wv & 1;
    const int m0 = by * 128, n0 = bx * 128;

    f32x4 acc[4][4] = {};

    const int srow = ln >> 2;
    const int sk8 = ln & 3;
    const int fr = ln & 15, fk = (ln >> 4) * 8;

    for (int k0 = 0; k0 < K; k0 += 32) {
#pragma unroll
        for (int i = wv; i < 8; i += 4) {
            gload_lds16(X + (long)(m0 + i * 16 + srow) * K + k0 + sk8 * 8,
                        Xs + i * 512);
            gload_lds16(Y + (long)(n0 + i * 16 + srow) * K + k0 + sk8 * 8,
                        Ys + i * 512);
        }
        __syncthreads();
        short8v a[4], b[4];
#pragma unroll
        for (int mi = 0; mi < 4; ++mi)
            a[mi] = *(const short8v*)(Xs + (wr * 64 + mi * 16 + fr) * 32 + fk);
#pragma unroll
        for (int ni = 0; ni < 4; ++ni)
            b[ni] = *(const short8v*)(Ys + (wc * 64 + ni * 16 + fr) * 32 + fk);
#pragma unroll
        for (int mi = 0; mi < 4; ++mi)
#pragma unroll
            for (int ni = 0; ni < 4; ++ni)
                acc[mi][ni] = __builtin_amdgcn_mfma_f32_16x16x32_bf16(
                    a[mi], b[ni], acc[mi][ni], 0, 0, 0);
        __syncthreads();
    }

    const int fv = (ln >> 4) * 4;
#pragma unroll
    for (int mi = 0; mi < 4; ++mi)
#pragma unroll
        for (int ni = 0; ni < 4; ++ni)
#pragma unroll
            for (int v = 0; v < 4; ++v) {
                const int row = m0 + wr * 64 + mi * 16 + fv + v;
                const int col = n0 + wc * 64 + ni * 16 + fr;
                float x = acc[mi][ni][v];
                if (RELU) x = fmaxf(x, 0.f);
                D[(long)row * N + col] = f2bf(x);
            }
}

// Same GEMM, fp32 output + per-column bias (for emlp).
__global__ __launch_bounds__(256) void bgemm_bias_f32(
    const short* __restrict__ X,
    const short* __restrict__ Y,
    float* __restrict__ D,
    const float* __restrict__ bias,
    int M, int N, int K)
{
    int bx, by, bz;
    xcd_block3(bx, by, bz);
    (void)bz;

    __shared__ short Xs[128 * 32];
    __shared__ short Ys[128 * 32];

    const int tid = threadIdx.x, wv = tid >> 6, ln = tid & 63;
    const int wr = wv >> 1, wc = wv & 1;
    const int m0 = by * 128, n0 = bx * 128;

    f32x4 acc[4][4] = {};

    const int srow = ln >> 2;
    const int sk8 = ln & 3;
    const int fr = ln & 15, fk = (ln >> 4) * 8;

    for (int k0 = 0; k0 < K; k0 += 32) {
#pragma unroll
        for (int i = wv; i < 8; i += 4) {
            gload_lds16(X + (long)(m0 + i * 16 + srow) * K + k0 + sk8 * 8,
                        Xs + i * 512);
            gload_lds16(Y + (long)(n0 + i * 16 + srow) * K + k0 + sk8 * 8,
                        Ys + i * 512);
        }
        __syncthreads();
        short8v a[4], b[4];
#pragma unroll
        for (int mi = 0; mi < 4; ++mi)
            a[mi] = *(const short8v*)(Xs + (wr * 64 + mi * 16 + fr) * 32 + fk);
#pragma unroll
        for (int ni = 0; ni < 4; ++ni)
            b[ni] = *(const short8v*)(Ys + (wc * 64 + ni * 16 + fr) * 32 + fk);
#pragma unroll
        for (int mi = 0; mi < 4; ++mi)
#pragma unroll
            for (int ni = 0; ni < 4; ++ni)
                acc[mi][ni] = __builtin_amdgcn_mfma_f32_16x16x32_bf16(
                    a[mi], b[ni], acc[mi][ni], 0, 0, 0);
        __syncthreads();
    }

    const int fv = (ln >> 4) * 4;
#pragma unroll
    for (int mi = 0; mi < 4; ++mi)
#pragma unroll
        for (int ni = 0; ni < 4; ++ni)
#pragma unroll
            for (int v = 0; v < 4; ++v) {
                const int row = m0 + wr * 64 + mi * 16 + fv + v;
                const int col = n0 + wc * 64 + ni * 16 + fr;
                D[(long)row * N + col] = acc[mi][ni][v] + bias[col];
            }
}

// ---------------------------------------------------------------------------
// conv3x3 main pass (ky-slab, 4 waves, XCD m-swizzle). FUSE_LN=true (conv2,
// gridDim.y==1 so one n-tile = all channels): stage bf16 conv+bias outputs
// into reused staging LDS, then 128 threads LN pixel rows against `res` and
// write the final rel tensor to `out` (cols >=100 zeroed).
// ---------------------------------------------------------------------------
template <int CINP, int CINW, int COUT, int OUTP, bool RELU, bool FUSE_LN>
__global__ __launch_bounds__(256) void conv_gemm(
    const short* __restrict__ img,
    const short* __restrict__ wflat,
    const float* __restrict__ bias,
    short* __restrict__ out,
    const short* __restrict__ res,
    const float* __restrict__ lng,
    const float* __restrict__ lnbv)
{
    constexpr int NCH = CINW / 32;
    constexpr int KW = 9 * CINW;

    __shared__ short SMEM[144 * 32 + 3 * 128 * 32];  // 16896 >= 128*114 lnbuf
    short* Xs = SMEM;
    short* Ys = SMEM + 144 * 32;

    const int tid = threadIdx.x, wv = tid >> 6, ln = tid & 63;
    const int wr = wv >> 1, wc = wv & 1;
    const int bx = blockIdx.x;
    const int bsw = (bx & 7) * ((int)gridDim.x >> 3) + (bx >> 3);
    const int m0 = bsw * 128;
    const int n0 = blockIdx.y * 128;

    f32x4 acc[4][4] = {};

    const int srow = ln >> 2;
    const int sk8 = ln & 3;
    const int fr = ln & 15, fk = (ln >> 4) * 8;

    for (int ky = 0; ky < 3; ++ky) {
        const int slab0 = m0 + (ky - 1) * 512 - 1;
        for (int cc = 0; cc < NCH; ++cc) {
            const int ci0 = cc * 32;
#pragma unroll
            for (int i = wv; i < 9; i += 4) {
                int rpx = slab0 + i * 16 + srow;
                rpx = rpx < 0 ? 0 : (rpx > (int)NNpix - 1 ? (int)NNpix - 1 : rpx);
                gload_lds16(img + (long)rpx * CINP + ci0 + sk8 * 8,
                            Xs + i * 512);
            }
#pragma unroll
            for (int kx = 0; kx < 3; ++kx) {
                const int wbase = (ky * 3 + kx) * CINW;
#pragma unroll
                for (int i = wv; i < 8; i += 4)
                    gload_lds16(wflat + (long)(n0 + i * 16 + srow) * KW + wbase + ci0 + sk8 * 8,
                                Ys + kx * 4096 + i * 512);
            }
            __syncthreads();
#pragma unroll
            for (int kx = 0; kx < 3; ++kx) {
                short8v a[4], b[4];
#pragma unroll
                for (int mi = 0; mi < 4; ++mi)
                    a[mi] = *(const short8v*)(Xs + (wr * 64 + mi * 16 + fr + kx) * 32 + fk);
#pragma unroll
                for (int ni = 0; ni < 4; ++ni)
                    b[ni] = *(const short8v*)(Ys + kx * 4096 + (wc * 64 + ni * 16 + fr) * 32 + fk);
#pragma unroll
                for (int mi = 0; mi < 4; ++mi)
#pragma unroll
                    for (int ni = 0; ni < 4; ++ni)
                        acc[mi][ni] = __builtin_amdgcn_mfma_f32_16x16x32_bf16(
                            a[mi], b[ni], acc[mi][ni], 0, 0, 0);
            }
            __syncthreads();
        }
    }

    const int fv = (ln >> 4) * 4;
    if (!FUSE_LN) {
#pragma unroll
        for (int mi = 0; mi < 4; ++mi)
#pragma unroll
            for (int ni = 0; ni < 4; ++ni)
#pragma unroll
                for (int v = 0; v < 4; ++v) {
                    const int px = m0 + wr * 64 + mi * 16 + fv + v;
                    const int co = n0 + wc * 64 + ni * 16 + fr;
                    if (co < COUT) {
                        float x = acc[mi][ni][v] + bias[co];
                        if (RELU) x = fmaxf(x, 0.f);
                        out[(long)px * OUTP + co] = f2bf(x);
                    } else if (co < OUTP) {
                        out[(long)px * OUTP + co] = 0;
                    }
                }
    } else {
        // stage conv+bias (bf16, matching the old O2P roundtrip numerics)
        short* lnbuf = SMEM;  // 128*114 = 14592 <= 16896
        __syncthreads();
#pragma unroll
        for (int mi = 0; mi < 4; ++mi)
#pragma unroll
            for (int ni = 0; ni < 4; ++ni)
#pragma unroll
                for (int v = 0; v < 4; ++v) {
                    const int pl = wr * 64 + mi * 16 + fv + v;
                    const int co = wc * 64 + ni * 16 + fr;
                    if (co < 112)
                        lnbuf[pl * 114 + co] =
                            (co < COUT) ? f2bf(acc[mi][ni][v] + bias[co]) : (short)0;
                }
        __syncthreads();
        if (tid < 128) {
            const long gpx = (long)m0 + tid;
            const short* rr = res + gpx * 112;
            const short* lr = lnbuf + tid * 114;
            float s = 0.f, ss = 0.f;
            for (int c = 0; c < 100; ++c) {
                const float t = bf2f(lr[c]) + bf2f(rr[c]);
                s += t; ss += t * t;
            }
            const float mean = s * 0.01f;
            const float var = ss * 0.01f - mean * mean;
            const float inv = rsqrtf(var + 1e-5f);
            short* orow = out + gpx * 112;
            for (int c = 0; c < 112; ++c) {
                short o = 0;
                if (c < 100) {
                    const float t = bf2f(lr[c]) + bf2f(rr[c]);
                    o = f2bf((t - mean) * inv * lng[c] + lnbv[c]);
                }
                orow[c] = o;
            }
        }
    }
}

// Edge path: gather 2044 border patches -> GEMM -> scatter (FUSE_LN for conv2).
template <int CINP, int CINW>
__global__ __launch_bounds__(256) void edge_gather(
    const short* __restrict__ img, short* __restrict__ EP)
{
    constexpr int KW = 9 * CINW;
    const int e = blockIdx.x;
    int y, x;
    bool real = true;
    if (e < 512)       { y = 0;   x = e; }
    else if (e < 1024) { y = 511; x = e - 512; }
    else if (e < 1534) { x = 0;   y = 1 + (e - 1024); }
    else if (e < 2044) { x = 511; y = 1 + (e - 1534); }
    else               { y = 0; x = 0; real = false; }

    const int tid = threadIdx.x;
    for (int idx = tid; idx < KW / 8; idx += 256) {
        const int tap = idx / (CINW / 8);
        const int c = (idx - tap * (CINW / 8)) * 8;
        short8v v = {0, 0, 0, 0, 0, 0, 0, 0};
        if (real && c < CINP) {
            const int yy = y + tap / 3 - 1, xx = x + tap % 3 - 1;
            if ((unsigned)yy < 512u && (unsigned)xx < 512u)
                v = *(const short8v*)(img + ((long)yy * 512 + xx) * CINP + c);
        }
        *(short8v*)(EP + (long)e * KW + idx * 8) = v;
    }
}

__device__ inline void edge_yx(int e, int& y, int& x) {
    if (e < 512)       { y = 0;   x = e; }
    else if (e < 1024) { y = 511; x = e - 512; }
    else if (e < 1534) { x = 0;   y = 1 + (e - 1024); }
    else               { x = 511; y = 1 + (e - 1534); }
}

template <int COUT, int OUTP, bool RELU, bool FUSE_LN>
__global__ __launch_bounds__(256) void conv_edge_gemm(
    const short* __restrict__ EP,
    const short* __restrict__ wflat,
    const float* __restrict__ bias,
    short* __restrict__ out, int K,
    const short* __restrict__ res,
    const float* __restrict__ lng,
    const float* __restrict__ lnbv)
{
    // FIX (round 15): SMEM must hold the 128x114 lnbuf reuse (14592 shorts),
    // not just the 2x128x32 staging tiles (8192) — round 14 overflowed LDS.
    __shared__ short SMEM[128 * 114];
    short* Xs = SMEM;
    short* Ys = SMEM + 128 * 32;

    const int tid = threadIdx.x, wv = tid >> 6, ln = tid & 63;
    const int wr = wv >> 1, wc = wv & 1;
    const int m0 = blockIdx.x * 128, n0 = blockIdx.y * 128;

    f32x4 acc[4][4] = {};

    const int srow = ln >> 2;
    const int sk8 = ln & 3;
    const int fr = ln & 15, fk = (ln >> 4) * 8;

    for (int k0 = 0; k0 < K; k0 += 32) {
#pragma unroll
        for (int i = wv; i < 8; i += 4) {
            gload_lds16(EP + (long)(m0 + i * 16 + srow) * K + k0 + sk8 * 8,
                        Xs + i * 512);
            gload_lds16(wflat + (long)(n0 + i * 16 + srow) * K + k0 + sk8 * 8,
                        Ys + i * 512);
        }
        __syncthreads();
        short8v a[4], b[4];
#pragma unroll
        for (int mi = 0; mi < 4; ++mi)
            a[mi] = *(const short8v*)(Xs + (wr * 64 + mi * 16 + fr) * 32 + fk);
#pragma unroll
        for (int ni = 0; ni < 4; ++ni)
            b[ni] = *(const short8v*)(Ys + (wc * 64 + ni * 16 + fr) * 32 + fk);
#pragma unroll
        for (int mi = 0; mi < 4; ++mi)
#pragma unroll
            for (int ni = 0; ni < 4; ++ni)
                acc[mi][ni] = __builtin_amdgcn_mfma_f32_16x16x32_bf16(
                    a[mi], b[ni], acc[mi][ni], 0, 0, 0);
        __syncthreads();
    }

    const int fv = (ln >> 4) * 4;
    if (!FUSE_LN) {
#pragma unroll
        for (int mi = 0; mi < 4; ++mi)
#pragma unroll
            for (int ni = 0; ni < 4; ++ni)
#pragma unroll
                for (int v = 0; v < 4; ++v) {
                    const int e = m0 + wr * 64 + mi * 16 + fv + v;
                    const int co = n0 + wc * 64 + ni * 16 + fr;
                    if (e >= 2044 || co >= COUT) continue;
                    int y, x;
                    edge_yx(e, y, x);
                    float v2 = acc[mi][ni][v] + bias[co];
                    if (RELU) v2 = fmaxf(v2, 0.f);
                    out[((long)y * 512 + x) * OUTP + co] = f2bf(v2);
                }
    } else {
        short* lnbuf = SMEM;
        __syncthreads();
#pragma unroll
        for (int mi = 0; mi < 4; ++mi)
#pragma unroll
            for (int ni = 0; ni < 4; ++ni)
#pragma unroll
                for (int v = 0; v < 4; ++v) {
                    const int pl = wr * 64 + mi * 16 + fv + v;
                    const int co = wc * 64 + ni * 16 + fr;
                    if (co < 112)
                        lnbuf[pl * 114 + co] =
                            (co < COUT) ? f2bf(acc[mi][ni][v] + bias[co]) : (short)0;
                }
        __syncthreads();
        if (tid < 128) {
            const int e = m0 + tid;
            if (e < 2044) {
                int y, x;
                edge_yx(e, y, x);
                const long gpx = (long)y * 512 + x;
                const short* rr = res + gpx * 112;
                const short* lr = lnbuf + tid * 114;
                float s = 0.f, ss = 0.f;
                for (int c = 0; c < 100; ++c) {
                    const float t = bf2f(lr[c]) + bf2f(rr[c]);
                    s += t; ss += t * t;
                }
                const float mean = s * 0.01f;
                const float var = ss * 0.01f - mean * mean;
                const float inv = rsqrtf(var + 1e-5f);
                short* orow = out + gpx * 112;
                for (int c = 0; c < 112; ++c) {
                    short o = 0;
                    if (c < 100) {
                        const float t = bf2f(lr[c]) + bf2f(rr[c]);
                        o = f2bf((t - mean) * inv * lng[c] + lnbv[c]);
                    }
                    orow[c] = o;
                }
            }
        }
    }
}

// ---------------------------------------------------------------------------
// Transposes / conversions
// ---------------------------------------------------------------------------
__global__ __launch_bounds__(256) void r_transpose(
    const float* __restrict__ R, short* __restrict__ Rt)
{
    __shared__ float Ts[64][65];
    const int tid = threadIdx.x;
    const long base = (long)blockIdx.z * 589824;
    const int d0 = blockIdx.y * 64, e0 = blockIdx.x * 64;
    const int c = tid & 63, rbase = tid >> 6;
#pragma unroll
    for (int j = 0; j < 16; ++j) {
        const int r = rbase + j * 4;
        Ts[r][c] = R[base + (long)(d0 + r) * 768 + e0 + c];
    }
    __syncthreads();
#pragma unroll
    for (int j = 0; j < 16; ++j) {
        const int e = rbase + j * 4;
        Rt[base + (long)(e0 + e) * 768 + d0 + c] = f2bf(Ts[c][e]);
    }
}

// mh_w{f,b}[l] [8][768][96] f32 -> WFBT [16][128][768] bf16 (o-major, padded).
__global__ __launch_bounds__(256) void wfb_transpose(
    const float* __restrict__ wf, const float* __restrict__ wb,
    short* __restrict__ dst)
{
    __shared__ float Ts[64][65];
    const int tid = threadIdx.x;
    const int z = blockIdx.z;
    const float* src = (z < 8) ? wf + (long)z * 73728 : wb + (long)(z - 8) * 73728;
    const int d0 = blockIdx.x * 64, o0 = blockIdx.y * 64;
    const int c = tid & 63, rbase = tid >> 6;
#pragma unroll
    for (int j = 0; j < 16; ++j) {
        const int r = rbase + j * 4;
        Ts[r][c] = (o0 + c < 96) ? src[(long)(d0 + r) * 96 + o0 + c] : 0.f;
    }
    __syncthreads();
#pragma unroll
    for (int j = 0; j < 16; ++j) {
        const int e = rbase + j * 4;
        dst[(long)z * 98304 + (long)(o0 + e) * 768 + d0 + c] = f2bf(Ts[c][e]);
    }
}

// Laplace-normalize bf16 Ahat (deterministic 2-partial rowsums) -> A and A^T.
__global__ __launch_bounds__(256) void a_laplace_t(
    const short* __restrict__ Ahat, const float* __restrict__ psum,
    short* __restrict__ ABF, short* __restrict__ ABFT)
{
    __shared__ float Ts[64][65];
    const int tid = threadIdx.x;
    const int r8 = blockIdx.z;
    const long ra = (long)r8 * 262144;
    const int i0 = blockIdx.y * 64, j0 = blockIdx.x * 64;
    const int c = tid & 63, rbase = tid >> 6;
    const float sj = psum[r8 * 1024 + (j0 + c) * 2] + psum[r8 * 1024 + (j0 + c) * 2 + 1];
    const float dj = rsqrtf(sj);
#pragma unroll
    for (int j = 0; j < 16; ++j) {
        const int r = rbase + j * 4;
        const float si = psum[r8 * 1024 + (i0 + r) * 2] + psum[r8 * 1024 + (i0 + r) * 2 + 1];
        const float di = rsqrtf(si);
        const float v = bf2f(Ahat[ra + (long)(i0 + r) * 512 + j0 + c]) * di * dj;
        Ts[r][c] = v;
        ABF[ra + (long)(i0 + r) * 512 + j0 + c] = f2bf(v);
    }
    __syncthreads();
#pragma unroll
    for (int j = 0; j < 16; ++j) {
        const int e = rbase + j * 4;
        ABFT[ra + (long)(j0 + e) * 512 + i0 + c] = f2bf(Ts[c][e]);
    }
}

// e[m][r*96+o] = bf16(relu(O1[r][m][o] + O2[r][m][o] + mh_b[r*96+o]))
__global__ __launch_bounds__(256) void gcn_combine(
    const short* __restrict__ O1, const short* __restrict__ O2,
    const float* __restrict__ mhb, short* __restrict__ e)
{
    const int idx = blockIdx.x * 256 + threadIdx.x;  // 393216
    const int m = idx / 768, c = idx - m * 768;
    const int r = c / 96, o = c - r * 96;
    const long oi = (long)r * 65536 + (long)m * 128 + o;
    float v = bf2f(O1[oi]) + bf2f(O2[oi]) + mhb[c];
    e[idx] = f2bf(fmaxf(v, 0.f));
}

__global__ __launch_bounds__(256) void rel_transpose(
    const short* __restrict__ relc, short* __restrict__ relp)
{
    __shared__ short Ts[64][40];
    const int tid = threadIdx.x;
    const long p0 = (long)blockIdx.x * 64;
    const int r0 = blockIdx.y * 32;
    {
        const int ch = tid >> 3, pxo = (tid & 7) * 8;
        short8v v = {0, 0, 0, 0, 0, 0, 0, 0};
        if (r0 + ch < 100)
            v = *(const short8v*)(relc + (long)(r0 + ch) * NNpix + p0 + pxo);
#pragma unroll
        for (int j = 0; j < 8; ++j) Ts[pxo + j][ch] = v[j];
    }
    __syncthreads();
    const int px = tid >> 2, k8 = (tid & 3) * 8;
    if (r0 + k8 < 112) {
        const short8v o = *(const short8v*)(&Ts[px][k8]);
        *(short8v*)(relp + (p0 + px) * 112 + r0 + k8) = o;
    }
}

__global__ __launch_bounds__(256) void conv_w_flat(
    const float* __restrict__ src, short* __restrict__ dst,
    int COUT, int CIN, int COUTP, int CINW)
{
    const int idx = blockIdx.x * 256 + threadIdx.x;
    const int KW = 9 * CINW;
    const int total = COUTP * KW;
    if (idx >= total) return;
    const int co = idx / KW;
    const int rem = idx - co * KW;
    const int tap = rem / CINW, ci = rem - tap * CINW;
    short v = 0;
    if (co < COUT && ci < CIN)
        v = f2bf(src[((long)co * CIN + ci) * 9 + tap]);
    dst[idx] = v;
}

__global__ __launch_bounds__(256) void f32_to_bf16k(
    const float* __restrict__ src, short* __restrict__ dst, long n)
{
    const long i = (long)blockIdx.x * 256 + threadIdx.x;
    if (i < n) dst[i] = f2bf(src[i]);
}

// ---------------------------------------------------------------------------
// Pixel-major channel LN (C=100, CP=112) — used for the l1 rel_ln only.
// ---------------------------------------------------------------------------
__global__ __launch_bounds__(256) void ln_pix(
    const short* __restrict__ x, const short* __restrict__ res,
    const float* __restrict__ g, const float* __restrict__ b,
    short* __restrict__ out)
{
    __shared__ float gs[100], bs[100];
    const int tid = threadIdx.x;
    if (tid < 100) { gs[tid] = g[tid]; bs[tid] = b[tid]; }
    __syncthreads();
    const long p = (long)blockIdx.x * 256 + tid;
    const short* xr = x + p * 112;
    const short* rr = res + p * 112;
    float v[104];
    float s = 0.f, ss = 0.f;
#pragma unroll
    for (int q = 0; q < 13; ++q) {
        const short8v xa = *(const short8v*)(xr + q * 8);
        const short8v ra = *(const short8v*)(rr + q * 8);
#pragma unroll
        for (int j = 0; j < 8; ++j) {
            const int idx = q * 8 + j;
            const float t = bf2f(xa[j]) + bf2f(ra[j]);
            if (idx < 100) { v[idx] = t; s += t; ss += t * t; }
        }
    }
    const float mean = s * 0.01f;
    const float var = ss * 0.01f - mean * mean;
    const float inv = rsqrtf(var + 1e-5f);
    short* orow = out + p * 112;
#pragma unroll
    for (int q = 0; q < 14; ++q) {
        short8v o;
#pragma unroll
        for (int j = 0; j < 8; ++j) {
            const int idx = q * 8 + j;
            o[j] = (idx < 100) ? f2bf((v[idx] - mean) * inv * gs[idx] + bs[idx])
                               : (short)0;
        }
        *(short8v*)(orow + q * 8) = o;
    }
}

// ---------------------------------------------------------------------------
// softmax over 8 relation logits + bf16 A_hat + deterministic rowsum partials
// ---------------------------------------------------------------------------
__global__ __launch_bounds__(256) void rel_softmax_laplace(
    const short* __restrict__ relp,
    const float* __restrict__ w,
    const float* __restrict__ bvec,
    short* __restrict__ Ahat,
    float* __restrict__ psum)
{
    __shared__ float ws[800];
    __shared__ float wred[8][4];
    const int tid = threadIdx.x;
    for (int i = tid; i < 800; i += 256) ws[i] = w[i];
    __syncthreads();

    const int i = blockIdx.y;
    const int j = blockIdx.x * 256 + tid;
    const long p = (long)i * 512 + j;
    const short* row = relp + p * 112;

    float acc[8];
#pragma unroll
    for (int r8 = 0; r8 < 8; ++r8) acc[r8] = bvec[r8];
#pragma unroll
    for (int q = 0; q < 13; ++q) {
        const short8v v = *(const short8v*)(row + q * 8);
#pragma unroll
        for (int jj = 0; jj < 8; ++jj) {
            const int r = q * 8 + jj;
            if (r < 100) {
                const float x = bf2f(v[jj]);
#pragma unroll
                for (int r8 = 0; r8 < 8; ++r8)
                    acc[r8] = fmaf(x, ws[r8 * 100 + r], acc[r8]);
            }
        }
    }
    float m = acc[0];
#pragma unroll
    for (int r8 = 1; r8 < 8; ++r8) m = fmaxf(m, acc[r8]);
    float s = 0.f;
#pragma unroll
    for (int r8 = 0; r8 < 8; ++r8) { acc[r8] = expf(acc[r8] - m); s += acc[r8]; }
    const float inv = 1.f / s;
#pragma unroll
    for (int r8 = 0; r8 < 8; ++r8) {
        const float a = acc[r8] * inv + (i == j ? 1.f : 0.f);
        acc[r8] = a;
        Ahat[(long)r8 * NNpix + p] = f2bf(a);
    }
    const int lane = tid & 63, wvv = tid >> 6;
#pragma unroll
    for (int r8 = 0; r8 < 8; ++r8) {
        float v = acc[r8];
        for (int off = 32; off > 0; off >>= 1) v += __shfl_down(v, off);
        if (lane == 0) wred[r8][wvv] = v;
    }
    __syncthreads();
    if (tid < 8) {
        const float v = wred[tid][0] + wred[tid][1] + wred[tid][2] + wred[tid][3];
        psum[tid * 1024 + i * 2 + blockIdx.x] = v;
    }
}

// Row LN over D=768 with fused bf16 emit of the normalized ents.
__global__ __launch_bounds__(256) void ln_row768(
    const float* __restrict__ x, const float* __restrict__ res,
    const float* __restrict__ g, const float* __restrict__ b,
    float* __restrict__ outf, short* __restrict__ outbf)
{
    const int n = blockIdx.x;
    const int tid = threadIdx.x;
    float v[3];
    float s = 0.f, ss = 0.f;
#pragma unroll
    for (int i = 0; i < 3; ++i) {
        const int c = tid + 256 * i;
        v[i] = x[(long)n * 768 + c] + res[(long)n * 768 + c];
        s += v[i]; ss += v[i] * v[i];
    }
    const int lane = tid & 63, wv = tid >> 6;
    for (int off = 32; off > 0; off >>= 1) {
        s += __shfl_down(s, off);
        ss += __shfl_down(ss, off);
    }
    __shared__ float rs[4], rss[4];
    if (lane == 0) { rs[wv] = s; rss[wv] = ss; }
    __syncthreads();
    s = rs[0] + rs[1] + rs[2] + rs[3];
    ss = rss[0] + rss[1] + rss[2] + rss[3];
    const float mean = s * (1.f / 768.f);
    const float var = ss * (1.f / 768.f) - mean * mean;
    const float inv = rsqrtf(var + 1e-5f);
#pragma unroll
    for (int i = 0; i < 3; ++i) {
        const int c = tid + 256 * i;
        const float o = (v[i] - mean) * inv * g[c] + b[c];
        outf[(long)n * 768 + c] = o;
        outbf[(long)n * 768 + c] = f2bf(o);
    }
}

__global__ __launch_bounds__(256) void final_rels(
    const short* __restrict__ relp, const float* __restrict__ w,
    const float* __restrict__ bvec, float* __restrict__ out)
{
    __shared__ float ws[800];
    const int tid = threadIdx.x;
    for (int i = tid; i < 800; i += 256) ws[i] = w[i];
    __syncthreads();
    const long p = (long)blockIdx.x * 256 + tid;
    const short* row = relp + p * 112;
    float acc[8];
#pragma unroll
    for (int r8 = 0; r8 < 8; ++r8) acc[r8] = bvec[r8];
#pragma unroll
    for (int q = 0; q < 13; ++q) {
        const short8v v = *(const short8v*)(row + q * 8);
#pragma unroll
        for (int jj = 0; jj < 8; ++jj) {
            const int r = q * 8 + jj;
            if (r < 100) {
                const float x = bf2f(v[jj]);
#pragma unroll
                for (int r8 = 0; r8 < 8; ++r8)
                    acc[r8] = fmaf(x, ws[r8 * 100 + r], acc[r8]);
            }
        }
    }
#pragma unroll
    for (int r8 = 0; r8 < 8; ++r8) out[p * 8 + r8] = acc[r8];
}

__global__ __launch_bounds__(256) void zero_f32(float* __restrict__ p, long n)
{
    const long i = (long)blockIdx.x * 256 + threadIdx.x;
    if (i < n) p[i] = 0.f;
}

// ---------------------------------------------------------------------------
extern "C" void kernel_launch(void* const* d_in, const int* in_sizes, int n_in,
                              void* d_out, int out_size, void* d_ws, size_t ws_size,
                              hipStream_t stream)
{
    (void)in_sizes; (void)n_in; (void)out_size; (void)ws_size;

    const float* ents_in   = (const float*)d_in[0];
    const float* R_local   = (const float*)d_in[1];
    const float* rel_mlp_w = (const float*)d_in[2];
    const float* rel_mlp_b = (const float*)d_in[3];
    const float* conv1_w   = (const float*)d_in[4];
    const float* conv1_b   = (const float*)d_in[5];
    const float* conv2_w   = (const float*)d_in[6];
    const float* conv2_b   = (const float*)d_in[7];
    const float* pffn_g    = (const float*)d_in[8];
    const float* pffn_b    = (const float*)d_in[9];
    const float* rln_g     = (const float*)d_in[10];
    const float* rln_b     = (const float*)d_in[11];
    const float* mh_wf     = (const float*)d_in[12];
    const float* mh_wb     = (const float*)d_in[13];
    const float* mh_b      = (const float*)d_in[14];
    const float* emlp_w    = (const float*)d_in[15];
    const float* emlp_b    = (const float*)d_in[16];
    const float* eln_g     = (const float*)d_in[17];
    const float* eln_b     = (const float*)d_in[18];
    float* out = (float*)d_out;

    // ---- workspace layout (1 KiB aligned) ----
    char* base = (char*)d_ws;
    size_t off = 0;
    auto alloc = [&](size_t bytes) {
        char* p = base + off;
        off += (bytes + 1023) & ~(size_t)1023;
        return p;
    };
    char* U1 = alloc(117964800 + 4096);              // RTL / H1T union
    short* RTL = (short*)U1;                         // [100][768][768] bf16
    short* H1T = (short*)U1;                         // [262144][208] bf16
    char* U2 = alloc(78643200 + 4096);               // TB union
    short* TB  = (short*)U2;                         // [100][512][768] bf16
    short* RELC   = (short*)alloc(52428800 + 4096);  // [100][512][512] bf16
    short* RELP_A = (short*)alloc(58720256 + 4096);  // [262144][112] bf16
    short* RELP_B = (short*)alloc(58720256 + 4096);
    short* RELP_C = (short*)alloc(58720256 + 4096);  // fused-LN output (l0)
    short* W1P = (short*)alloc(294912 * 2);          // [256][9*128] bf16
    short* W2P = (short*)alloc(258048 * 2);          // [128][9*224] bf16
    short* EPB = (short*)alloc(2048L * 2016 * 2 + 4096); // edge patch matrix
    // ---- TAIL region: zeroed at the start of EVERY call ----
    const size_t tail0 = off;
    short* EBF  = (short*)alloc(393216L * 2);        // ents bf16 [512][768]
    short* ABUF = (short*)alloc(2097152L * 2);       // Ahat bf16 [8][512][512]
    float* PSUM = (float*)alloc(8192L * 4);          // [8][512][2] partials
    short* ABF  = (short*)alloc(2097152L * 2);       // A bf16
    short* ABFT = (short*)alloc(2097152L * 2);       // A^T bf16 (contig)
    short* WFBT = (short*)alloc(1572864L * 2);       // [16][128][768] bf16
    short* HFBT = (short*)alloc(1048576L * 2);       // [16][128][512] bf16
    short* O1B  = (short*)alloc(524288L * 2);        // [8][512][128] bf16
    short* O2B  = (short*)alloc(524288L * 2);        // (contig after O1B)
    short* EB2  = (short*)alloc(393216L * 2);        // e bf16 [512][768]
    short* EWB  = (short*)alloc(589824L * 2);        // emlp_w bf16 [768][768]
    float* E2   = (float*)alloc(393216L * 4);
    float* ENTS1 = (float*)alloc(393216L * 4);       // layer-0 output ents
    const long tailN = (long)((off - tail0) / 4);
    (void)O2B;

    zero_f32<<<(int)((tailN + 255) / 256), 256, 0, stream>>>(
        (float*)(base + tail0), tailN);

    for (int l = 0; l < 2; ++l) {
        // RELP_res: pre-posFFN rel tensor (residual). RELP_out: post-LN rel.
        short* RELP_res = (l == 0) ? RELP_A : RELP_B;
        short* RELP_out = (l == 0) ? RELP_C : RELP_A;
        const float* ents_cur = (l == 0) ? ents_in : ENTS1;
        float* ents_next = (l == 0) ? ENTS1 : out;

        if (l == 0)
            f32_to_bf16k<<<1536, 256, 0, stream>>>(ents_in, EBF, 393216);

        r_transpose<<<dim3(12, 12, 100), 256, 0, stream>>>(
            R_local + (long)l * 58982400, RTL);

        // t[r] = ents @ R[r] ; rel[r] = relu(t[r] @ ents^T)
        bgemm_xyt<false><<<dim3(6, 4, 100), 256, 0, stream>>>(
            EBF, 0, RTL, 589824L, TB, 393216L, 512, 768, 768);
        bgemm_xyt<true><<<dim3(4, 4, 100), 256, 0, stream>>>(
            TB, 393216L, EBF, 0, RELC, 262144L, 512, 512, 768);
        rel_transpose<<<dim3(4096, 4), 256, 0, stream>>>(RELC, RELP_res);
        if (l > 0)  // rel_ln against layer-0's final rels
            ln_pix<<<1024, 256, 0, stream>>>(RELP_res, RELP_C,
                rln_g + l * 100, rln_b + l * 100, RELP_res);

        // posFFN convs: ky-slab MFMA main pass (XCD-swizzled) + edge fix;
        // conv2 (main + edge) fuses the channel-LN, writing RELP_out.
        conv_w_flat<<<1152, 256, 0, stream>>>(
            conv1_w + (long)l * 180000, W1P, 200, 100, 256, 128);
        conv_w_flat<<<1008, 256, 0, stream>>>(
            conv2_w + (long)l * 180000, W2P, 100, 200, 128, 224);

        conv_gemm<112, 128, 200, 208, true, false>
            <<<dim3(2048, 2), 256, 0, stream>>>(
            RELP_res, W1P, conv1_b + l * 200, H1T, nullptr, nullptr, nullptr);
        edge_gather<112, 128><<<2048, 256, 0, stream>>>(RELP_res, EPB);
        conv_edge_gemm<200, 208, true, false>
            <<<dim3(16, 2), 256, 0, stream>>>(
            EPB, W1P, conv1_b + l * 200, H1T, 1152, nullptr, nullptr, nullptr);

        conv_gemm<208, 224, 100, 112, false, true>
            <<<dim3(2048, 1), 256, 0, stream>>>(
            H1T, W2P, conv2_b + l * 100, RELP_out,
            RELP_res, pffn_g + l * 100, pffn_b + l * 100);
        edge_gather<208, 224><<<2048, 256, 0, stream>>>(H1T, EPB);
        conv_edge_gemm<100, 112, false, true>
            <<<dim3(16, 1), 256, 0, stream>>>(
            EPB, W2P, conv2_b + l * 100, RELP_out, 2016,
            RELP_res, pffn_g + l * 100, pffn_b + l * 100);

        // softmax + deterministic rowsum partials; Laplace into bf16 A, A^T
        rel_softmax_laplace<<<dim3(2, 512), 256, 0, stream>>>(
            RELP_out, rel_mlp_w, rel_mlp_b, ABUF, PSUM);
        a_laplace_t<<<dim3(8, 8, 8), 256, 0, stream>>>(ABUF, PSUM, ABF, ABFT);

        // GCN via MFMA: HFT/HBT = h^T; merged O-GEMM (z<8: A.hf, z>=8: A^T.hb)
        wfb_transpose<<<dim3(12, 2, 16), 256, 0, stream>>>(
            mh_wf + (long)l * 589824, mh_wb + (long)l * 589824, WFBT);
        bgemm_xyt<false><<<dim3(4, 1, 16), 256, 0, stream>>>(
            WFBT, 98304L, EBF, 0, HFBT, 65536L, 128, 512, 768);
        bgemm_xyt<false><<<dim3(1, 4, 16), 256, 0, stream>>>(
            ABF, 262144L, HFBT, 65536L, O1B, 65536L, 512, 128, 512);
        gcn_combine<<<1536, 256, 0, stream>>>(O1B, O1B + 8L * 65536,
                                              mh_b + l * 768, EB2);

        // ent_mlp (MFMA) + residual LN (out-of-place; fused bf16 emit)
        f32_to_bf16k<<<2304, 256, 0, stream>>>(
            emlp_w + (long)l * 589824, EWB, 589824);
        bgemm_bias_f32<<<dim3(6, 4), 256, 0, stream>>>(
            EB2, EWB, E2, emlp_b + l * 768, 512, 768, 768);
        ln_row768<<<512, 256, 0, stream>>>(E2, ents_cur,
            eln_g + l * 768, eln_b + l * 768, ents_next, EBF);
    }

    // layer-1 final rels live in RELP_A (RELP_out of l=1)
    final_rels<<<1024, 256, 0, stream>>>(RELP_A, rel_mlp_w, rel_mlp_b, out + 393216);
}

// Round 16
// 1759.214 us; speedup vs baseline: 1.2489x; 1.2489x over previous
//
#include <hip/hip_runtime.h>
#include <hip/hip_bf16.h>

// DecoderIGCN forward. Round 16: round-15 conv2-fused channel-LN with the
// epilogue memory pattern fixed — t staged in LDS (stride-120, aligned),
// per-row stats vectorized, and the output written as a linear coalesced
// short8 stream (round 15's 2B scalar stores caused 10x write amplification,
// WRITE_SIZE 589MB vs 58.7MB logical). N=512, D=768, RDIM=100, R=8, L=2.

static constexpr long NNpix = 512L * 512L; // 262144

typedef __attribute__((ext_vector_type(8))) short short8v;
typedef __attribute__((ext_vector_type(4))) float f32x4;

__device__ inline float bf2f(short s) {
    unsigned u = ((unsigned)(unsigned short)s) << 16;
    float f; __builtin_memcpy(&f, &u, 4);
    return f;
}
__device__ inline short f2bf(float f) {
    unsigned u; __builtin_memcpy(&u, &f, 4);
    u += 0x7fff + ((u >> 16) & 1);   // RNE
    return (short)(u >> 16);
}
__device__ inline void gload_lds16(const short* g, short* l) {
    __builtin_amdgcn_global_load_lds(
        (const __attribute__((address_space(1))) unsigned int*)g,
        (__attribute__((address_space(3))) unsigned int*)l, 16, 0, 0);
}

// Bijective XCD swizzle of the flattened block index (requires total%8==0;
// identity otherwise). Consecutive swizzled ids share an XCD's L2.
__device__ inline void xcd_block3(int& bx, int& by, int& bz) {
    const long gx = gridDim.x, gy = gridDim.y;
    const long total = gx * gy * (long)gridDim.z;
    long lin = blockIdx.x + gx * (blockIdx.y + gy * (long)blockIdx.z);
    if ((total & 7) == 0)
        lin = (lin & 7) * (total >> 3) + (lin >> 3);
    const long gxy = gx * gy;
    bz = (int)(lin / gxy);
    const int rem = (int)(lin - (long)bz * gxy);
    by = rem / (int)gx;
    bx = rem - by * (int)gx;
}

// ---------------------------------------------------------------------------
// bf16 MFMA GEMM: D[M][N] = (relu?)(X[M][K] . Y[N][K]^T), all bf16 (shorts).
// 128x128 tile, BK=32, 256 threads (4 waves, 2x2), 16x16x32 MFMA.
// ---------------------------------------------------------------------------
template <bool RELU>
__global__ __launch_bounds__(256) void bgemm_xyt(
    const short* __restrict__ X, long sX,
    const short* __restrict__ Y, long sY,
    short* __restrict__ D, long sD,
    int M, int N, int K)
{
    int bx, by, bz;
    xcd_block3(bx, by, bz);
    X += (long)bz * sX;
    Y += (long)bz * sY;
    D += (long)bz * sD;

    __shared__ short Xs[128 * 32];
    __shared__ short Ys[128 * 32];

    const int tid = threadIdx.x, wv = tid >> 6, ln = tid & 63;
    const int wr = wv >> 1, wc = wv & 1;
    const int m0 = by * 128, n0 = bx * 128;

    f32x4 acc[4][4] = {};

    const int srow = ln >> 2;
    const int sk8 = ln & 3;
    const int fr = ln & 15, fk = (ln >> 4) * 8;

    for (int k0 = 0; k0 < K; k0 += 32) {
#pragma unroll
        for (int i = wv; i < 8; i += 4) {
            gload_lds16(X + (long)(m0 + i * 16 + srow) * K + k0 + sk8 * 8,
                        Xs + i * 512);
            gload_lds16(Y + (long)(n0 + i * 16 + srow) * K + k0 + sk8 * 8,
                        Ys + i * 512);
        }
        __syncthreads();
        short8v a[4], b[4];
#pragma unroll
        for (int mi = 0; mi < 4; ++mi)
            a[mi] = *(const short8v*)(Xs + (wr * 64 + mi * 16 + fr) * 32 + fk);
#pragma unroll
        for (int ni = 0; ni < 4; ++ni)
            b[ni] = *(const short8v*)(Ys + (wc * 64 + ni * 16 + fr) * 32 + fk);
#pragma unroll
        for (int mi = 0; mi < 4; ++mi)
#pragma unroll
            for (int ni = 0; ni < 4; ++ni)
                acc[mi][ni] = __builtin_amdgcn_mfma_f32_16x16x32_bf16(
                    a[mi], b[ni], acc[mi][ni], 0, 0, 0);
        __syncthreads();
    }

    const int fv = (ln >> 4) * 4;
#pragma unroll
    for (int mi = 0; mi < 4; ++mi)
#pragma unroll
        for (int ni = 0; ni < 4; ++ni)
#pragma unroll
            for (int v = 0; v < 4; ++v) {
                const int row = m0 + wr * 64 + mi * 16 + fv + v;
                const int col = n0 + wc * 64 + ni * 16 + fr;
                float x = acc[mi][ni][v];
                if (RELU) x = fmaxf(x, 0.f);
                D[(long)row * N + col] = f2bf(x);
            }
}

// Same GEMM, fp32 output + per-column bias (for emlp).
__global__ __launch_bounds__(256) void bgemm_bias_f32(
    const short* __restrict__ X,
    const short* __restrict__ Y,
    float* __restrict__ D,
    const float* __restrict__ bias,
    int M, int N, int K)
{
    int bx, by, bz;
    xcd_block3(bx, by, bz);
    (void)bz;

    __shared__ short Xs[128 * 32];
    __shared__ short Ys[128 * 32];

    const int tid = threadIdx.x, wv = tid >> 6, ln = tid & 63;
    const int wr = wv >> 1, wc = wv & 1;
    const int m0 = by * 128, n0 = bx * 128;

    f32x4 acc[4][4] = {};

    const int srow = ln >> 2;
    const int sk8 = ln & 3;
    const int fr = ln & 15, fk = (ln >> 4) * 8;

    for (int k0 = 0; k0 < K; k0 += 32) {
#pragma unroll
        for (int i = wv; i < 8; i += 4) {
            gload_lds16(X + (long)(m0 + i * 16 + srow) * K + k0 + sk8 * 8,
                        Xs + i * 512);
            gload_lds16(Y + (long)(n0 + i * 16 + srow) * K + k0 + sk8 * 8,
                        Ys + i * 512);
        }
        __syncthreads();
        short8v a[4], b[4];
#pragma unroll
        for (int mi = 0; mi < 4; ++mi)
            a[mi] = *(const short8v*)(Xs + (wr * 64 + mi * 16 + fr) * 32 + fk);
#pragma unroll
        for (int ni = 0; ni < 4; ++ni)
            b[ni] = *(const short8v*)(Ys + (wc * 64 + ni * 16 + fr) * 32 + fk);
#pragma unroll
        for (int mi = 0; mi < 4; ++mi)
#pragma unroll
            for (int ni = 0; ni < 4; ++ni)
                acc[mi][ni] = __builtin_amdgcn_mfma_f32_16x16x32_bf16(
                    a[mi], b[ni], acc[mi][ni], 0, 0, 0);
        __syncthreads();
    }

    const int fv = (ln >> 4) * 4;
#pragma unroll
    for (int mi = 0; mi < 4; ++mi)
#pragma unroll
        for (int ni = 0; ni < 4; ++ni)
#pragma unroll
            for (int v = 0; v < 4; ++v) {
                const int row = m0 + wr * 64 + mi * 16 + fv + v;
                const int col = n0 + wc * 64 + ni * 16 + fr;
                D[(long)row * N + col] = acc[mi][ni][v] + bias[col];
            }
}

// ---------------------------------------------------------------------------
// conv3x3 main pass (ky-slab, 4 waves, XCD m-swizzle). FUSE_LN=true (conv2,
// gridDim.y==1): stage t = bf16(conv+bias)+res in LDS [128][120], per-row
// stats (vector LDS reads), then a linear coalesced short8 output stream.
// ---------------------------------------------------------------------------
template <int CINP, int CINW, int COUT, int OUTP, bool RELU, bool FUSE_LN>
__global__ __launch_bounds__(256) void conv_gemm(
    const short* __restrict__ img,
    const short* __restrict__ wflat,
    const float* __restrict__ bias,
    short* __restrict__ out,
    const short* __restrict__ res,
    const float* __restrict__ lng,
    const float* __restrict__ lnbv)
{
    constexpr int NCH = CINW / 32;
    constexpr int KW = 9 * CINW;

    __shared__ short SMEM[144 * 32 + 3 * 128 * 32];  // 16896 >= 128*120 lnbuf
    short* Xs = SMEM;
    short* Ys = SMEM + 144 * 32;

    const int tid = threadIdx.x, wv = tid >> 6, ln = tid & 63;
    const int wr = wv >> 1, wc = wv & 1;
    const int bx = blockIdx.x;
    const int bsw = (bx & 7) * ((int)gridDim.x >> 3) + (bx >> 3);
    const int m0 = bsw * 128;
    const int n0 = blockIdx.y * 128;

    f32x4 acc[4][4] = {};

    const int srow = ln >> 2;
    const int sk8 = ln & 3;
    const int fr = ln & 15, fk = (ln >> 4) * 8;

    for (int ky = 0; ky < 3; ++ky) {
        const int slab0 = m0 + (ky - 1) * 512 - 1;
        for (int cc = 0; cc < NCH; ++cc) {
            const int ci0 = cc * 32;
#pragma unroll
            for (int i = wv; i < 9; i += 4) {
                int rpx = slab0 + i * 16 + srow;
                rpx = rpx < 0 ? 0 : (rpx > (int)NNpix - 1 ? (int)NNpix - 1 : rpx);
                gload_lds16(img + (long)rpx * CINP + ci0 + sk8 * 8,
                            Xs + i * 512);
            }
#pragma unroll
            for (int kx = 0; kx < 3; ++kx) {
                const int wbase = (ky * 3 + kx) * CINW;
#pragma unroll
                for (int i = wv; i < 8; i += 4)
                    gload_lds16(wflat + (long)(n0 + i * 16 + srow) * KW + wbase + ci0 + sk8 * 8,
                                Ys + kx * 4096 + i * 512);
            }
            __syncthreads();
#pragma unroll
            for (int kx = 0; kx < 3; ++kx) {
                short8v a[4], b[4];
#pragma unroll
                for (int mi = 0; mi < 4; ++mi)
                    a[mi] = *(const short8v*)(Xs + (wr * 64 + mi * 16 + fr + kx) * 32 + fk);
#pragma unroll
                for (int ni = 0; ni < 4; ++ni)
                    b[ni] = *(const short8v*)(Ys + kx * 4096 + (wc * 64 + ni * 16 + fr) * 32 + fk);
#pragma unroll
                for (int mi = 0; mi < 4; ++mi)
#pragma unroll
                    for (int ni = 0; ni < 4; ++ni)
                        acc[mi][ni] = __builtin_amdgcn_mfma_f32_16x16x32_bf16(
                            a[mi], b[ni], acc[mi][ni], 0, 0, 0);
            }
            __syncthreads();
        }
    }

    const int fv = (ln >> 4) * 4;
    if constexpr (!FUSE_LN) {
#pragma unroll
        for (int mi = 0; mi < 4; ++mi)
#pragma unroll
            for (int ni = 0; ni < 4; ++ni)
#pragma unroll
                for (int v = 0; v < 4; ++v) {
                    const int px = m0 + wr * 64 + mi * 16 + fv + v;
                    const int co = n0 + wc * 64 + ni * 16 + fr;
                    if (co < COUT) {
                        float x = acc[mi][ni][v] + bias[co];
                        if (RELU) x = fmaxf(x, 0.f);
                        out[(long)px * OUTP + co] = f2bf(x);
                    } else if (co < OUTP) {
                        out[(long)px * OUTP + co] = 0;
                    }
                }
    } else {
        __shared__ float rmean[128], rinv[128], gs[100], bs[100];
        short* lnbuf = SMEM;  // [128][120] = 15360 shorts <= 16896
        __syncthreads();      // K-loop LDS reads complete
        if (tid < 100) { gs[tid] = lng[tid]; bs[tid] = lnbv[tid]; }
        // Phase A: t = bf16(conv+bias) + res (res read in coalesced 32B runs)
#pragma unroll
        for (int mi = 0; mi < 4; ++mi)
#pragma unroll
            for (int ni = 0; ni < 4; ++ni)
#pragma unroll
                for (int v = 0; v < 4; ++v) {
                    const int pl = wr * 64 + mi * 16 + fv + v;
                    const int co = wc * 64 + ni * 16 + fr;
                    if (co < 112) {
                        float t = 0.f;
                        if (co < COUT) {
                            const long gpx = (long)m0 + pl;
                            t = bf2f(f2bf(acc[mi][ni][v] + bias[co]))
                              + bf2f(res[gpx * 112 + co]);
                        }
                        lnbuf[pl * 120 + co] = f2bf(t);
                    }
                }
        __syncthreads();
        // Phase B: per-row stats from vectorized LDS reads
        if (tid < 128) {
            const short* lr = lnbuf + tid * 120;
            float s = 0.f, ss = 0.f;
#pragma unroll
            for (int q = 0; q < 13; ++q) {
                const short8v v8 = *(const short8v*)(lr + q * 8);
#pragma unroll
                for (int j = 0; j < 8; ++j) {
                    const int idx = q * 8 + j;
                    if (idx < 100) {
                        const float t = bf2f(v8[j]);
                        s += t; ss += t * t;
                    }
                }
            }
            const float mean = s * 0.01f;
            const float var = ss * 0.01f - mean * mean;
            rmean[tid] = mean;
            rinv[tid] = rsqrtf(var + 1e-5f);
        }
        __syncthreads();
        // Phase C: linear coalesced short8 output stream (block region is
        // contiguous: rows m0..m0+127 x 112 channels)
        for (int c = tid; c < 128 * 14; c += 256) {
            const int row = c / 14, q = c - row * 14;
            const float mean = rmean[row], inv = rinv[row];
            const short8v v8 = *(const short8v*)(lnbuf + row * 120 + q * 8);
            short8v o;
#pragma unroll
            for (int j = 0; j < 8; ++j) {
                const int idx = q * 8 + j;
                o[j] = (idx < 100)
                    ? f2bf((bf2f(v8[j]) - mean) * inv * gs[idx] + bs[idx])
                    : (short)0;
            }
            *(short8v*)(out + ((long)m0 + row) * 112 + q * 8) = o;
        }
    }
}

// Edge path: gather 2044 border patches -> GEMM -> scatter (FUSE_LN for conv2).
template <int CINP, int CINW>
__global__ __launch_bounds__(256) void edge_gather(
    const short* __restrict__ img, short* __restrict__ EP)
{
    constexpr int KW = 9 * CINW;
    const int e = blockIdx.x;
    int y, x;
    bool real = true;
    if (e < 512)       { y = 0;   x = e; }
    else if (e < 1024) { y = 511; x = e - 512; }
    else if (e < 1534) { x = 0;   y = 1 + (e - 1024); }
    else if (e < 2044) { x = 511; y = 1 + (e - 1534); }
    else               { y = 0; x = 0; real = false; }

    const int tid = threadIdx.x;
    for (int idx = tid; idx < KW / 8; idx += 256) {
        const int tap = idx / (CINW / 8);
        const int c = (idx - tap * (CINW / 8)) * 8;
        short8v v = {0, 0, 0, 0, 0, 0, 0, 0};
        if (real && c < CINP) {
            const int yy = y + tap / 3 - 1, xx = x + tap % 3 - 1;
            if ((unsigned)yy < 512u && (unsigned)xx < 512u)
                v = *(const short8v*)(img + ((long)yy * 512 + xx) * CINP + c);
        }
        *(short8v*)(EP + (long)e * KW + idx * 8) = v;
    }
}

__device__ inline void edge_yx(int e, int& y, int& x) {
    if (e < 512)       { y = 0;   x = e; }
    else if (e < 1024) { y = 511; x = e - 512; }
    else if (e < 1534) { x = 0;   y = 1 + (e - 1024); }
    else               { x = 511; y = 1 + (e - 1534); }
}

template <int COUT, int OUTP, bool RELU, bool FUSE_LN>
__global__ __launch_bounds__(256) void conv_edge_gemm(
    const short* __restrict__ EP,
    const short* __restrict__ wflat,
    const float* __restrict__ bias,
    short* __restrict__ out, int K,
    const short* __restrict__ res,
    const float* __restrict__ lng,
    const float* __restrict__ lnbv)
{
    __shared__ short SMEM[128 * 120];  // >= 8192 staging; = lnbuf size
    short* Xs = SMEM;
    short* Ys = SMEM + 128 * 32;

    const int tid = threadIdx.x, wv = tid >> 6, ln = tid & 63;
    const int wr = wv >> 1, wc = wv & 1;
    const int m0 = blockIdx.x * 128, n0 = blockIdx.y * 128;

    f32x4 acc[4][4] = {};

    const int srow = ln >> 2;
    const int sk8 = ln & 3;
    const int fr = ln & 15, fk = (ln >> 4) * 8;

    for (int k0 = 0; k0 < K; k0 += 32) {
#pragma unroll
        for (int i = wv; i < 8; i += 4) {
            gload_lds16(EP + (long)(m0 + i * 16 + srow) * K + k0 + sk8 * 8,
                        Xs + i * 512);
            gload_lds16(wflat + (long)(n0 + i * 16 + srow) * K + k0 + sk8 * 8,
                        Ys + i * 512);
        }
        __syncthreads();
        short8v a[4], b[4];
#pragma unroll
        for (int mi = 0; mi < 4; ++mi)
            a[mi] = *(const short8v*)(Xs + (wr * 64 + mi * 16 + fr) * 32 + fk);
#pragma unroll
        for (int ni = 0; ni < 4; ++ni)
            b[ni] = *(const short8v*)(Ys + (wc * 64 + ni * 16 + fr) * 32 + fk);
#pragma unroll
        for (int mi = 0; mi < 4; ++mi)
#pragma unroll
            for (int ni = 0; ni < 4; ++ni)
                acc[mi][ni] = __builtin_amdgcn_mfma_f32_16x16x32_bf16(
                    a[mi], b[ni], acc[mi][ni], 0, 0, 0);
        __syncthreads();
    }

    const int fv = (ln >> 4) * 4;
    if constexpr (!FUSE_LN) {
#pragma unroll
        for (int mi = 0; mi < 4; ++mi)
#pragma unroll
            for (int ni = 0; ni < 4; ++ni)
#pragma unroll
                for (int v = 0; v < 4; ++v) {
                    const int e = m0 + wr * 64 + mi * 16 + fv + v;
                    const int co = n0 + wc * 64 + ni * 16 + fr;
                    if (e >= 2044 || co >= COUT) continue;
                    int y, x;
                    edge_yx(e, y, x);
                    float v2 = acc[mi][ni][v] + bias[co];
                    if (RELU) v2 = fmaxf(v2, 0.f);
                    out[((long)y * 512 + x) * OUTP + co] = f2bf(v2);
                }
    } else {
        __shared__ float rmean[128], rinv[128], gs[100], bs[100];
        short* lnbuf = SMEM;
        __syncthreads();
        if (tid < 100) { gs[tid] = lng[tid]; bs[tid] = lnbv[tid]; }
        // Phase A: t = bf16(conv+bias) + res
#pragma unroll
        for (int mi = 0; mi < 4; ++mi)
#pragma unroll
            for (int ni = 0; ni < 4; ++ni)
#pragma unroll
                for (int v = 0; v < 4; ++v) {
                    const int pl = wr * 64 + mi * 16 + fv + v;
                    const int co = wc * 64 + ni * 16 + fr;
                    if (co < 112) {
                        const int e = m0 + pl;
                        float t = 0.f;
                        if (co < COUT && e < 2044) {
                            int y, x;
                            edge_yx(e, y, x);
                            t = bf2f(f2bf(acc[mi][ni][v] + bias[co]))
                              + bf2f(res[((long)y * 512 + x) * 112 + co]);
                        }
                        lnbuf[pl * 120 + co] = f2bf(t);
                    }
                }
        __syncthreads();
        // Phase B: per-row stats
        if (tid < 128) {
            const short* lr = lnbuf + tid * 120;
            float s = 0.f, ss = 0.f;
#pragma unroll
            for (int q = 0; q < 13; ++q) {
                const short8v v8 = *(const short8v*)(lr + q * 8);
#pragma unroll
                for (int j = 0; j < 8; ++j) {
                    const int idx = q * 8 + j;
                    if (idx < 100) {
                        const float t = bf2f(v8[j]);
                        s += t; ss += t * t;
                    }
                }
            }
            const float mean = s * 0.01f;
            const float var = ss * 0.01f - mean * mean;
            rmean[tid] = mean;
            rinv[tid] = rsqrtf(var + 1e-5f);
        }
        __syncthreads();
        // Phase C: vectorized stores (rows scattered; 16B chunks per store)
        for (int c = tid; c < 128 * 14; c += 256) {
            const int row = c / 14, q = c - row * 14;
            const int e = m0 + row;
            if (e >= 2044) continue;
            int y, x;
            edge_yx(e, y, x);
            const float mean = rmean[row], inv = rinv[row];
            const short8v v8 = *(const short8v*)(lnbuf + row * 120 + q * 8);
            short8v o;
#pragma unroll
            for (int j = 0; j < 8; ++j) {
                const int idx = q * 8 + j;
                o[j] = (idx < 100)
                    ? f2bf((bf2f(v8[j]) - mean) * inv * gs[idx] + bs[idx])
                    : (short)0;
            }
            *(short8v*)(out + ((long)y * 512 + x) * 112 + q * 8) = o;
        }
    }
}

// ---------------------------------------------------------------------------
// Transposes / conversions
// ---------------------------------------------------------------------------
__global__ __launch_bounds__(256) void r_transpose(
    const float* __restrict__ R, short* __restrict__ Rt)
{
    __shared__ float Ts[64][65];
    const int tid = threadIdx.x;
    const long base = (long)blockIdx.z * 589824;
    const int d0 = blockIdx.y * 64, e0 = blockIdx.x * 64;
    const int c = tid & 63, rbase = tid >> 6;
#pragma unroll
    for (int j = 0; j < 16; ++j) {
        const int r = rbase + j * 4;
        Ts[r][c] = R[base + (long)(d0 + r) * 768 + e0 + c];
    }
    __syncthreads();
#pragma unroll
    for (int j = 0; j < 16; ++j) {
        const int e = rbase + j * 4;
        Rt[base + (long)(e0 + e) * 768 + d0 + c] = f2bf(Ts[c][e]);
    }
}

// mh_w{f,b}[l] [8][768][96] f32 -> WFBT [16][128][768] bf16 (o-major, padded).
__global__ __launch_bounds__(256) void wfb_transpose(
    const float* __restrict__ wf, const float* __restrict__ wb,
    short* __restrict__ dst)
{
    __shared__ float Ts[64][65];
    const int tid = threadIdx.x;
    const int z = blockIdx.z;
    const float* src = (z < 8) ? wf + (long)z * 73728 : wb + (long)(z - 8) * 73728;
    const int d0 = blockIdx.x * 64, o0 = blockIdx.y * 64;
    const int c = tid & 63, rbase = tid >> 6;
#pragma unroll
    for (int j = 0; j < 16; ++j) {
        const int r = rbase + j * 4;
        Ts[r][c] = (o0 + c < 96) ? src[(long)(d0 + r) * 96 + o0 + c] : 0.f;
    }
    __syncthreads();
#pragma unroll
    for (int j = 0; j < 16; ++j) {
        const int e = rbase + j * 4;
        dst[(long)z * 98304 + (long)(o0 + e) * 768 + d0 + c] = f2bf(Ts[c][e]);
    }
}

// Laplace-normalize bf16 Ahat (deterministic 2-partial rowsums) -> A and A^T.
__global__ __launch_bounds__(256) void a_laplace_t(
    const short* __restrict__ Ahat, const float* __restrict__ psum,
    short* __restrict__ ABF, short* __restrict__ ABFT)
{
    __shared__ float Ts[64][65];
    const int tid = threadIdx.x;
    const int r8 = blockIdx.z;
    const long ra = (long)r8 * 262144;
    const int i0 = blockIdx.y * 64, j0 = blockIdx.x * 64;
    const int c = tid & 63, rbase = tid >> 6;
    const float sj = psum[r8 * 1024 + (j0 + c) * 2] + psum[r8 * 1024 + (j0 + c) * 2 + 1];
    const float dj = rsqrtf(sj);
#pragma unroll
    for (int j = 0; j < 16; ++j) {
        const int r = rbase + j * 4;
        const float si = psum[r8 * 1024 + (i0 + r) * 2] + psum[r8 * 1024 + (i0 + r) * 2 + 1];
        const float di = rsqrtf(si);
        const float v = bf2f(Ahat[ra + (long)(i0 + r) * 512 + j0 + c]) * di * dj;
        Ts[r][c] = v;
        ABF[ra + (long)(i0 + r) * 512 + j0 + c] = f2bf(v);
    }
    __syncthreads();
#pragma unroll
    for (int j = 0; j < 16; ++j) {
        const int e = rbase + j * 4;
        ABFT[ra + (long)(j0 + e) * 512 + i0 + c] = f2bf(Ts[c][e]);
    }
}

// e[m][r*96+o] = bf16(relu(O1[r][m][o] + O2[r][m][o] + mh_b[r*96+o]))
__global__ __launch_bounds__(256) void gcn_combine(
    const short* __restrict__ O1, const short* __restrict__ O2,
    const float* __restrict__ mhb, short* __restrict__ e)
{
    const int idx = blockIdx.x * 256 + threadIdx.x;  // 393216
    const int m = idx / 768, c = idx - m * 768;
    const int r = c / 96, o = c - r * 96;
    const long oi = (long)r * 65536 + (long)m * 128 + o;
    float v = bf2f(O1[oi]) + bf2f(O2[oi]) + mhb[c];
    e[idx] = f2bf(fmaxf(v, 0.f));
}

__global__ __launch_bounds__(256) void rel_transpose(
    const short* __restrict__ relc, short* __restrict__ relp)
{
    __shared__ short Ts[64][40];
    const int tid = threadIdx.x;
    const long p0 = (long)blockIdx.x * 64;
    const int r0 = blockIdx.y * 32;
    {
        const int ch = tid >> 3, pxo = (tid & 7) * 8;
        short8v v = {0, 0, 0, 0, 0, 0, 0, 0};
        if (r0 + ch < 100)
            v = *(const short8v*)(relc + (long)(r0 + ch) * NNpix + p0 + pxo);
#pragma unroll
        for (int j = 0; j < 8; ++j) Ts[pxo + j][ch] = v[j];
    }
    __syncthreads();
    const int px = tid >> 2, k8 = (tid & 3) * 8;
    if (r0 + k8 < 112) {
        const short8v o = *(const short8v*)(&Ts[px][k8]);
        *(short8v*)(relp + (p0 + px) * 112 + r0 + k8) = o;
    }
}

__global__ __launch_bounds__(256) void conv_w_flat(
    const float* __restrict__ src, short* __restrict__ dst,
    int COUT, int CIN, int COUTP, int CINW)
{
    const int idx = blockIdx.x * 256 + threadIdx.x;
    const int KW = 9 * CINW;
    const int total = COUTP * KW;
    if (idx >= total) return;
    const int co = idx / KW;
    const int rem = idx - co * KW;
    const int tap = rem / CINW, ci = rem - tap * CINW;
    short v = 0;
    if (co < COUT && ci < CIN)
        v = f2bf(src[((long)co * CIN + ci) * 9 + tap]);
    dst[idx] = v;
}

__global__ __launch_bounds__(256) void f32_to_bf16k(
    const float* __restrict__ src, short* __restrict__ dst, long n)
{
    const long i = (long)blockIdx.x * 256 + threadIdx.x;
    if (i < n) dst[i] = f2bf(src[i]);
}

// ---------------------------------------------------------------------------
// Pixel-major channel LN (C=100, CP=112) — used for the l1 rel_ln only.
// ---------------------------------------------------------------------------
__global__ __launch_bounds__(256) void ln_pix(
    const short* __restrict__ x, const short* __restrict__ res,
    const float* __restrict__ g, const float* __restrict__ b,
    short* __restrict__ out)
{
    __shared__ float gs[100], bs[100];
    const int tid = threadIdx.x;
    if (tid < 100) { gs[tid] = g[tid]; bs[tid] = b[tid]; }
    __syncthreads();
    const long p = (long)blockIdx.x * 256 + tid;
    const short* xr = x + p * 112;
    const short* rr = res + p * 112;
    float v[104];
    float s = 0.f, ss = 0.f;
#pragma unroll
    for (int q = 0; q < 13; ++q) {
        const short8v xa = *(const short8v*)(xr + q * 8);
        const short8v ra = *(const short8v*)(rr + q * 8);
#pragma unroll
        for (int j = 0; j < 8; ++j) {
            const int idx = q * 8 + j;
            const float t = bf2f(xa[j]) + bf2f(ra[j]);
            if (idx < 100) { v[idx] = t; s += t; ss += t * t; }
        }
    }
    const float mean = s * 0.01f;
    const float var = ss * 0.01f - mean * mean;
    const float inv = rsqrtf(var + 1e-5f);
    short* orow = out + p * 112;
#pragma unroll
    for (int q = 0; q < 14; ++q) {
        short8v o;
#pragma unroll
        for (int j = 0; j < 8; ++j) {
            const int idx = q * 8 + j;
            o[j] = (idx < 100) ? f2bf((v[idx] - mean) * inv * gs[idx] + bs[idx])
                               : (short)0;
        }
        *(short8v*)(orow + q * 8) = o;
    }
}

// ---------------------------------------------------------------------------
// softmax over 8 relation logits + bf16 A_hat + deterministic rowsum partials
// ---------------------------------------------------------------------------
__global__ __launch_bounds__(256) void rel_softmax_laplace(
    const short* __restrict__ relp,
    const float* __restrict__ w,
    const float* __restrict__ bvec,
    short* __restrict__ Ahat,
    float* __restrict__ psum)
{
    __shared__ float ws[800];
    __shared__ float wred[8][4];
    const int tid = threadIdx.x;
    for (int i = tid; i < 800; i += 256) ws[i] = w[i];
    __syncthreads();

    const int i = blockIdx.y;
    const int j = blockIdx.x * 256 + tid;
    const long p = (long)i * 512 + j;
    const short* row = relp + p * 112;

    float acc[8];
#pragma unroll
    for (int r8 = 0; r8 < 8; ++r8) acc[r8] = bvec[r8];
#pragma unroll
    for (int q = 0; q < 13; ++q) {
        const short8v v = *(const short8v*)(row + q * 8);
#pragma unroll
        for (int jj = 0; jj < 8; ++jj) {
            const int r = q * 8 + jj;
            if (r < 100) {
                const float x = bf2f(v[jj]);
#pragma unroll
                for (int r8 = 0; r8 < 8; ++r8)
                    acc[r8] = fmaf(x, ws[r8 * 100 + r], acc[r8]);
            }
        }
    }
    float m = acc[0];
#pragma unroll
    for (int r8 = 1; r8 < 8; ++r8) m = fmaxf(m, acc[r8]);
    float s = 0.f;
#pragma unroll
    for (int r8 = 0; r8 < 8; ++r8) { acc[r8] = expf(acc[r8] - m); s += acc[r8]; }
    const float inv = 1.f / s;
#pragma unroll
    for (int r8 = 0; r8 < 8; ++r8) {
        const float a = acc[r8] * inv + (i == j ? 1.f : 0.f);
        acc[r8] = a;
        Ahat[(long)r8 * NNpix + p] = f2bf(a);
    }
    const int lane = tid & 63, wvv = tid >> 6;
#pragma unroll
    for (int r8 = 0; r8 < 8; ++r8) {
        float v = acc[r8];
        for (int off = 32; off > 0; off >>= 1) v += __shfl_down(v, off);
        if (lane == 0) wred[r8][wvv] = v;
    }
    __syncthreads();
    if (tid < 8) {
        const float v = wred[tid][0] + wred[tid][1] + wred[tid][2] + wred[tid][3];
        psum[tid * 1024 + i * 2 + blockIdx.x] = v;
    }
}

// Row LN over D=768 with fused bf16 emit of the normalized ents.
__global__ __launch_bounds__(256) void ln_row768(
    const float* __restrict__ x, const float* __restrict__ res,
    const float* __restrict__ g, const float* __restrict__ b,
    float* __restrict__ outf, short* __restrict__ outbf)
{
    const int n = blockIdx.x;
    const int tid = threadIdx.x;
    float v[3];
    float s = 0.f, ss = 0.f;
#pragma unroll
    for (int i = 0; i < 3; ++i) {
        const int c = tid + 256 * i;
        v[i] = x[(long)n * 768 + c] + res[(long)n * 768 + c];
        s += v[i]; ss += v[i] * v[i];
    }
    const int lane = tid & 63, wv = tid >> 6;
    for (int off = 32; off > 0; off >>= 1) {
        s += __shfl_down(s, off);
        ss += __shfl_down(ss, off);
    }
    __shared__ float rs[4], rss[4];
    if (lane == 0) { rs[wv] = s; rss[wv] = ss; }
    __syncthreads();
    s = rs[0] + rs[1] + rs[2] + rs[3];
    ss = rss[0] + rss[1] + rss[2] + rss[3];
    const float mean = s * (1.f / 768.f);
    const float var = ss * (1.f / 768.f) - mean * mean;
    const float inv = rsqrtf(var + 1e-5f);
#pragma unroll
    for (int i = 0; i < 3; ++i) {
        const int c = tid + 256 * i;
        const float o = (v[i] - mean) * inv * g[c] + b[c];
        outf[(long)n * 768 + c] = o;
        outbf[(long)n * 768 + c] = f2bf(o);
    }
}

__global__ __launch_bounds__(256) void final_rels(
    const short* __restrict__ relp, const float* __restrict__ w,
    const float* __restrict__ bvec, float* __restrict__ out)
{
    __shared__ float ws[800];
    const int tid = threadIdx.x;
    for (int i = tid; i < 800; i += 256) ws[i] = w[i];
    __syncthreads();
    const long p = (long)blockIdx.x * 256 + tid;
    const short* row = relp + p * 112;
    float acc[8];
#pragma unroll
    for (int r8 = 0; r8 < 8; ++r8) acc[r8] = bvec[r8];
#pragma unroll
    for (int q = 0; q < 13; ++q) {
        const short8v v = *(const short8v*)(row + q * 8);
#pragma unroll
        for (int jj = 0; jj < 8; ++jj) {
            const int r = q * 8 + jj;
            if (r < 100) {
                const float x = bf2f(v[jj]);
#pragma unroll
                for (int r8 = 0; r8 < 8; ++r8)
                    acc[r8] = fmaf(x, ws[r8 * 100 + r], acc[r8]);
            }
        }
    }
#pragma unroll
    for (int r8 = 0; r8 < 8; ++r8) out[p * 8 + r8] = acc[r8];
}

__global__ __launch_bounds__(256) void zero_f32(float* __restrict__ p, long n)
{
    const long i = (long)blockIdx.x * 256 + threadIdx.x;
    if (i < n) p[i] = 0.f;
}

// ---------------------------------------------------------------------------
extern "C" void kernel_launch(void* const* d_in, const int* in_sizes, int n_in,
                              void* d_out, int out_size, void* d_ws, size_t ws_size,
                              hipStream_t stream)
{
    (void)in_sizes; (void)n_in; (void)out_size; (void)ws_size;

    const float* ents_in   = (const float*)d_in[0];
    const float* R_local   = (const float*)d_in[1];
    const float* rel_mlp_w = (const float*)d_in[2];
    const float* rel_mlp_b = (const float*)d_in[3];
    const float* conv1_w   = (const float*)d_in[4];
    const float* conv1_b   = (const float*)d_in[5];
    const float* conv2_w   = (const float*)d_in[6];
    const float* conv2_b   = (const float*)d_in[7];
    const float* pffn_g    = (const float*)d_in[8];
    const float* pffn_b    = (const float*)d_in[9];
    const float* rln_g     = (const float*)d_in[10];
    const float* rln_b     = (const float*)d_in[11];
    const float* mh_wf     = (const float*)d_in[12];
    const float* mh_wb     = (const float*)d_in[13];
    const float* mh_b      = (const float*)d_in[14];
    const float* emlp_w    = (const float*)d_in[15];
    const float* emlp_b    = (const float*)d_in[16];
    const float* eln_g     = (const float*)d_in[17];
    const float* eln_b     = (const float*)d_in[18];
    float* out = (float*)d_out;

    // ---- workspace layout (1 KiB aligned) ----
    char* base = (char*)d_ws;
    size_t off = 0;
    auto alloc = [&](size_t bytes) {
        char* p = base + off;
        off += (bytes + 1023) & ~(size_t)1023;
        return p;
    };
    char* U1 = alloc(117964800 + 4096);              // RTL / H1T union
    short* RTL = (short*)U1;                         // [100][768][768] bf16
    short* H1T = (short*)U1;                         // [262144][208] bf16
    char* U2 = alloc(78643200 + 4096);               // TB union
    short* TB  = (short*)U2;                         // [100][512][768] bf16
    short* RELC   = (short*)alloc(52428800 + 4096);  // [100][512][512] bf16
    short* RELP_A = (short*)alloc(58720256 + 4096);  // [262144][112] bf16
    short* RELP_B = (short*)alloc(58720256 + 4096);
    short* RELP_C = (short*)alloc(58720256 + 4096);  // fused-LN output (l0)
    short* W1P = (short*)alloc(294912 * 2);          // [256][9*128] bf16
    short* W2P = (short*)alloc(258048 * 2);          // [128][9*224] bf16
    short* EPB = (short*)alloc(2048L * 2016 * 2 + 4096); // edge patch matrix
    // ---- TAIL region: zeroed at the start of EVERY call ----
    const size_t tail0 = off;
    short* EBF  = (short*)alloc(393216L * 2);        // ents bf16 [512][768]
    short* ABUF = (short*)alloc(2097152L * 2);       // Ahat bf16 [8][512][512]
    float* PSUM = (float*)alloc(8192L * 4);          // [8][512][2] partials
    short* ABF  = (short*)alloc(2097152L * 2);       // A bf16
    short* ABFT = (short*)alloc(2097152L * 2);       // A^T bf16 (contig)
    short* WFBT = (short*)alloc(1572864L * 2);       // [16][128][768] bf16
    short* HFBT = (short*)alloc(1048576L * 2);       // [16][128][512] bf16
    short* O1B  = (short*)alloc(524288L * 2);        // [8][512][128] bf16
    short* O2B  = (short*)alloc(524288L * 2);        // (contig after O1B)
    short* EB2  = (short*)alloc(393216L * 2);        // e bf16 [512][768]
    short* EWB  = (short*)alloc(589824L * 2);        // emlp_w bf16 [768][768]
    float* E2   = (float*)alloc(393216L * 4);
    float* ENTS1 = (float*)alloc(393216L * 4);       // layer-0 output ents
    const long tailN = (long)((off - tail0) / 4);
    (void)O2B;

    zero_f32<<<(int)((tailN + 255) / 256), 256, 0, stream>>>(
        (float*)(base + tail0), tailN);

    for (int l = 0; l < 2; ++l) {
        // RELP_res: pre-posFFN rel tensor (residual). RELP_out: post-LN rel.
        short* RELP_res = (l == 0) ? RELP_A : RELP_B;
        short* RELP_out = (l == 0) ? RELP_C : RELP_A;
        const float* ents_cur = (l == 0) ? ents_in : ENTS1;
        float* ents_next = (l == 0) ? ENTS1 : out;

        if (l == 0)
            f32_to_bf16k<<<1536, 256, 0, stream>>>(ents_in, EBF, 393216);

        r_transpose<<<dim3(12, 12, 100), 256, 0, stream>>>(
            R_local + (long)l * 58982400, RTL);

        // t[r] = ents @ R[r] ; rel[r] = relu(t[r] @ ents^T)
        bgemm_xyt<false><<<dim3(6, 4, 100), 256, 0, stream>>>(
            EBF, 0, RTL, 589824L, TB, 393216L, 512, 768, 768);
        bgemm_xyt<true><<<dim3(4, 4, 100), 256, 0, stream>>>(
            TB, 393216L, EBF, 0, RELC, 262144L, 512, 512, 768);
        rel_transpose<<<dim3(4096, 4), 256, 0, stream>>>(RELC, RELP_res);
        if (l > 0)  // rel_ln against layer-0's final rels
            ln_pix<<<1024, 256, 0, stream>>>(RELP_res, RELP_C,
                rln_g + l * 100, rln_b + l * 100, RELP_res);

        // posFFN convs: ky-slab MFMA main pass (XCD-swizzled) + edge fix;
        // conv2 (main + edge) fuses the channel-LN, writing RELP_out.
        conv_w_flat<<<1152, 256, 0, stream>>>(
            conv1_w + (long)l * 180000, W1P, 200, 100, 256, 128);
        conv_w_flat<<<1008, 256, 0, stream>>>(
            conv2_w + (long)l * 180000, W2P, 100, 200, 128, 224);

        conv_gemm<112, 128, 200, 208, true, false>
            <<<dim3(2048, 2), 256, 0, stream>>>(
            RELP_res, W1P, conv1_b + l * 200, H1T, nullptr, nullptr, nullptr);
        edge_gather<112, 128><<<2048, 256, 0, stream>>>(RELP_res, EPB);
        conv_edge_gemm<200, 208, true, false>
            <<<dim3(16, 2), 256, 0, stream>>>(
            EPB, W1P, conv1_b + l * 200, H1T, 1152, nullptr, nullptr, nullptr);

        conv_gemm<208, 224, 100, 112, false, true>
            <<<dim3(2048, 1), 256, 0, stream>>>(
            H1T, W2P, conv2_b + l * 100, RELP_out,
            RELP_res, pffn_g + l * 100, pffn_b + l * 100);
        edge_gather<208, 224><<<2048, 256, 0, stream>>>(H1T, EPB);
        conv_edge_gemm<100, 112, false, true>
            <<<dim3(16, 1), 256, 0, stream>>>(
            EPB, W2P, conv2_b + l * 100, RELP_out, 2016,
            RELP_res, pffn_g + l * 100, pffn_b + l * 100);

        // softmax + deterministic rowsum partials; Laplace into bf16 A, A^T
        rel_softmax_laplace<<<dim3(2, 512), 256, 0, stream>>>(
            RELP_out, rel_mlp_w, rel_mlp_b, ABUF, PSUM);
        a_laplace_t<<<dim3(8, 8, 8), 256, 0, stream>>>(ABUF, PSUM, ABF, ABFT);

        // GCN via MFMA: HFT/HBT = h^T; merged O-GEMM (z<8: A.hf, z>=8: A^T.hb)
        wfb_transpose<<<dim3(12, 2, 16), 256, 0, stream>>>(
            mh_wf + (long)l * 589824, mh_wb + (long)l * 589824, WFBT);
        bgemm_xyt<false><<<dim3(4, 1, 16), 256, 0, stream>>>(
            WFBT, 98304L, EBF, 0, HFBT, 65536L, 128, 512, 768);
        bgemm_xyt<false><<<dim3(1, 4, 16), 256, 0, stream>>>(
            ABF, 262144L, HFBT, 65536L, O1B, 65536L, 512, 128, 512);
        gcn_combine<<<1536, 256, 0, stream>>>(O1B, O1B + 8L * 65536,
                                              mh_b + l * 768, EB2);

        // ent_mlp (MFMA) + residual LN (out-of-place; fused bf16 emit)
        f32_to_bf16k<<<2304, 256, 0, stream>>>(
            emlp_w + (long)l * 589824, EWB, 589824);
        bgemm_bias_f32<<<dim3(6, 4), 256, 0, stream>>>(
            EB2, EWB, E2, emlp_b + l * 768, 512, 768, 768);
        ln_row768<<<512, 256, 0, stream>>>(E2, ents_cur,
            eln_g + l * 768, eln_b + l * 768, ents_next, EBF);
    }

    // layer-1 final rels live in RELP_A (RELP_out of l=1)
    final_rels<<<1024, 256, 0, stream>>>(RELP_A, rel_mlp_w, rel_mlp_b, out + 393216);
}

// Round 17
// 1710.212 us; speedup vs baseline: 1.2847x; 1.0287x over previous
//
#include <hip/hip_runtime.h>
#include <hip/hip_bf16.h>

// DecoderIGCN forward. Round 17: rel_transpose restructured to full-channel
// blocks (64 px x 112 ch in LDS) with layer-1's channel-LN fused (reads the
// RELP_C residual in-kernel; ln_pix eliminated) and fully linear coalesced
// RELP writes. Everything else identical to round 16 (1759 us).
// N=512, D=768, RDIM=100, R=8, L=2.

static constexpr long NNpix = 512L * 512L; // 262144

typedef __attribute__((ext_vector_type(8))) short short8v;
typedef __attribute__((ext_vector_type(4))) float f32x4;

__device__ inline float bf2f(short s) {
    unsigned u = ((unsigned)(unsigned short)s) << 16;
    float f; __builtin_memcpy(&f, &u, 4);
    return f;
}
__device__ inline short f2bf(float f) {
    unsigned u; __builtin_memcpy(&u, &f, 4);
    u += 0x7fff + ((u >> 16) & 1);   // RNE
    return (short)(u >> 16);
}
__device__ inline void gload_lds16(const short* g, short* l) {
    __builtin_amdgcn_global_load_lds(
        (const __attribute__((address_space(1))) unsigned int*)g,
        (__attribute__((address_space(3))) unsigned int*)l, 16, 0, 0);
}

// Bijective XCD swizzle of the flattened block index (requires total%8==0;
// identity otherwise). Consecutive swizzled ids share an XCD's L2.
__device__ inline void xcd_block3(int& bx, int& by, int& bz) {
    const long gx = gridDim.x, gy = gridDim.y;
    const long total = gx * gy * (long)gridDim.z;
    long lin = blockIdx.x + gx * (blockIdx.y + gy * (long)blockIdx.z);
    if ((total & 7) == 0)
        lin = (lin & 7) * (total >> 3) + (lin >> 3);
    const long gxy = gx * gy;
    bz = (int)(lin / gxy);
    const int rem = (int)(lin - (long)bz * gxy);
    by = rem / (int)gx;
    bx = rem - by * (int)gx;
}

// ---------------------------------------------------------------------------
// bf16 MFMA GEMM: D[M][N] = (relu?)(X[M][K] . Y[N][K]^T), all bf16 (shorts).
// 128x128 tile, BK=32, 256 threads (4 waves, 2x2), 16x16x32 MFMA.
// ---------------------------------------------------------------------------
template <bool RELU>
__global__ __launch_bounds__(256) void bgemm_xyt(
    const short* __restrict__ X, long sX,
    const short* __restrict__ Y, long sY,
    short* __restrict__ D, long sD,
    int M, int N, int K)
{
    int bx, by, bz;
    xcd_block3(bx, by, bz);
    X += (long)bz * sX;
    Y += (long)bz * sY;
    D += (long)bz * sD;

    __shared__ short Xs[128 * 32];
    __shared__ short Ys[128 * 32];

    const int tid = threadIdx.x, wv = tid >> 6, ln = tid & 63;
    const int wr = wv >> 1, wc = wv & 1;
    const int m0 = by * 128, n0 = bx * 128;

    f32x4 acc[4][4] = {};

    const int srow = ln >> 2;
    const int sk8 = ln & 3;
    const int fr = ln & 15, fk = (ln >> 4) * 8;

    for (int k0 = 0; k0 < K; k0 += 32) {
#pragma unroll
        for (int i = wv; i < 8; i += 4) {
            gload_lds16(X + (long)(m0 + i * 16 + srow) * K + k0 + sk8 * 8,
                        Xs + i * 512);
            gload_lds16(Y + (long)(n0 + i * 16 + srow) * K + k0 + sk8 * 8,
                        Ys + i * 512);
        }
        __syncthreads();
        short8v a[4], b[4];
#pragma unroll
        for (int mi = 0; mi < 4; ++mi)
            a[mi] = *(const short8v*)(Xs + (wr * 64 + mi * 16 + fr) * 32 + fk);
#pragma unroll
        for (int ni = 0; ni < 4; ++ni)
            b[ni] = *(const short8v*)(Ys + (wc * 64 + ni * 16 + fr) * 32 + fk);
#pragma unroll
        for (int mi = 0; mi < 4; ++mi)
#pragma unroll
            for (int ni = 0; ni < 4; ++ni)
                acc[mi][ni] = __builtin_amdgcn_mfma_f32_16x16x32_bf16(
                    a[mi], b[ni], acc[mi][ni], 0, 0, 0);
        __syncthreads();
    }

    const int fv = (ln >> 4) * 4;
#pragma unroll
    for (int mi = 0; mi < 4; ++mi)
#pragma unroll
        for (int ni = 0; ni < 4; ++ni)
#pragma unroll
            for (int v = 0; v < 4; ++v) {
                const int row = m0 + wr * 64 + mi * 16 + fv + v;
                const int col = n0 + wc * 64 + ni * 16 + fr;
                float x = acc[mi][ni][v];
                if (RELU) x = fmaxf(x, 0.f);
                D[(long)row * N + col] = f2bf(x);
            }
}

// Same GEMM, fp32 output + per-column bias (for emlp).
__global__ __launch_bounds__(256) void bgemm_bias_f32(
    const short* __restrict__ X,
    const short* __restrict__ Y,
    float* __restrict__ D,
    const float* __restrict__ bias,
    int M, int N, int K)
{
    int bx, by, bz;
    xcd_block3(bx, by, bz);
    (void)bz;

    __shared__ short Xs[128 * 32];
    __shared__ short Ys[128 * 32];

    const int tid = threadIdx.x, wv = tid >> 6, ln = tid & 63;
    const int wr = wv >> 1, wc = wv & 1;
    const int m0 = by * 128, n0 = bx * 128;

    f32x4 acc[4][4] = {};

    const int srow = ln >> 2;
    const int sk8 = ln & 3;
    const int fr = ln & 15, fk = (ln >> 4) * 8;

    for (int k0 = 0; k0 < K; k0 += 32) {
#pragma unroll
        for (int i = wv; i < 8; i += 4) {
            gload_lds16(X + (long)(m0 + i * 16 + srow) * K + k0 + sk8 * 8,
                        Xs + i * 512);
            gload_lds16(Y + (long)(n0 + i * 16 + srow) * K + k0 + sk8 * 8,
                        Ys + i * 512);
        }
        __syncthreads();
        short8v a[4], b[4];
#pragma unroll
        for (int mi = 0; mi < 4; ++mi)
            a[mi] = *(const short8v*)(Xs + (wr * 64 + mi * 16 + fr) * 32 + fk);
#pragma unroll
        for (int ni = 0; ni < 4; ++ni)
            b[ni] = *(const short8v*)(Ys + (wc * 64 + ni * 16 + fr) * 32 + fk);
#pragma unroll
        for (int mi = 0; mi < 4; ++mi)
#pragma unroll
            for (int ni = 0; ni < 4; ++ni)
                acc[mi][ni] = __builtin_amdgcn_mfma_f32_16x16x32_bf16(
                    a[mi], b[ni], acc[mi][ni], 0, 0, 0);
        __syncthreads();
    }

    const int fv = (ln >> 4) * 4;
#pragma unroll
    for (int mi = 0; mi < 4; ++mi)
#pragma unroll
        for (int ni = 0; ni < 4; ++ni)
#pragma unroll
            for (int v = 0; v < 4; ++v) {
                const int row = m0 + wr * 64 + mi * 16 + fv + v;
                const int col = n0 + wc * 64 + ni * 16 + fr;
                D[(long)row * N + col] = acc[mi][ni][v] + bias[col];
            }
}

// ---------------------------------------------------------------------------
// conv3x3 main pass (ky-slab, 4 waves, XCD m-swizzle). FUSE_LN=true (conv2,
// gridDim.y==1): stage t = bf16(conv+bias)+res in LDS [128][120], per-row
// stats (vector LDS reads), then a linear coalesced short8 output stream.
// ---------------------------------------------------------------------------
template <int CINP, int CINW, int COUT, int OUTP, bool RELU, bool FUSE_LN>
__global__ __launch_bounds__(256) void conv_gemm(
    const short* __restrict__ img,
    const short* __restrict__ wflat,
    const float* __restrict__ bias,
    short* __restrict__ out,
    const short* __restrict__ res,
    const float* __restrict__ lng,
    const float* __restrict__ lnbv)
{
    constexpr int NCH = CINW / 32;
    constexpr int KW = 9 * CINW;

    __shared__ short SMEM[144 * 32 + 3 * 128 * 32];  // 16896 >= 128*120 lnbuf
    short* Xs = SMEM;
    short* Ys = SMEM + 144 * 32;

    const int tid = threadIdx.x, wv = tid >> 6, ln = tid & 63;
    const int wr = wv >> 1, wc = wv & 1;
    const int bx = blockIdx.x;
    const int bsw = (bx & 7) * ((int)gridDim.x >> 3) + (bx >> 3);
    const int m0 = bsw * 128;
    const int n0 = blockIdx.y * 128;

    f32x4 acc[4][4] = {};

    const int srow = ln >> 2;
    const int sk8 = ln & 3;
    const int fr = ln & 15, fk = (ln >> 4) * 8;

    for (int ky = 0; ky < 3; ++ky) {
        const int slab0 = m0 + (ky - 1) * 512 - 1;
        for (int cc = 0; cc < NCH; ++cc) {
            const int ci0 = cc * 32;
#pragma unroll
            for (int i = wv; i < 9; i += 4) {
                int rpx = slab0 + i * 16 + srow;
                rpx = rpx < 0 ? 0 : (rpx > (int)NNpix - 1 ? (int)NNpix - 1 : rpx);
                gload_lds16(img + (long)rpx * CINP + ci0 + sk8 * 8,
                            Xs + i * 512);
            }
#pragma unroll
            for (int kx = 0; kx < 3; ++kx) {
                const int wbase = (ky * 3 + kx) * CINW;
#pragma unroll
                for (int i = wv; i < 8; i += 4)
                    gload_lds16(wflat + (long)(n0 + i * 16 + srow) * KW + wbase + ci0 + sk8 * 8,
                                Ys + kx * 4096 + i * 512);
            }
            __syncthreads();
#pragma unroll
            for (int kx = 0; kx < 3; ++kx) {
                short8v a[4], b[4];
#pragma unroll
                for (int mi = 0; mi < 4; ++mi)
                    a[mi] = *(const short8v*)(Xs + (wr * 64 + mi * 16 + fr + kx) * 32 + fk);
#pragma unroll
                for (int ni = 0; ni < 4; ++ni)
                    b[ni] = *(const short8v*)(Ys + kx * 4096 + (wc * 64 + ni * 16 + fr) * 32 + fk);
#pragma unroll
                for (int mi = 0; mi < 4; ++mi)
#pragma unroll
                    for (int ni = 0; ni < 4; ++ni)
                        acc[mi][ni] = __builtin_amdgcn_mfma_f32_16x16x32_bf16(
                            a[mi], b[ni], acc[mi][ni], 0, 0, 0);
            }
            __syncthreads();
        }
    }

    const int fv = (ln >> 4) * 4;
    if constexpr (!FUSE_LN) {
#pragma unroll
        for (int mi = 0; mi < 4; ++mi)
#pragma unroll
            for (int ni = 0; ni < 4; ++ni)
#pragma unroll
                for (int v = 0; v < 4; ++v) {
                    const int px = m0 + wr * 64 + mi * 16 + fv + v;
                    const int co = n0 + wc * 64 + ni * 16 + fr;
                    if (co < COUT) {
                        float x = acc[mi][ni][v] + bias[co];
                        if (RELU) x = fmaxf(x, 0.f);
                        out[(long)px * OUTP + co] = f2bf(x);
                    } else if (co < OUTP) {
                        out[(long)px * OUTP + co] = 0;
                    }
                }
    } else {
        __shared__ float rmean[128], rinv[128], gs[100], bs[100];
        short* lnbuf = SMEM;  // [128][120] = 15360 shorts <= 16896
        __syncthreads();      // K-loop LDS reads complete
        if (tid < 100) { gs[tid] = lng[tid]; bs[tid] = lnbv[tid]; }
        // Phase A: t = bf16(conv+bias) + res (res read in coalesced 32B runs)
#pragma unroll
        for (int mi = 0; mi < 4; ++mi)
#pragma unroll
            for (int ni = 0; ni < 4; ++ni)
#pragma unroll
                for (int v = 0; v < 4; ++v) {
                    const int pl = wr * 64 + mi * 16 + fv + v;
                    const int co = wc * 64 + ni * 16 + fr;
                    if (co < 112) {
                        float t = 0.f;
                        if (co < COUT) {
                            const long gpx = (long)m0 + pl;
                            t = bf2f(f2bf(acc[mi][ni][v] + bias[co]))
                              + bf2f(res[gpx * 112 + co]);
                        }
                        lnbuf[pl * 120 + co] = f2bf(t);
                    }
                }
        __syncthreads();
        // Phase B: per-row stats from vectorized LDS reads
        if (tid < 128) {
            const short* lr = lnbuf + tid * 120;
            float s = 0.f, ss = 0.f;
#pragma unroll
            for (int q = 0; q < 13; ++q) {
                const short8v v8 = *(const short8v*)(lr + q * 8);
#pragma unroll
                for (int j = 0; j < 8; ++j) {
                    const int idx = q * 8 + j;
                    if (idx < 100) {
                        const float t = bf2f(v8[j]);
                        s += t; ss += t * t;
                    }
                }
            }
            const float mean = s * 0.01f;
            const float var = ss * 0.01f - mean * mean;
            rmean[tid] = mean;
            rinv[tid] = rsqrtf(var + 1e-5f);
        }
        __syncthreads();
        // Phase C: linear coalesced short8 output stream
        for (int c = tid; c < 128 * 14; c += 256) {
            const int row = c / 14, q = c - row * 14;
            const float mean = rmean[row], inv = rinv[row];
            const short8v v8 = *(const short8v*)(lnbuf + row * 120 + q * 8);
            short8v o;
#pragma unroll
            for (int j = 0; j < 8; ++j) {
                const int idx = q * 8 + j;
                o[j] = (idx < 100)
                    ? f2bf((bf2f(v8[j]) - mean) * inv * gs[idx] + bs[idx])
                    : (short)0;
            }
            *(short8v*)(out + ((long)m0 + row) * 112 + q * 8) = o;
        }
    }
}

// Edge path: gather 2044 border patches -> GEMM -> scatter (FUSE_LN for conv2).
template <int CINP, int CINW>
__global__ __launch_bounds__(256) void edge_gather(
    const short* __restrict__ img, short* __restrict__ EP)
{
    constexpr int KW = 9 * CINW;
    const int e = blockIdx.x;
    int y, x;
    bool real = true;
    if (e < 512)       { y = 0;   x = e; }
    else if (e < 1024) { y = 511; x = e - 512; }
    else if (e < 1534) { x = 0;   y = 1 + (e - 1024); }
    else if (e < 2044) { x = 511; y = 1 + (e - 1534); }
    else               { y = 0; x = 0; real = false; }

    const int tid = threadIdx.x;
    for (int idx = tid; idx < KW / 8; idx += 256) {
        const int tap = idx / (CINW / 8);
        const int c = (idx - tap * (CINW / 8)) * 8;
        short8v v = {0, 0, 0, 0, 0, 0, 0, 0};
        if (real && c < CINP) {
            const int yy = y + tap / 3 - 1, xx = x + tap % 3 - 1;
            if ((unsigned)yy < 512u && (unsigned)xx < 512u)
                v = *(const short8v*)(img + ((long)yy * 512 + xx) * CINP + c);
        }
        *(short8v*)(EP + (long)e * KW + idx * 8) = v;
    }
}

__device__ inline void edge_yx(int e, int& y, int& x) {
    if (e < 512)       { y = 0;   x = e; }
    else if (e < 1024) { y = 511; x = e - 512; }
    else if (e < 1534) { x = 0;   y = 1 + (e - 1024); }
    else               { x = 511; y = 1 + (e - 1534); }
}

template <int COUT, int OUTP, bool RELU, bool FUSE_LN>
__global__ __launch_bounds__(256) void conv_edge_gemm(
    const short* __restrict__ EP,
    const short* __restrict__ wflat,
    const float* __restrict__ bias,
    short* __restrict__ out, int K,
    const short* __restrict__ res,
    const float* __restrict__ lng,
    const float* __restrict__ lnbv)
{
    __shared__ short SMEM[128 * 120];  // >= 8192 staging; = lnbuf size
    short* Xs = SMEM;
    short* Ys = SMEM + 128 * 32;

    const int tid = threadIdx.x, wv = tid >> 6, ln = tid & 63;
    const int wr = wv >> 1, wc = wv & 1;
    const int m0 = blockIdx.x * 128, n0 = blockIdx.y * 128;

    f32x4 acc[4][4] = {};

    const int srow = ln >> 2;
    const int sk8 = ln & 3;
    const int fr = ln & 15, fk = (ln >> 4) * 8;

    for (int k0 = 0; k0 < K; k0 += 32) {
#pragma unroll
        for (int i = wv; i < 8; i += 4) {
            gload_lds16(EP + (long)(m0 + i * 16 + srow) * K + k0 + sk8 * 8,
                        Xs + i * 512);
            gload_lds16(wflat + (long)(n0 + i * 16 + srow) * K + k0 + sk8 * 8,
                        Ys + i * 512);
        }
        __syncthreads();
        short8v a[4], b[4];
#pragma unroll
        for (int mi = 0; mi < 4; ++mi)
            a[mi] = *(const short8v*)(Xs + (wr * 64 + mi * 16 + fr) * 32 + fk);
#pragma unroll
        for (int ni = 0; ni < 4; ++ni)
            b[ni] = *(const short8v*)(Ys + (wc * 64 + ni * 16 + fr) * 32 + fk);
#pragma unroll
        for (int mi = 0; mi < 4; ++mi)
#pragma unroll
            for (int ni = 0; ni < 4; ++ni)
                acc[mi][ni] = __builtin_amdgcn_mfma_f32_16x16x32_bf16(
                    a[mi], b[ni], acc[mi][ni], 0, 0, 0);
        __syncthreads();
    }

    const int fv = (ln >> 4) * 4;
    if constexpr (!FUSE_LN) {
#pragma unroll
        for (int mi = 0; mi < 4; ++mi)
#pragma unroll
            for (int ni = 0; ni < 4; ++ni)
#pragma unroll
                for (int v = 0; v < 4; ++v) {
                    const int e = m0 + wr * 64 + mi * 16 + fv + v;
                    const int co = n0 + wc * 64 + ni * 16 + fr;
                    if (e >= 2044 || co >= COUT) continue;
                    int y, x;
                    edge_yx(e, y, x);
                    float v2 = acc[mi][ni][v] + bias[co];
                    if (RELU) v2 = fmaxf(v2, 0.f);
                    out[((long)y * 512 + x) * OUTP + co] = f2bf(v2);
                }
    } else {
        __shared__ float rmean[128], rinv[128], gs[100], bs[100];
        short* lnbuf = SMEM;
        __syncthreads();
        if (tid < 100) { gs[tid] = lng[tid]; bs[tid] = lnbv[tid]; }
        // Phase A: t = bf16(conv+bias) + res
#pragma unroll
        for (int mi = 0; mi < 4; ++mi)
#pragma unroll
            for (int ni = 0; ni < 4; ++ni)
#pragma unroll
                for (int v = 0; v < 4; ++v) {
                    const int pl = wr * 64 + mi * 16 + fv + v;
                    const int co = wc * 64 + ni * 16 + fr;
                    if (co < 112) {
                        const int e = m0 + pl;
                        float t = 0.f;
                        if (co < COUT && e < 2044) {
                            int y, x;
                            edge_yx(e, y, x);
                            t = bf2f(f2bf(acc[mi][ni][v] + bias[co]))
                              + bf2f(res[((long)y * 512 + x) * 112 + co]);
                        }
                        lnbuf[pl * 120 + co] = f2bf(t);
                    }
                }
        __syncthreads();
        // Phase B: per-row stats
        if (tid < 128) {
            const short* lr = lnbuf + tid * 120;
            float s = 0.f, ss = 0.f;
#pragma unroll
            for (int q = 0; q < 13; ++q) {
                const short8v v8 = *(const short8v*)(lr + q * 8);
#pragma unroll
                for (int j = 0; j < 8; ++j) {
                    const int idx = q * 8 + j;
                    if (idx < 100) {
                        const float t = bf2f(v8[j]);
                        s += t; ss += t * t;
                    }
                }
            }
            const float mean = s * 0.01f;
            const float var = ss * 0.01f - mean * mean;
            rmean[tid] = mean;
            rinv[tid] = rsqrtf(var + 1e-5f);
        }
        __syncthreads();
        // Phase C: vectorized stores (rows scattered; 16B chunks per store)
        for (int c = tid; c < 128 * 14; c += 256) {
            const int row = c / 14, q = c - row * 14;
            const int e = m0 + row;
            if (e >= 2044) continue;
            int y, x;
            edge_yx(e, y, x);
            const float mean = rmean[row], inv = rinv[row];
            const short8v v8 = *(const short8v*)(lnbuf + row * 120 + q * 8);
            short8v o;
#pragma unroll
            for (int j = 0; j < 8; ++j) {
                const int idx = q * 8 + j;
                o[j] = (idx < 100)
                    ? f2bf((bf2f(v8[j]) - mean) * inv * gs[idx] + bs[idx])
                    : (short)0;
            }
            *(short8v*)(out + ((long)y * 512 + x) * 112 + q * 8) = o;
        }
    }
}

// ---------------------------------------------------------------------------
// Transposes / conversions
// ---------------------------------------------------------------------------
__global__ __launch_bounds__(256) void r_transpose(
    const float* __restrict__ R, short* __restrict__ Rt)
{
    __shared__ float Ts[64][65];
    const int tid = threadIdx.x;
    const long base = (long)blockIdx.z * 589824;
    const int d0 = blockIdx.y * 64, e0 = blockIdx.x * 64;
    const int c = tid & 63, rbase = tid >> 6;
#pragma unroll
    for (int j = 0; j < 16; ++j) {
        const int r = rbase + j * 4;
        Ts[r][c] = R[base + (long)(d0 + r) * 768 + e0 + c];
    }
    __syncthreads();
#pragma unroll
    for (int j = 0; j < 16; ++j) {
        const int e = rbase + j * 4;
        Rt[base + (long)(e0 + e) * 768 + d0 + c] = f2bf(Ts[c][e]);
    }
}

// mh_w{f,b}[l] [8][768][96] f32 -> WFBT [16][128][768] bf16 (o-major, padded).
__global__ __launch_bounds__(256) void wfb_transpose(
    const float* __restrict__ wf, const float* __restrict__ wb,
    short* __restrict__ dst)
{
    __shared__ float Ts[64][65];
    const int tid = threadIdx.x;
    const int z = blockIdx.z;
    const float* src = (z < 8) ? wf + (long)z * 73728 : wb + (long)(z - 8) * 73728;
    const int d0 = blockIdx.x * 64, o0 = blockIdx.y * 64;
    const int c = tid & 63, rbase = tid >> 6;
#pragma unroll
    for (int j = 0; j < 16; ++j) {
        const int r = rbase + j * 4;
        Ts[r][c] = (o0 + c < 96) ? src[(long)(d0 + r) * 96 + o0 + c] : 0.f;
    }
    __syncthreads();
#pragma unroll
    for (int j = 0; j < 16; ++j) {
        const int e = rbase + j * 4;
        dst[(long)z * 98304 + (long)(o0 + e) * 768 + d0 + c] = f2bf(Ts[c][e]);
    }
}

// Laplace-normalize bf16 Ahat (deterministic 2-partial rowsums) -> A and A^T.
__global__ __launch_bounds__(256) void a_laplace_t(
    const short* __restrict__ Ahat, const float* __restrict__ psum,
    short* __restrict__ ABF, short* __restrict__ ABFT)
{
    __shared__ float Ts[64][65];
    const int tid = threadIdx.x;
    const int r8 = blockIdx.z;
    const long ra = (long)r8 * 262144;
    const int i0 = blockIdx.y * 64, j0 = blockIdx.x * 64;
    const int c = tid & 63, rbase = tid >> 6;
    const float sj = psum[r8 * 1024 + (j0 + c) * 2] + psum[r8 * 1024 + (j0 + c) * 2 + 1];
    const float dj = rsqrtf(sj);
#pragma unroll
    for (int j = 0; j < 16; ++j) {
        const int r = rbase + j * 4;
        const float si = psum[r8 * 1024 + (i0 + r) * 2] + psum[r8 * 1024 + (i0 + r) * 2 + 1];
        const float di = rsqrtf(si);
        const float v = bf2f(Ahat[ra + (long)(i0 + r) * 512 + j0 + c]) * di * dj;
        Ts[r][c] = v;
        ABF[ra + (long)(i0 + r) * 512 + j0 + c] = f2bf(v);
    }
    __syncthreads();
#pragma unroll
    for (int j = 0; j < 16; ++j) {
        const int e = rbase + j * 4;
        ABFT[ra + (long)(j0 + e) * 512 + i0 + c] = f2bf(Ts[c][e]);
    }
}

// e[m][r*96+o] = bf16(relu(O1[r][m][o] + O2[r][m][o] + mh_b[r*96+o]))
__global__ __launch_bounds__(256) void gcn_combine(
    const short* __restrict__ O1, const short* __restrict__ O2,
    const float* __restrict__ mhb, short* __restrict__ e)
{
    const int idx = blockIdx.x * 256 + threadIdx.x;  // 393216
    const int m = idx / 768, c = idx - m * 768;
    const int r = c / 96, o = c - r * 96;
    const long oi = (long)r * 65536 + (long)m * 128 + o;
    float v = bf2f(O1[oi]) + bf2f(O2[oi]) + mhb[c];
    e[idx] = f2bf(fmaxf(v, 0.f));
}

// ---------------------------------------------------------------------------
// Channel-major -> pixel-major transpose of the rel tensor, full-channel
// blocks (64 px x 112 ch in LDS). DO_LN=true additionally applies the
// channel-LN against `res` (layer-1 rel_ln), eliminating the ln_pix pass.
// Output written as a fully linear coalesced short8 stream.
// ---------------------------------------------------------------------------
template <bool DO_LN>
__global__ __launch_bounds__(256) void rel_transpose_ln(
    const short* __restrict__ relc,   // [100][512][512]
    short* __restrict__ relp,         // [262144][112]
    const short* __restrict__ res,    // [262144][112] (DO_LN only)
    const float* __restrict__ g, const float* __restrict__ b)
{
    __shared__ short Ts[64][112];
    __shared__ float rmean[64], rinv[64], gs[100], bs[100];
    const int tid = threadIdx.x;
    const long p0 = (long)blockIdx.x * 64;

    if (DO_LN && tid < 100) { gs[tid] = g[tid]; bs[tid] = b[tid]; }

    const int ch = tid >> 3, pxo = (tid & 7) * 8;
#pragma unroll
    for (int r0 = 0; r0 < 128; r0 += 32) {
        const int c = r0 + ch;
        short8v v = {0, 0, 0, 0, 0, 0, 0, 0};
        if (c < 100)
            v = *(const short8v*)(relc + (long)c * NNpix + p0 + pxo);
        if (c < 112)
#pragma unroll
            for (int j = 0; j < 8; ++j) Ts[pxo + j][c] = v[j];
    }
    __syncthreads();

    if constexpr (DO_LN) {
        // t = bf16(rel) + bf16(res), staged back to LDS as bf16
        for (int cix = tid; cix < 64 * 14; cix += 256) {
            const int row = cix / 14, q = cix - row * 14;
            short8v tv = *(const short8v*)(&Ts[row][q * 8]);
            const short8v rv = *(const short8v*)(res + (p0 + row) * 112 + q * 8);
#pragma unroll
            for (int j = 0; j < 8; ++j) {
                const int idx = q * 8 + j;
                const float t = (idx < 100) ? bf2f(tv[j]) + bf2f(rv[j]) : 0.f;
                tv[j] = f2bf(t);
            }
            *(short8v*)(&Ts[row][q * 8]) = tv;
        }
        __syncthreads();
        if (tid < 64) {
            float s = 0.f, ss = 0.f;
#pragma unroll
            for (int q = 0; q < 13; ++q) {
                const short8v v8 = *(const short8v*)(&Ts[tid][q * 8]);
#pragma unroll
                for (int j = 0; j < 8; ++j) {
                    const int idx = q * 8 + j;
                    if (idx < 100) {
                        const float t = bf2f(v8[j]);
                        s += t; ss += t * t;
                    }
                }
            }
            const float mean = s * 0.01f;
            rmean[tid] = mean;
            rinv[tid] = rsqrtf(ss * 0.01f - mean * mean + 1e-5f);
        }
        __syncthreads();
    }

    for (int cix = tid; cix < 64 * 14; cix += 256) {
        const int row = cix / 14, q = cix - row * 14;
        short8v v8 = *(const short8v*)(&Ts[row][q * 8]);
        if constexpr (DO_LN) {
            const float mean = rmean[row], inv = rinv[row];
            short8v o;
#pragma unroll
            for (int j = 0; j < 8; ++j) {
                const int idx = q * 8 + j;
                o[j] = (idx < 100)
                    ? f2bf((bf2f(v8[j]) - mean) * inv * gs[idx] + bs[idx])
                    : (short)0;
            }
            v8 = o;
        }
        *(short8v*)(relp + (p0 + row) * 112 + q * 8) = v8;
    }
}

__global__ __launch_bounds__(256) void conv_w_flat(
    const float* __restrict__ src, short* __restrict__ dst,
    int COUT, int CIN, int COUTP, int CINW)
{
    const int idx = blockIdx.x * 256 + threadIdx.x;
    const int KW = 9 * CINW;
    const int total = COUTP * KW;
    if (idx >= total) return;
    const int co = idx / KW;
    const int rem = idx - co * KW;
    const int tap = rem / CINW, ci = rem - tap * CINW;
    short v = 0;
    if (co < COUT && ci < CIN)
        v = f2bf(src[((long)co * CIN + ci) * 9 + tap]);
    dst[idx] = v;
}

__global__ __launch_bounds__(256) void f32_to_bf16k(
    const float* __restrict__ src, short* __restrict__ dst, long n)
{
    const long i = (long)blockIdx.x * 256 + threadIdx.x;
    if (i < n) dst[i] = f2bf(src[i]);
}

// ---------------------------------------------------------------------------
// softmax over 8 relation logits + bf16 A_hat + deterministic rowsum partials
// ---------------------------------------------------------------------------
__global__ __launch_bounds__(256) void rel_softmax_laplace(
    const short* __restrict__ relp,
    const float* __restrict__ w,
    const float* __restrict__ bvec,
    short* __restrict__ Ahat,
    float* __restrict__ psum)
{
    __shared__ float ws[800];
    __shared__ float wred[8][4];
    const int tid = threadIdx.x;
    for (int i = tid; i < 800; i += 256) ws[i] = w[i];
    __syncthreads();

    const int i = blockIdx.y;
    const int j = blockIdx.x * 256 + tid;
    const long p = (long)i * 512 + j;
    const short* row = relp + p * 112;

    float acc[8];
#pragma unroll
    for (int r8 = 0; r8 < 8; ++r8) acc[r8] = bvec[r8];
#pragma unroll
    for (int q = 0; q < 13; ++q) {
        const short8v v = *(const short8v*)(row + q * 8);
#pragma unroll
        for (int jj = 0; jj < 8; ++jj) {
            const int r = q * 8 + jj;
            if (r < 100) {
                const float x = bf2f(v[jj]);
#pragma unroll
                for (int r8 = 0; r8 < 8; ++r8)
                    acc[r8] = fmaf(x, ws[r8 * 100 + r], acc[r8]);
            }
        }
    }
    float m = acc[0];
#pragma unroll
    for (int r8 = 1; r8 < 8; ++r8) m = fmaxf(m, acc[r8]);
    float s = 0.f;
#pragma unroll
    for (int r8 = 0; r8 < 8; ++r8) { acc[r8] = expf(acc[r8] - m); s += acc[r8]; }
    const float inv = 1.f / s;
#pragma unroll
    for (int r8 = 0; r8 < 8; ++r8) {
        const float a = acc[r8] * inv + (i == j ? 1.f : 0.f);
        acc[r8] = a;
        Ahat[(long)r8 * NNpix + p] = f2bf(a);
    }
    const int lane = tid & 63, wvv = tid >> 6;
#pragma unroll
    for (int r8 = 0; r8 < 8; ++r8) {
        float v = acc[r8];
        for (int off = 32; off > 0; off >>= 1) v += __shfl_down(v, off);
        if (lane == 0) wred[r8][wvv] = v;
    }
    __syncthreads();
    if (tid < 8) {
        const float v = wred[tid][0] + wred[tid][1] + wred[tid][2] + wred[tid][3];
        psum[tid * 1024 + i * 2 + blockIdx.x] = v;
    }
}

// Row LN over D=768 with fused bf16 emit of the normalized ents.
__global__ __launch_bounds__(256) void ln_row768(
    const float* __restrict__ x, const float* __restrict__ res,
    const float* __restrict__ g, const float* __restrict__ b,
    float* __restrict__ outf, short* __restrict__ outbf)
{
    const int n = blockIdx.x;
    const int tid = threadIdx.x;
    float v[3];
    float s = 0.f, ss = 0.f;
#pragma unroll
    for (int i = 0; i < 3; ++i) {
        const int c = tid + 256 * i;
        v[i] = x[(long)n * 768 + c] + res[(long)n * 768 + c];
        s += v[i]; ss += v[i] * v[i];
    }
    const int lane = tid & 63, wv = tid >> 6;
    for (int off = 32; off > 0; off >>= 1) {
        s += __shfl_down(s, off);
        ss += __shfl_down(ss, off);
    }
    __shared__ float rs[4], rss[4];
    if (lane == 0) { rs[wv] = s; rss[wv] = ss; }
    __syncthreads();
    s = rs[0] + rs[1] + rs[2] + rs[3];
    ss = rss[0] + rss[1] + rss[2] + rss[3];
    const float mean = s * (1.f / 768.f);
    const float var = ss * (1.f / 768.f) - mean * mean;
    const float inv = rsqrtf(var + 1e-5f);
#pragma unroll
    for (int i = 0; i < 3; ++i) {
        const int c = tid + 256 * i;
        const float o = (v[i] - mean) * inv * g[c] + b[c];
        outf[(long)n * 768 + c] = o;
        outbf[(long)n * 768 + c] = f2bf(o);
    }
}

__global__ __launch_bounds__(256) void final_rels(
    const short* __restrict__ relp, const float* __restrict__ w,
    const float* __restrict__ bvec, float* __restrict__ out)
{
    __shared__ float ws[800];
    const int tid = threadIdx.x;
    for (int i = tid; i < 800; i += 256) ws[i] = w[i];
    __syncthreads();
    const long p = (long)blockIdx.x * 256 + tid;
    const short* row = relp + p * 112;
    float acc[8];
#pragma unroll
    for (int r8 = 0; r8 < 8; ++r8) acc[r8] = bvec[r8];
#pragma unroll
    for (int q = 0; q < 13; ++q) {
        const short8v v = *(const short8v*)(row + q * 8);
#pragma unroll
        for (int jj = 0; jj < 8; ++jj) {
            const int r = q * 8 + jj;
            if (r < 100) {
                const float x = bf2f(v[jj]);
#pragma unroll
                for (int r8 = 0; r8 < 8; ++r8)
                    acc[r8] = fmaf(x, ws[r8 * 100 + r], acc[r8]);
            }
        }
    }
#pragma unroll
    for (int r8 = 0; r8 < 8; ++r8) out[p * 8 + r8] = acc[r8];
}

__global__ __launch_bounds__(256) void zero_f32(float* __restrict__ p, long n)
{
    const long i = (long)blockIdx.x * 256 + threadIdx.x;
    if (i < n) p[i] = 0.f;
}

// ---------------------------------------------------------------------------
extern "C" void kernel_launch(void* const* d_in, const int* in_sizes, int n_in,
                              void* d_out, int out_size, void* d_ws, size_t ws_size,
                              hipStream_t stream)
{
    (void)in_sizes; (void)n_in; (void)out_size; (void)ws_size;

    const float* ents_in   = (const float*)d_in[0];
    const float* R_local   = (const float*)d_in[1];
    const float* rel_mlp_w = (const float*)d_in[2];
    const float* rel_mlp_b = (const float*)d_in[3];
    const float* conv1_w   = (const float*)d_in[4];
    const float* conv1_b   = (const float*)d_in[5];
    const float* conv2_w   = (const float*)d_in[6];
    const float* conv2_b   = (const float*)d_in[7];
    const float* pffn_g    = (const float*)d_in[8];
    const float* pffn_b    = (const float*)d_in[9];
    const float* rln_g     = (const float*)d_in[10];
    const float* rln_b     = (const float*)d_in[11];
    const float* mh_wf     = (const float*)d_in[12];
    const float* mh_wb     = (const float*)d_in[13];
    const float* mh_b      = (const float*)d_in[14];
    const float* emlp_w    = (const float*)d_in[15];
    const float* emlp_b    = (const float*)d_in[16];
    const float* eln_g     = (const float*)d_in[17];
    const float* eln_b     = (const float*)d_in[18];
    float* out = (float*)d_out;

    // ---- workspace layout (1 KiB aligned) ----
    char* base = (char*)d_ws;
    size_t off = 0;
    auto alloc = [&](size_t bytes) {
        char* p = base + off;
        off += (bytes + 1023) & ~(size_t)1023;
        return p;
    };
    char* U1 = alloc(117964800 + 4096);              // RTL / H1T union
    short* RTL = (short*)U1;                         // [100][768][768] bf16
    short* H1T = (short*)U1;                         // [262144][208] bf16
    char* U2 = alloc(78643200 + 4096);               // TB union
    short* TB  = (short*)U2;                         // [100][512][768] bf16
    short* RELC   = (short*)alloc(52428800 + 4096);  // [100][512][512] bf16
    short* RELP_A = (short*)alloc(58720256 + 4096);  // [262144][112] bf16
    short* RELP_B = (short*)alloc(58720256 + 4096);
    short* RELP_C = (short*)alloc(58720256 + 4096);  // fused-LN output (l0)
    short* W1P = (short*)alloc(294912 * 2);          // [256][9*128] bf16
    short* W2P = (short*)alloc(258048 * 2);          // [128][9*224] bf16
    short* EPB = (short*)alloc(2048L * 2016 * 2 + 4096); // edge patch matrix
    // ---- TAIL region: zeroed at the start of EVERY call ----
    const size_t tail0 = off;
    short* EBF  = (short*)alloc(393216L * 2);        // ents bf16 [512][768]
    short* ABUF = (short*)alloc(2097152L * 2);       // Ahat bf16 [8][512][512]
    float* PSUM = (float*)alloc(8192L * 4);          // [8][512][2] partials
    short* ABF  = (short*)alloc(2097152L * 2);       // A bf16
    short* ABFT = (short*)alloc(2097152L * 2);       // A^T bf16 (contig)
    short* WFBT = (short*)alloc(1572864L * 2);       // [16][128][768] bf16
    short* HFBT = (short*)alloc(1048576L * 2);       // [16][128][512] bf16
    short* O1B  = (short*)alloc(524288L * 2);        // [8][512][128] bf16
    short* O2B  = (short*)alloc(524288L * 2);        // (contig after O1B)
    short* EB2  = (short*)alloc(393216L * 2);        // e bf16 [512][768]
    short* EWB  = (short*)alloc(589824L * 2);        // emlp_w bf16 [768][768]
    float* E2   = (float*)alloc(393216L * 4);
    float* ENTS1 = (float*)alloc(393216L * 4);       // layer-0 output ents
    const long tailN = (long)((off - tail0) / 4);
    (void)O2B;

    zero_f32<<<(int)((tailN + 255) / 256), 256, 0, stream>>>(
        (float*)(base + tail0), tailN);

    for (int l = 0; l < 2; ++l) {
        // RELP_res: pre-posFFN rel tensor (residual). RELP_out: post-LN rel.
        short* RELP_res = (l == 0) ? RELP_A : RELP_B;
        short* RELP_out = (l == 0) ? RELP_C : RELP_A;
        const float* ents_cur = (l == 0) ? ents_in : ENTS1;
        float* ents_next = (l == 0) ? ENTS1 : out;

        if (l == 0)
            f32_to_bf16k<<<1536, 256, 0, stream>>>(ents_in, EBF, 393216);

        r_transpose<<<dim3(12, 12, 100), 256, 0, stream>>>(
            R_local + (long)l * 58982400, RTL);

        // t[r] = ents @ R[r] ; rel[r] = relu(t[r] @ ents^T)
        bgemm_xyt<false><<<dim3(6, 4, 100), 256, 0, stream>>>(
            EBF, 0, RTL, 589824L, TB, 393216L, 512, 768, 768);
        bgemm_xyt<true><<<dim3(4, 4, 100), 256, 0, stream>>>(
            TB, 393216L, EBF, 0, RELC, 262144L, 512, 512, 768);
        // transpose to pixel-major; l1 fuses the rel_ln against RELP_C
        if (l == 0)
            rel_transpose_ln<false><<<4096, 256, 0, stream>>>(
                RELC, RELP_res, nullptr, nullptr, nullptr);
        else
            rel_transpose_ln<true><<<4096, 256, 0, stream>>>(
                RELC, RELP_res, RELP_C, rln_g + 100, rln_b + 100);

        // posFFN convs: ky-slab MFMA main pass (XCD-swizzled) + edge fix;
        // conv2 (main + edge) fuses the channel-LN, writing RELP_out.
        conv_w_flat<<<1152, 256, 0, stream>>>(
            conv1_w + (long)l * 180000, W1P, 200, 100, 256, 128);
        conv_w_flat<<<1008, 256, 0, stream>>>(
            conv2_w + (long)l * 180000, W2P, 100, 200, 128, 224);

        conv_gemm<112, 128, 200, 208, true, false>
            <<<dim3(2048, 2), 256, 0, stream>>>(
            RELP_res, W1P, conv1_b + l * 200, H1T, nullptr, nullptr, nullptr);
        edge_gather<112, 128><<<2048, 256, 0, stream>>>(RELP_res, EPB);
        conv_edge_gemm<200, 208, true, false>
            <<<dim3(16, 2), 256, 0, stream>>>(
            EPB, W1P, conv1_b + l * 200, H1T, 1152, nullptr, nullptr, nullptr);

        conv_gemm<208, 224, 100, 112, false, true>
            <<<dim3(2048, 1), 256, 0, stream>>>(
            H1T, W2P, conv2_b + l * 100, RELP_out,
            RELP_res, pffn_g + l * 100, pffn_b + l * 100);
        edge_gather<208, 224><<<2048, 256, 0, stream>>>(H1T, EPB);
        conv_edge_gemm<100, 112, false, true>
            <<<dim3(16, 1), 256, 0, stream>>>(
            EPB, W2P, conv2_b + l * 100, RELP_out, 2016,
            RELP_res, pffn_g + l * 100, pffn_b + l * 100);

        // softmax + deterministic rowsum partials; Laplace into bf16 A, A^T
        rel_softmax_laplace<<<dim3(2, 512), 256, 0, stream>>>(
            RELP_out, rel_mlp_w, rel_mlp_b, ABUF, PSUM);
        a_laplace_t<<<dim3(8, 8, 8), 256, 0, stream>>>(ABUF, PSUM, ABF, ABFT);

        // GCN via MFMA: HFT/HBT = h^T; merged O-GEMM (z<8: A.hf, z>=8: A^T.hb)
        wfb_transpose<<<dim3(12, 2, 16), 256, 0, stream>>>(
            mh_wf + (long)l * 589824, mh_wb + (long)l * 589824, WFBT);
        bgemm_xyt<false><<<dim3(4, 1, 16), 256, 0, stream>>>(
            WFBT, 98304L, EBF, 0, HFBT, 65536L, 128, 512, 768);
        bgemm_xyt<false><<<dim3(1, 4, 16), 256, 0, stream>>>(
            ABF, 262144L, HFBT, 65536L, O1B, 65536L, 512, 128, 512);
        gcn_combine<<<1536, 256, 0, stream>>>(O1B, O1B + 8L * 65536,
                                              mh_b + l * 768, EB2);

        // ent_mlp (MFMA) + residual LN (out-of-place; fused bf16 emit)
        f32_to_bf16k<<<2304, 256, 0, stream>>>(
            emlp_w + (long)l * 589824, EWB, 589824);
        bgemm_bias_f32<<<dim3(6, 4), 256, 0, stream>>>(
            EB2, EWB, E2, emlp_b + l * 768, 512, 768, 768);
        ln_row768<<<512, 256, 0, stream>>>(E2, ents_cur,
            eln_g + l * 768, eln_b + l * 768, ents_next, EBF);
    }

    // layer-1 final rels live in RELP_A (RELP_out of l=1)
    final_rels<<<1024, 256, 0, stream>>>(RELP_A, rel_mlp_w, rel_mlp_b, out + 393216);
}

// Round 18
// 1688.176 us; speedup vs baseline: 1.3014x; 1.0131x over previous
//
#include <hip/hip_runtime.h>
#include <hip/hip_bf16.h>

// DecoderIGCN forward. Round 18: final_rels fused into layer-1's
// rel_softmax_laplace (the softmax kernel already computes the exact logits;
// stage them in LDS and stream linearly to d_out — kills a 58.7MB re-read
// pass and final_rels' 8x write amplification). Rest identical to round 17.
// N=512, D=768, RDIM=100, R=8, L=2.

static constexpr long NNpix = 512L * 512L; // 262144

typedef __attribute__((ext_vector_type(8))) short short8v;
typedef __attribute__((ext_vector_type(4))) float f32x4;

__device__ inline float bf2f(short s) {
    unsigned u = ((unsigned)(unsigned short)s) << 16;
    float f; __builtin_memcpy(&f, &u, 4);
    return f;
}
__device__ inline short f2bf(float f) {
    unsigned u; __builtin_memcpy(&u, &f, 4);
    u += 0x7fff + ((u >> 16) & 1);   // RNE
    return (short)(u >> 16);
}
__device__ inline void gload_lds16(const short* g, short* l) {
    __builtin_amdgcn_global_load_lds(
        (const __attribute__((address_space(1))) unsigned int*)g,
        (__attribute__((address_space(3))) unsigned int*)l, 16, 0, 0);
}

// Bijective XCD swizzle of the flattened block index (requires total%8==0;
// identity otherwise). Consecutive swizzled ids share an XCD's L2.
__device__ inline void xcd_block3(int& bx, int& by, int& bz) {
    const long gx = gridDim.x, gy = gridDim.y;
    const long total = gx * gy * (long)gridDim.z;
    long lin = blockIdx.x + gx * (blockIdx.y + gy * (long)blockIdx.z);
    if ((total & 7) == 0)
        lin = (lin & 7) * (total >> 3) + (lin >> 3);
    const long gxy = gx * gy;
    bz = (int)(lin / gxy);
    const int rem = (int)(lin - (long)bz * gxy);
    by = rem / (int)gx;
    bx = rem - by * (int)gx;
}

// ---------------------------------------------------------------------------
// bf16 MFMA GEMM: D[M][N] = (relu?)(X[M][K] . Y[N][K]^T), all bf16 (shorts).
// 128x128 tile, BK=32, 256 threads (4 waves, 2x2), 16x16x32 MFMA.
// ---------------------------------------------------------------------------
template <bool RELU>
__global__ __launch_bounds__(256) void bgemm_xyt(
    const short* __restrict__ X, long sX,
    const short* __restrict__ Y, long sY,
    short* __restrict__ D, long sD,
    int M, int N, int K)
{
    int bx, by, bz;
    xcd_block3(bx, by, bz);
    X += (long)bz * sX;
    Y += (long)bz * sY;
    D += (long)bz * sD;

    __shared__ short Xs[128 * 32];
    __shared__ short Ys[128 * 32];

    const int tid = threadIdx.x, wv = tid >> 6, ln = tid & 63;
    const int wr = wv >> 1, wc = wv & 1;
    const int m0 = by * 128, n0 = bx * 128;

    f32x4 acc[4][4] = {};

    const int srow = ln >> 2;
    const int sk8 = ln & 3;
    const int fr = ln & 15, fk = (ln >> 4) * 8;

    for (int k0 = 0; k0 < K; k0 += 32) {
#pragma unroll
        for (int i = wv; i < 8; i += 4) {
            gload_lds16(X + (long)(m0 + i * 16 + srow) * K + k0 + sk8 * 8,
                        Xs + i * 512);
            gload_lds16(Y + (long)(n0 + i * 16 + srow) * K + k0 + sk8 * 8,
                        Ys + i * 512);
        }
        __syncthreads();
        short8v a[4], b[4];
#pragma unroll
        for (int mi = 0; mi < 4; ++mi)
            a[mi] = *(const short8v*)(Xs + (wr * 64 + mi * 16 + fr) * 32 + fk);
#pragma unroll
        for (int ni = 0; ni < 4; ++ni)
            b[ni] = *(const short8v*)(Ys + (wc * 64 + ni * 16 + fr) * 32 + fk);
#pragma unroll
        for (int mi = 0; mi < 4; ++mi)
#pragma unroll
            for (int ni = 0; ni < 4; ++ni)
                acc[mi][ni] = __builtin_amdgcn_mfma_f32_16x16x32_bf16(
                    a[mi], b[ni], acc[mi][ni], 0, 0, 0);
        __syncthreads();
    }

    const int fv = (ln >> 4) * 4;
#pragma unroll
    for (int mi = 0; mi < 4; ++mi)
#pragma unroll
        for (int ni = 0; ni < 4; ++ni)
#pragma unroll
            for (int v = 0; v < 4; ++v) {
                const int row = m0 + wr * 64 + mi * 16 + fv + v;
                const int col = n0 + wc * 64 + ni * 16 + fr;
                float x = acc[mi][ni][v];
                if (RELU) x = fmaxf(x, 0.f);
                D[(long)row * N + col] = f2bf(x);
            }
}

// Same GEMM, fp32 output + per-column bias (for emlp).
__global__ __launch_bounds__(256) void bgemm_bias_f32(
    const short* __restrict__ X,
    const short* __restrict__ Y,
    float* __restrict__ D,
    const float* __restrict__ bias,
    int M, int N, int K)
{
    int bx, by, bz;
    xcd_block3(bx, by, bz);
    (void)bz;

    __shared__ short Xs[128 * 32];
    __shared__ short Ys[128 * 32];

    const int tid = threadIdx.x, wv = tid >> 6, ln = tid & 63;
    const int wr = wv >> 1, wc = wv & 1;
    const int m0 = by * 128, n0 = bx * 128;

    f32x4 acc[4][4] = {};

    const int srow = ln >> 2;
    const int sk8 = ln & 3;
    const int fr = ln & 15, fk = (ln >> 4) * 8;

    for (int k0 = 0; k0 < K; k0 += 32) {
#pragma unroll
        for (int i = wv; i < 8; i += 4) {
            gload_lds16(X + (long)(m0 + i * 16 + srow) * K + k0 + sk8 * 8,
                        Xs + i * 512);
            gload_lds16(Y + (long)(n0 + i * 16 + srow) * K + k0 + sk8 * 8,
                        Ys + i * 512);
        }
        __syncthreads();
        short8v a[4], b[4];
#pragma unroll
        for (int mi = 0; mi < 4; ++mi)
            a[mi] = *(const short8v*)(Xs + (wr * 64 + mi * 16 + fr) * 32 + fk);
#pragma unroll
        for (int ni = 0; ni < 4; ++ni)
            b[ni] = *(const short8v*)(Ys + (wc * 64 + ni * 16 + fr) * 32 + fk);
#pragma unroll
        for (int mi = 0; mi < 4; ++mi)
#pragma unroll
            for (int ni = 0; ni < 4; ++ni)
                acc[mi][ni] = __builtin_amdgcn_mfma_f32_16x16x32_bf16(
                    a[mi], b[ni], acc[mi][ni], 0, 0, 0);
        __syncthreads();
    }

    const int fv = (ln >> 4) * 4;
#pragma unroll
    for (int mi = 0; mi < 4; ++mi)
#pragma unroll
        for (int ni = 0; ni < 4; ++ni)
#pragma unroll
            for (int v = 0; v < 4; ++v) {
                const int row = m0 + wr * 64 + mi * 16 + fv + v;
                const int col = n0 + wc * 64 + ni * 16 + fr;
                D[(long)row * N + col] = acc[mi][ni][v] + bias[col];
            }
}

// ---------------------------------------------------------------------------
// conv3x3 main pass (ky-slab, 4 waves, XCD m-swizzle). FUSE_LN=true (conv2,
// gridDim.y==1): stage t = bf16(conv+bias)+res in LDS [128][120], per-row
// stats (vector LDS reads), then a linear coalesced short8 output stream.
// ---------------------------------------------------------------------------
template <int CINP, int CINW, int COUT, int OUTP, bool RELU, bool FUSE_LN>
__global__ __launch_bounds__(256) void conv_gemm(
    const short* __restrict__ img,
    const short* __restrict__ wflat,
    const float* __restrict__ bias,
    short* __restrict__ out,
    const short* __restrict__ res,
    const float* __restrict__ lng,
    const float* __restrict__ lnbv)
{
    constexpr int NCH = CINW / 32;
    constexpr int KW = 9 * CINW;

    __shared__ short SMEM[144 * 32 + 3 * 128 * 32];  // 16896 >= 128*120 lnbuf
    short* Xs = SMEM;
    short* Ys = SMEM + 144 * 32;

    const int tid = threadIdx.x, wv = tid >> 6, ln = tid & 63;
    const int wr = wv >> 1, wc = wv & 1;
    const int bx = blockIdx.x;
    const int bsw = (bx & 7) * ((int)gridDim.x >> 3) + (bx >> 3);
    const int m0 = bsw * 128;
    const int n0 = blockIdx.y * 128;

    f32x4 acc[4][4] = {};

    const int srow = ln >> 2;
    const int sk8 = ln & 3;
    const int fr = ln & 15, fk = (ln >> 4) * 8;

    for (int ky = 0; ky < 3; ++ky) {
        const int slab0 = m0 + (ky - 1) * 512 - 1;
        for (int cc = 0; cc < NCH; ++cc) {
            const int ci0 = cc * 32;
#pragma unroll
            for (int i = wv; i < 9; i += 4) {
                int rpx = slab0 + i * 16 + srow;
                rpx = rpx < 0 ? 0 : (rpx > (int)NNpix - 1 ? (int)NNpix - 1 : rpx);
                gload_lds16(img + (long)rpx * CINP + ci0 + sk8 * 8,
                            Xs + i * 512);
            }
#pragma unroll
            for (int kx = 0; kx < 3; ++kx) {
                const int wbase = (ky * 3 + kx) * CINW;
#pragma unroll
                for (int i = wv; i < 8; i += 4)
                    gload_lds16(wflat + (long)(n0 + i * 16 + srow) * KW + wbase + ci0 + sk8 * 8,
                                Ys + kx * 4096 + i * 512);
            }
            __syncthreads();
#pragma unroll
            for (int kx = 0; kx < 3; ++kx) {
                short8v a[4], b[4];
#pragma unroll
                for (int mi = 0; mi < 4; ++mi)
                    a[mi] = *(const short8v*)(Xs + (wr * 64 + mi * 16 + fr + kx) * 32 + fk);
#pragma unroll
                for (int ni = 0; ni < 4; ++ni)
                    b[ni] = *(const short8v*)(Ys + kx * 4096 + (wc * 64 + ni * 16 + fr) * 32 + fk);
#pragma unroll
                for (int mi = 0; mi < 4; ++mi)
#pragma unroll
                    for (int ni = 0; ni < 4; ++ni)
                        acc[mi][ni] = __builtin_amdgcn_mfma_f32_16x16x32_bf16(
                            a[mi], b[ni], acc[mi][ni], 0, 0, 0);
            }
            __syncthreads();
        }
    }

    const int fv = (ln >> 4) * 4;
    if constexpr (!FUSE_LN) {
#pragma unroll
        for (int mi = 0; mi < 4; ++mi)
#pragma unroll
            for (int ni = 0; ni < 4; ++ni)
#pragma unroll
                for (int v = 0; v < 4; ++v) {
                    const int px = m0 + wr * 64 + mi * 16 + fv + v;
                    const int co = n0 + wc * 64 + ni * 16 + fr;
                    if (co < COUT) {
                        float x = acc[mi][ni][v] + bias[co];
                        if (RELU) x = fmaxf(x, 0.f);
                        out[(long)px * OUTP + co] = f2bf(x);
                    } else if (co < OUTP) {
                        out[(long)px * OUTP + co] = 0;
                    }
                }
    } else {
        __shared__ float rmean[128], rinv[128], gs[100], bs[100];
        short* lnbuf = SMEM;  // [128][120] = 15360 shorts <= 16896
        __syncthreads();      // K-loop LDS reads complete
        if (tid < 100) { gs[tid] = lng[tid]; bs[tid] = lnbv[tid]; }
        // Phase A: t = bf16(conv+bias) + res
#pragma unroll
        for (int mi = 0; mi < 4; ++mi)
#pragma unroll
            for (int ni = 0; ni < 4; ++ni)
#pragma unroll
                for (int v = 0; v < 4; ++v) {
                    const int pl = wr * 64 + mi * 16 + fv + v;
                    const int co = wc * 64 + ni * 16 + fr;
                    if (co < 112) {
                        float t = 0.f;
                        if (co < COUT) {
                            const long gpx = (long)m0 + pl;
                            t = bf2f(f2bf(acc[mi][ni][v] + bias[co]))
                              + bf2f(res[gpx * 112 + co]);
                        }
                        lnbuf[pl * 120 + co] = f2bf(t);
                    }
                }
        __syncthreads();
        // Phase B: per-row stats from vectorized LDS reads
        if (tid < 128) {
            const short* lr = lnbuf + tid * 120;
            float s = 0.f, ss = 0.f;
#pragma unroll
            for (int q = 0; q < 13; ++q) {
                const short8v v8 = *(const short8v*)(lr + q * 8);
#pragma unroll
                for (int j = 0; j < 8; ++j) {
                    const int idx = q * 8 + j;
                    if (idx < 100) {
                        const float t = bf2f(v8[j]);
                        s += t; ss += t * t;
                    }
                }
            }
            const float mean = s * 0.01f;
            const float var = ss * 0.01f - mean * mean;
            rmean[tid] = mean;
            rinv[tid] = rsqrtf(var + 1e-5f);
        }
        __syncthreads();
        // Phase C: linear coalesced short8 output stream
        for (int c = tid; c < 128 * 14; c += 256) {
            const int row = c / 14, q = c - row * 14;
            const float mean = rmean[row], inv = rinv[row];
            const short8v v8 = *(const short8v*)(lnbuf + row * 120 + q * 8);
            short8v o;
#pragma unroll
            for (int j = 0; j < 8; ++j) {
                const int idx = q * 8 + j;
                o[j] = (idx < 100)
                    ? f2bf((bf2f(v8[j]) - mean) * inv * gs[idx] + bs[idx])
                    : (short)0;
            }
            *(short8v*)(out + ((long)m0 + row) * 112 + q * 8) = o;
        }
    }
}

// Edge path: gather 2044 border patches -> GEMM -> scatter (FUSE_LN for conv2).
template <int CINP, int CINW>
__global__ __launch_bounds__(256) void edge_gather(
    const short* __restrict__ img, short* __restrict__ EP)
{
    constexpr int KW = 9 * CINW;
    const int e = blockIdx.x;
    int y, x;
    bool real = true;
    if (e < 512)       { y = 0;   x = e; }
    else if (e < 1024) { y = 511; x = e - 512; }
    else if (e < 1534) { x = 0;   y = 1 + (e - 1024); }
    else if (e < 2044) { x = 511; y = 1 + (e - 1534); }
    else               { y = 0; x = 0; real = false; }

    const int tid = threadIdx.x;
    for (int idx = tid; idx < KW / 8; idx += 256) {
        const int tap = idx / (CINW / 8);
        const int c = (idx - tap * (CINW / 8)) * 8;
        short8v v = {0, 0, 0, 0, 0, 0, 0, 0};
        if (real && c < CINP) {
            const int yy = y + tap / 3 - 1, xx = x + tap % 3 - 1;
            if ((unsigned)yy < 512u && (unsigned)xx < 512u)
                v = *(const short8v*)(img + ((long)yy * 512 + xx) * CINP + c);
        }
        *(short8v*)(EP + (long)e * KW + idx * 8) = v;
    }
}

__device__ inline void edge_yx(int e, int& y, int& x) {
    if (e < 512)       { y = 0;   x = e; }
    else if (e < 1024) { y = 511; x = e - 512; }
    else if (e < 1534) { x = 0;   y = 1 + (e - 1024); }
    else               { x = 511; y = 1 + (e - 1534); }
}

template <int COUT, int OUTP, bool RELU, bool FUSE_LN>
__global__ __launch_bounds__(256) void conv_edge_gemm(
    const short* __restrict__ EP,
    const short* __restrict__ wflat,
    const float* __restrict__ bias,
    short* __restrict__ out, int K,
    const short* __restrict__ res,
    const float* __restrict__ lng,
    const float* __restrict__ lnbv)
{
    __shared__ short SMEM[128 * 120];  // >= 8192 staging; = lnbuf size
    short* Xs = SMEM;
    short* Ys = SMEM + 128 * 32;

    const int tid = threadIdx.x, wv = tid >> 6, ln = tid & 63;
    const int wr = wv >> 1, wc = wv & 1;
    const int m0 = blockIdx.x * 128, n0 = blockIdx.y * 128;

    f32x4 acc[4][4] = {};

    const int srow = ln >> 2;
    const int sk8 = ln & 3;
    const int fr = ln & 15, fk = (ln >> 4) * 8;

    for (int k0 = 0; k0 < K; k0 += 32) {
#pragma unroll
        for (int i = wv; i < 8; i += 4) {
            gload_lds16(EP + (long)(m0 + i * 16 + srow) * K + k0 + sk8 * 8,
                        Xs + i * 512);
            gload_lds16(wflat + (long)(n0 + i * 16 + srow) * K + k0 + sk8 * 8,
                        Ys + i * 512);
        }
        __syncthreads();
        short8v a[4], b[4];
#pragma unroll
        for (int mi = 0; mi < 4; ++mi)
            a[mi] = *(const short8v*)(Xs + (wr * 64 + mi * 16 + fr) * 32 + fk);
#pragma unroll
        for (int ni = 0; ni < 4; ++ni)
            b[ni] = *(const short8v*)(Ys + (wc * 64 + ni * 16 + fr) * 32 + fk);
#pragma unroll
        for (int mi = 0; mi < 4; ++mi)
#pragma unroll
            for (int ni = 0; ni < 4; ++ni)
                acc[mi][ni] = __builtin_amdgcn_mfma_f32_16x16x32_bf16(
                    a[mi], b[ni], acc[mi][ni], 0, 0, 0);
        __syncthreads();
    }

    const int fv = (ln >> 4) * 4;
    if constexpr (!FUSE_LN) {
#pragma unroll
        for (int mi = 0; mi < 4; ++mi)
#pragma unroll
            for (int ni = 0; ni < 4; ++ni)
#pragma unroll
                for (int v = 0; v < 4; ++v) {
                    const int e = m0 + wr * 64 + mi * 16 + fv + v;
                    const int co = n0 + wc * 64 + ni * 16 + fr;
                    if (e >= 2044 || co >= COUT) continue;
                    int y, x;
                    edge_yx(e, y, x);
                    float v2 = acc[mi][ni][v] + bias[co];
                    if (RELU) v2 = fmaxf(v2, 0.f);
                    out[((long)y * 512 + x) * OUTP + co] = f2bf(v2);
                }
    } else {
        __shared__ float rmean[128], rinv[128], gs[100], bs[100];
        short* lnbuf = SMEM;
        __syncthreads();
        if (tid < 100) { gs[tid] = lng[tid]; bs[tid] = lnbv[tid]; }
        // Phase A: t = bf16(conv+bias) + res
#pragma unroll
        for (int mi = 0; mi < 4; ++mi)
#pragma unroll
            for (int ni = 0; ni < 4; ++ni)
#pragma unroll
                for (int v = 0; v < 4; ++v) {
                    const int pl = wr * 64 + mi * 16 + fv + v;
                    const int co = wc * 64 + ni * 16 + fr;
                    if (co < 112) {
                        const int e = m0 + pl;
                        float t = 0.f;
                        if (co < COUT && e < 2044) {
                            int y, x;
                            edge_yx(e, y, x);
                            t = bf2f(f2bf(acc[mi][ni][v] + bias[co]))
                              + bf2f(res[((long)y * 512 + x) * 112 + co]);
                        }
                        lnbuf[pl * 120 + co] = f2bf(t);
                    }
                }
        __syncthreads();
        // Phase B: per-row stats
        if (tid < 128) {
            const short* lr = lnbuf + tid * 120;
            float s = 0.f, ss = 0.f;
#pragma unroll
            for (int q = 0; q < 13; ++q) {
                const short8v v8 = *(const short8v*)(lr + q * 8);
#pragma unroll
                for (int j = 0; j < 8; ++j) {
                    const int idx = q * 8 + j;
                    if (idx < 100) {
                        const float t = bf2f(v8[j]);
                        s += t; ss += t * t;
                    }
                }
            }
            const float mean = s * 0.01f;
            const float var = ss * 0.01f - mean * mean;
            rmean[tid] = mean;
            rinv[tid] = rsqrtf(var + 1e-5f);
        }
        __syncthreads();
        // Phase C: vectorized stores (rows scattered; 16B chunks per store)
        for (int c = tid; c < 128 * 14; c += 256) {
            const int row = c / 14, q = c - row * 14;
            const int e = m0 + row;
            if (e >= 2044) continue;
            int y, x;
            edge_yx(e, y, x);
            const float mean = rmean[row], inv = rinv[row];
            const short8v v8 = *(const short8v*)(lnbuf + row * 120 + q * 8);
            short8v o;
#pragma unroll
            for (int j = 0; j < 8; ++j) {
                const int idx = q * 8 + j;
                o[j] = (idx < 100)
                    ? f2bf((bf2f(v8[j]) - mean) * inv * gs[idx] + bs[idx])
                    : (short)0;
            }
            *(short8v*)(out + ((long)y * 512 + x) * 112 + q * 8) = o;
        }
    }
}

// ---------------------------------------------------------------------------
// Transposes / conversions
// ---------------------------------------------------------------------------
__global__ __launch_bounds__(256) void r_transpose(
    const float* __restrict__ R, short* __restrict__ Rt)
{
    __shared__ float Ts[64][65];
    const int tid = threadIdx.x;
    const long base = (long)blockIdx.z * 589824;
    const int d0 = blockIdx.y * 64, e0 = blockIdx.x * 64;
    const int c = tid & 63, rbase = tid >> 6;
#pragma unroll
    for (int j = 0; j < 16; ++j) {
        const int r = rbase + j * 4;
        Ts[r][c] = R[base + (long)(d0 + r) * 768 + e0 + c];
    }
    __syncthreads();
#pragma unroll
    for (int j = 0; j < 16; ++j) {
        const int e = rbase + j * 4;
        Rt[base + (long)(e0 + e) * 768 + d0 + c] = f2bf(Ts[c][e]);
    }
}

// mh_w{f,b}[l] [8][768][96] f32 -> WFBT [16][128][768] bf16 (o-major, padded).
__global__ __launch_bounds__(256) void wfb_transpose(
    const float* __restrict__ wf, const float* __restrict__ wb,
    short* __restrict__ dst)
{
    __shared__ float Ts[64][65];
    const int tid = threadIdx.x;
    const int z = blockIdx.z;
    const float* src = (z < 8) ? wf + (long)z * 73728 : wb + (long)(z - 8) * 73728;
    const int d0 = blockIdx.x * 64, o0 = blockIdx.y * 64;
    const int c = tid & 63, rbase = tid >> 6;
#pragma unroll
    for (int j = 0; j < 16; ++j) {
        const int r = rbase + j * 4;
        Ts[r][c] = (o0 + c < 96) ? src[(long)(d0 + r) * 96 + o0 + c] : 0.f;
    }
    __syncthreads();
#pragma unroll
    for (int j = 0; j < 16; ++j) {
        const int e = rbase + j * 4;
        dst[(long)z * 98304 + (long)(o0 + e) * 768 + d0 + c] = f2bf(Ts[c][e]);
    }
}

// Laplace-normalize bf16 Ahat (deterministic 2-partial rowsums) -> A and A^T.
__global__ __launch_bounds__(256) void a_laplace_t(
    const short* __restrict__ Ahat, const float* __restrict__ psum,
    short* __restrict__ ABF, short* __restrict__ ABFT)
{
    __shared__ float Ts[64][65];
    const int tid = threadIdx.x;
    const int r8 = blockIdx.z;
    const long ra = (long)r8 * 262144;
    const int i0 = blockIdx.y * 64, j0 = blockIdx.x * 64;
    const int c = tid & 63, rbase = tid >> 6;
    const float sj = psum[r8 * 1024 + (j0 + c) * 2] + psum[r8 * 1024 + (j0 + c) * 2 + 1];
    const float dj = rsqrtf(sj);
#pragma unroll
    for (int j = 0; j < 16; ++j) {
        const int r = rbase + j * 4;
        const float si = psum[r8 * 1024 + (i0 + r) * 2] + psum[r8 * 1024 + (i0 + r) * 2 + 1];
        const float di = rsqrtf(si);
        const float v = bf2f(Ahat[ra + (long)(i0 + r) * 512 + j0 + c]) * di * dj;
        Ts[r][c] = v;
        ABF[ra + (long)(i0 + r) * 512 + j0 + c] = f2bf(v);
    }
    __syncthreads();
#pragma unroll
    for (int j = 0; j < 16; ++j) {
        const int e = rbase + j * 4;
        ABFT[ra + (long)(j0 + e) * 512 + i0 + c] = f2bf(Ts[c][e]);
    }
}

// e[m][r*96+o] = bf16(relu(O1[r][m][o] + O2[r][m][o] + mh_b[r*96+o]))
__global__ __launch_bounds__(256) void gcn_combine(
    const short* __restrict__ O1, const short* __restrict__ O2,
    const float* __restrict__ mhb, short* __restrict__ e)
{
    const int idx = blockIdx.x * 256 + threadIdx.x;  // 393216
    const int m = idx / 768, c = idx - m * 768;
    const int r = c / 96, o = c - r * 96;
    const long oi = (long)r * 65536 + (long)m * 128 + o;
    float v = bf2f(O1[oi]) + bf2f(O2[oi]) + mhb[c];
    e[idx] = f2bf(fmaxf(v, 0.f));
}

// ---------------------------------------------------------------------------
// Channel-major -> pixel-major transpose of the rel tensor, full-channel
// blocks (64 px x 112 ch in LDS). DO_LN=true additionally applies the
// channel-LN against `res` (layer-1 rel_ln). Linear coalesced writes.
// ---------------------------------------------------------------------------
template <bool DO_LN>
__global__ __launch_bounds__(256) void rel_transpose_ln(
    const short* __restrict__ relc,   // [100][512][512]
    short* __restrict__ relp,         // [262144][112]
    const short* __restrict__ res,    // [262144][112] (DO_LN only)
    const float* __restrict__ g, const float* __restrict__ b)
{
    __shared__ short Ts[64][112];
    __shared__ float rmean[64], rinv[64], gs[100], bs[100];
    const int tid = threadIdx.x;
    const long p0 = (long)blockIdx.x * 64;

    if (DO_LN && tid < 100) { gs[tid] = g[tid]; bs[tid] = b[tid]; }

    const int ch = tid >> 3, pxo = (tid & 7) * 8;
#pragma unroll
    for (int r0 = 0; r0 < 128; r0 += 32) {
        const int c = r0 + ch;
        short8v v = {0, 0, 0, 0, 0, 0, 0, 0};
        if (c < 100)
            v = *(const short8v*)(relc + (long)c * NNpix + p0 + pxo);
        if (c < 112)
#pragma unroll
            for (int j = 0; j < 8; ++j) Ts[pxo + j][c] = v[j];
    }
    __syncthreads();

    if constexpr (DO_LN) {
        for (int cix = tid; cix < 64 * 14; cix += 256) {
            const int row = cix / 14, q = cix - row * 14;
            short8v tv = *(const short8v*)(&Ts[row][q * 8]);
            const short8v rv = *(const short8v*)(res + (p0 + row) * 112 + q * 8);
#pragma unroll
            for (int j = 0; j < 8; ++j) {
                const int idx = q * 8 + j;
                const float t = (idx < 100) ? bf2f(tv[j]) + bf2f(rv[j]) : 0.f;
                tv[j] = f2bf(t);
            }
            *(short8v*)(&Ts[row][q * 8]) = tv;
        }
        __syncthreads();
        if (tid < 64) {
            float s = 0.f, ss = 0.f;
#pragma unroll
            for (int q = 0; q < 13; ++q) {
                const short8v v8 = *(const short8v*)(&Ts[tid][q * 8]);
#pragma unroll
                for (int j = 0; j < 8; ++j) {
                    const int idx = q * 8 + j;
                    if (idx < 100) {
                        const float t = bf2f(v8[j]);
                        s += t; ss += t * t;
                    }
                }
            }
            const float mean = s * 0.01f;
            rmean[tid] = mean;
            rinv[tid] = rsqrtf(ss * 0.01f - mean * mean + 1e-5f);
        }
        __syncthreads();
    }

    for (int cix = tid; cix < 64 * 14; cix += 256) {
        const int row = cix / 14, q = cix - row * 14;
        short8v v8 = *(const short8v*)(&Ts[row][q * 8]);
        if constexpr (DO_LN) {
            const float mean = rmean[row], inv = rinv[row];
            short8v o;
#pragma unroll
            for (int j = 0; j < 8; ++j) {
                const int idx = q * 8 + j;
                o[j] = (idx < 100)
                    ? f2bf((bf2f(v8[j]) - mean) * inv * gs[idx] + bs[idx])
                    : (short)0;
            }
            v8 = o;
        }
        *(short8v*)(relp + (p0 + row) * 112 + q * 8) = v8;
    }
}

__global__ __launch_bounds__(256) void conv_w_flat(
    const float* __restrict__ src, short* __restrict__ dst,
    int COUT, int CIN, int COUTP, int CINW)
{
    const int idx = blockIdx.x * 256 + threadIdx.x;
    const int KW = 9 * CINW;
    const int total = COUTP * KW;
    if (idx >= total) return;
    const int co = idx / KW;
    const int rem = idx - co * KW;
    const int tap = rem / CINW, ci = rem - tap * CINW;
    short v = 0;
    if (co < COUT && ci < CIN)
        v = f2bf(src[((long)co * CIN + ci) * 9 + tap]);
    dst[idx] = v;
}

__global__ __launch_bounds__(256) void f32_to_bf16k(
    const float* __restrict__ src, short* __restrict__ dst, long n)
{
    const long i = (long)blockIdx.x * 256 + threadIdx.x;
    if (i < n) dst[i] = f2bf(src[i]);
}

// ---------------------------------------------------------------------------
// softmax over 8 relation logits + bf16 A_hat + deterministic rowsum partials.
// EMIT_LOGITS=true (layer 1): also streams the pre-softmax logits (the final
// rels output) to `logits_out` via an LDS stage + fully linear float4 writes.
// ---------------------------------------------------------------------------
template <bool EMIT_LOGITS>
__global__ __launch_bounds__(256) void rel_softmax_laplace(
    const short* __restrict__ relp,
    const float* __restrict__ w,
    const float* __restrict__ bvec,
    short* __restrict__ Ahat,
    float* __restrict__ psum,
    float* __restrict__ logits_out)
{
    __shared__ float ws[800];
    __shared__ float wred[8][4];
    __shared__ float lout[2048];          // 256 px x 8 logits (EMIT only)
    const int tid = threadIdx.x;
    for (int i = tid; i < 800; i += 256) ws[i] = w[i];
    __syncthreads();

    const int i = blockIdx.y;
    const int j = blockIdx.x * 256 + tid;
    const long p = (long)i * 512 + j;
    const short* row = relp + p * 112;

    float acc[8];
#pragma unroll
    for (int r8 = 0; r8 < 8; ++r8) acc[r8] = bvec[r8];
#pragma unroll
    for (int q = 0; q < 13; ++q) {
        const short8v v = *(const short8v*)(row + q * 8);
#pragma unroll
        for (int jj = 0; jj < 8; ++jj) {
            const int r = q * 8 + jj;
            if (r < 100) {
                const float x = bf2f(v[jj]);
#pragma unroll
                for (int r8 = 0; r8 < 8; ++r8)
                    acc[r8] = fmaf(x, ws[r8 * 100 + r], acc[r8]);
            }
        }
    }
    if constexpr (EMIT_LOGITS) {
#pragma unroll
        for (int r8 = 0; r8 < 8; ++r8) lout[tid * 8 + r8] = acc[r8];
    }
    float m = acc[0];
#pragma unroll
    for (int r8 = 1; r8 < 8; ++r8) m = fmaxf(m, acc[r8]);
    float s = 0.f;
#pragma unroll
    for (int r8 = 0; r8 < 8; ++r8) { acc[r8] = expf(acc[r8] - m); s += acc[r8]; }
    const float inv = 1.f / s;
#pragma unroll
    for (int r8 = 0; r8 < 8; ++r8) {
        const float a = acc[r8] * inv + (i == j ? 1.f : 0.f);
        acc[r8] = a;
        Ahat[(long)r8 * NNpix + p] = f2bf(a);
    }
    const int lane = tid & 63, wvv = tid >> 6;
#pragma unroll
    for (int r8 = 0; r8 < 8; ++r8) {
        float v = acc[r8];
        for (int off = 32; off > 0; off >>= 1) v += __shfl_down(v, off);
        if (lane == 0) wred[r8][wvv] = v;
    }
    __syncthreads();
    if (tid < 8) {
        const float v = wred[tid][0] + wred[tid][1] + wred[tid][2] + wred[tid][3];
        psum[tid * 1024 + i * 2 + blockIdx.x] = v;
    }
    if constexpr (EMIT_LOGITS) {
        // block's pixels are contiguous: linear float4 stream of 8KB
        const long pbase = (long)i * 512 + blockIdx.x * 256;
        float4* dst = (float4*)(logits_out + pbase * 8);
        const float4* src4 = (const float4*)lout;
#pragma unroll
        for (int c = tid; c < 512; c += 256)
            dst[c] = src4[c];
    }
}

// Row LN over D=768 with fused bf16 emit of the normalized ents.
__global__ __launch_bounds__(256) void ln_row768(
    const float* __restrict__ x, const float* __restrict__ res,
    const float* __restrict__ g, const float* __restrict__ b,
    float* __restrict__ outf, short* __restrict__ outbf)
{
    const int n = blockIdx.x;
    const int tid = threadIdx.x;
    float v[3];
    float s = 0.f, ss = 0.f;
#pragma unroll
    for (int i = 0; i < 3; ++i) {
        const int c = tid + 256 * i;
        v[i] = x[(long)n * 768 + c] + res[(long)n * 768 + c];
        s += v[i]; ss += v[i] * v[i];
    }
    const int lane = tid & 63, wv = tid >> 6;
    for (int off = 32; off > 0; off >>= 1) {
        s += __shfl_down(s, off);
        ss += __shfl_down(ss, off);
    }
    __shared__ float rs[4], rss[4];
    if (lane == 0) { rs[wv] = s; rss[wv] = ss; }
    __syncthreads();
    s = rs[0] + rs[1] + rs[2] + rs[3];
    ss = rss[0] + rss[1] + rss[2] + rss[3];
    const float mean = s * (1.f / 768.f);
    const float var = ss * (1.f / 768.f) - mean * mean;
    const float inv = rsqrtf(var + 1e-5f);
#pragma unroll
    for (int i = 0; i < 3; ++i) {
        const int c = tid + 256 * i;
        const float o = (v[i] - mean) * inv * g[c] + b[c];
        outf[(long)n * 768 + c] = o;
        outbf[(long)n * 768 + c] = f2bf(o);
    }
}

__global__ __launch_bounds__(256) void zero_f32(float* __restrict__ p, long n)
{
    const long i = (long)blockIdx.x * 256 + threadIdx.x;
    if (i < n) p[i] = 0.f;
}

// ---------------------------------------------------------------------------
extern "C" void kernel_launch(void* const* d_in, const int* in_sizes, int n_in,
                              void* d_out, int out_size, void* d_ws, size_t ws_size,
                              hipStream_t stream)
{
    (void)in_sizes; (void)n_in; (void)out_size; (void)ws_size;

    const float* ents_in   = (const float*)d_in[0];
    const float* R_local   = (const float*)d_in[1];
    const float* rel_mlp_w = (const float*)d_in[2];
    const float* rel_mlp_b = (const float*)d_in[3];
    const float* conv1_w   = (const float*)d_in[4];
    const float* conv1_b   = (const float*)d_in[5];
    const float* conv2_w   = (const float*)d_in[6];
    const float* conv2_b   = (const float*)d_in[7];
    const float* pffn_g    = (const float*)d_in[8];
    const float* pffn_b    = (const float*)d_in[9];
    const float* rln_g     = (const float*)d_in[10];
    const float* rln_b     = (const float*)d_in[11];
    const float* mh_wf     = (const float*)d_in[12];
    const float* mh_wb     = (const float*)d_in[13];
    const float* mh_b      = (const float*)d_in[14];
    const float* emlp_w    = (const float*)d_in[15];
    const float* emlp_b    = (const float*)d_in[16];
    const float* eln_g     = (const float*)d_in[17];
    const float* eln_b     = (const float*)d_in[18];
    float* out = (float*)d_out;

    // ---- workspace layout (1 KiB aligned) ----
    char* base = (char*)d_ws;
    size_t off = 0;
    auto alloc = [&](size_t bytes) {
        char* p = base + off;
        off += (bytes + 1023) & ~(size_t)1023;
        return p;
    };
    char* U1 = alloc(117964800 + 4096);              // RTL / H1T union
    short* RTL = (short*)U1;                         // [100][768][768] bf16
    short* H1T = (short*)U1;                         // [262144][208] bf16
    char* U2 = alloc(78643200 + 4096);               // TB union
    short* TB  = (short*)U2;                         // [100][512][768] bf16
    short* RELC   = (short*)alloc(52428800 + 4096);  // [100][512][512] bf16
    short* RELP_A = (short*)alloc(58720256 + 4096);  // [262144][112] bf16
    short* RELP_B = (short*)alloc(58720256 + 4096);
    short* RELP_C = (short*)alloc(58720256 + 4096);  // fused-LN output (l0)
    short* W1P = (short*)alloc(294912 * 2);          // [256][9*128] bf16
    short* W2P = (short*)alloc(258048 * 2);          // [128][9*224] bf16
    short* EPB = (short*)alloc(2048L * 2016 * 2 + 4096); // edge patch matrix
    // ---- TAIL region: zeroed at the start of EVERY call ----
    const size_t tail0 = off;
    short* EBF  = (short*)alloc(393216L * 2);        // ents bf16 [512][768]
    short* ABUF = (short*)alloc(2097152L * 2);       // Ahat bf16 [8][512][512]
    float* PSUM = (float*)alloc(8192L * 4);          // [8][512][2] partials
    short* ABF  = (short*)alloc(2097152L * 2);       // A bf16
    short* ABFT = (short*)alloc(2097152L * 2);       // A^T bf16 (contig)
    short* WFBT = (short*)alloc(1572864L * 2);       // [16][128][768] bf16
    short* HFBT = (short*)alloc(1048576L * 2);       // [16][128][512] bf16
    short* O1B  = (short*)alloc(524288L * 2);        // [8][512][128] bf16
    short* O2B  = (short*)alloc(524288L * 2);        // (contig after O1B)
    short* EB2  = (short*)alloc(393216L * 2);        // e bf16 [512][768]
    short* EWB  = (short*)alloc(589824L * 2);        // emlp_w bf16 [768][768]
    float* E2   = (float*)alloc(393216L * 4);
    float* ENTS1 = (float*)alloc(393216L * 4);       // layer-0 output ents
    const long tailN = (long)((off - tail0) / 4);
    (void)O2B;

    zero_f32<<<(int)((tailN + 255) / 256), 256, 0, stream>>>(
        (float*)(base + tail0), tailN);

    for (int l = 0; l < 2; ++l) {
        // RELP_res: pre-posFFN rel tensor (residual). RELP_out: post-LN rel.
        short* RELP_res = (l == 0) ? RELP_A : RELP_B;
        short* RELP_out = (l == 0) ? RELP_C : RELP_A;
        const float* ents_cur = (l == 0) ? ents_in : ENTS1;
        float* ents_next = (l == 0) ? ENTS1 : out;

        if (l == 0)
            f32_to_bf16k<<<1536, 256, 0, stream>>>(ents_in, EBF, 393216);

        r_transpose<<<dim3(12, 12, 100), 256, 0, stream>>>(
            R_local + (long)l * 58982400, RTL);

        // t[r] = ents @ R[r] ; rel[r] = relu(t[r] @ ents^T)
        bgemm_xyt<false><<<dim3(6, 4, 100), 256, 0, stream>>>(
            EBF, 0, RTL, 589824L, TB, 393216L, 512, 768, 768);
        bgemm_xyt<true><<<dim3(4, 4, 100), 256, 0, stream>>>(
            TB, 393216L, EBF, 0, RELC, 262144L, 512, 512, 768);
        // transpose to pixel-major; l1 fuses the rel_ln against RELP_C
        if (l == 0)
            rel_transpose_ln<false><<<4096, 256, 0, stream>>>(
                RELC, RELP_res, nullptr, nullptr, nullptr);
        else
            rel_transpose_ln<true><<<4096, 256, 0, stream>>>(
                RELC, RELP_res, RELP_C, rln_g + 100, rln_b + 100);

        // posFFN convs: ky-slab MFMA main pass (XCD-swizzled) + edge fix;
        // conv2 (main + edge) fuses the channel-LN, writing RELP_out.
        conv_w_flat<<<1152, 256, 0, stream>>>(
            conv1_w + (long)l * 180000, W1P, 200, 100, 256, 128);
        conv_w_flat<<<1008, 256, 0, stream>>>(
            conv2_w + (long)l * 180000, W2P, 100, 200, 128, 224);

        conv_gemm<112, 128, 200, 208, true, false>
            <<<dim3(2048, 2), 256, 0, stream>>>(
            RELP_res, W1P, conv1_b + l * 200, H1T, nullptr, nullptr, nullptr);
        edge_gather<112, 128><<<2048, 256, 0, stream>>>(RELP_res, EPB);
        conv_edge_gemm<200, 208, true, false>
            <<<dim3(16, 2), 256, 0, stream>>>(
            EPB, W1P, conv1_b + l * 200, H1T, 1152, nullptr, nullptr, nullptr);

        conv_gemm<208, 224, 100, 112, false, true>
            <<<dim3(2048, 1), 256, 0, stream>>>(
            H1T, W2P, conv2_b + l * 100, RELP_out,
            RELP_res, pffn_g + l * 100, pffn_b + l * 100);
        edge_gather<208, 224><<<2048, 256, 0, stream>>>(H1T, EPB);
        conv_edge_gemm<100, 112, false, true>
            <<<dim3(16, 1), 256, 0, stream>>>(
            EPB, W2P, conv2_b + l * 100, RELP_out, 2016,
            RELP_res, pffn_g + l * 100, pffn_b + l * 100);

        // softmax + deterministic rowsum partials; Laplace into bf16 A, A^T.
        // Layer 1 also emits the final rels logits directly into d_out.
        if (l == 0)
            rel_softmax_laplace<false><<<dim3(2, 512), 256, 0, stream>>>(
                RELP_out, rel_mlp_w, rel_mlp_b, ABUF, PSUM, nullptr);
        else
            rel_softmax_laplace<true><<<dim3(2, 512), 256, 0, stream>>>(
                RELP_out, rel_mlp_w, rel_mlp_b, ABUF, PSUM, out + 393216);
        a_laplace_t<<<dim3(8, 8, 8), 256, 0, stream>>>(ABUF, PSUM, ABF, ABFT);

        // GCN via MFMA: HFT/HBT = h^T; merged O-GEMM (z<8: A.hf, z>=8: A^T.hb)
        wfb_transpose<<<dim3(12, 2, 16), 256, 0, stream>>>(
            mh_wf + (long)l * 589824, mh_wb + (long)l * 589824, WFBT);
        bgemm_xyt<false><<<dim3(4, 1, 16), 256, 0, stream>>>(
            WFBT, 98304L, EBF, 0, HFBT, 65536L, 128, 512, 768);
        bgemm_xyt<false><<<dim3(1, 4, 16), 256, 0, stream>>>(
            ABF, 262144L, HFBT, 65536L, O1B, 65536L, 512, 128, 512);
        gcn_combine<<<1536, 256, 0, stream>>>(O1B, O1B + 8L * 65536,
                                              mh_b + l * 768, EB2);

        // ent_mlp (MFMA) + residual LN (out-of-place; fused bf16 emit)
        f32_to_bf16k<<<2304, 256, 0, stream>>>(
            emlp_w + (long)l * 589824, EWB, 589824);
        bgemm_bias_f32<<<dim3(6, 4), 256, 0, stream>>>(
            EB2, EWB, E2, emlp_b + l * 768, 512, 768, 768);
        ln_row768<<<512, 256, 0, stream>>>(E2, ents_cur,
            eln_g + l * 768, eln_b + l * 768, ents_next, EBF);
    }
}

// Round 19
// 1653.637 us; speedup vs baseline: 1.3286x; 1.0209x over previous
//
#include <hip/hip_runtime.h>
#include <hip/hip_bf16.h>

// DecoderIGCN forward. Round 19: conv1 re-parameterized to 64-co n-tiles
// (NI=2: acc regs 64->32, ~4 blocks/CU vs 3 — occupancy-targeted, same
// algorithm). Conv2 keeps NI=4 (LN fusion needs full-channel n-tile).
// Rest identical to round 18 (1688 us). N=512, D=768, RDIM=100, R=8, L=2.

static constexpr long NNpix = 512L * 512L; // 262144

typedef __attribute__((ext_vector_type(8))) short short8v;
typedef __attribute__((ext_vector_type(4))) float f32x4;

__device__ inline float bf2f(short s) {
    unsigned u = ((unsigned)(unsigned short)s) << 16;
    float f; __builtin_memcpy(&f, &u, 4);
    return f;
}
__device__ inline short f2bf(float f) {
    unsigned u; __builtin_memcpy(&u, &f, 4);
    u += 0x7fff + ((u >> 16) & 1);   // RNE
    return (short)(u >> 16);
}
__device__ inline void gload_lds16(const short* g, short* l) {
    __builtin_amdgcn_global_load_lds(
        (const __attribute__((address_space(1))) unsigned int*)g,
        (__attribute__((address_space(3))) unsigned int*)l, 16, 0, 0);
}

// Bijective XCD swizzle of the flattened block index (requires total%8==0;
// identity otherwise). Consecutive swizzled ids share an XCD's L2.
__device__ inline void xcd_block3(int& bx, int& by, int& bz) {
    const long gx = gridDim.x, gy = gridDim.y;
    const long total = gx * gy * (long)gridDim.z;
    long lin = blockIdx.x + gx * (blockIdx.y + gy * (long)blockIdx.z);
    if ((total & 7) == 0)
        lin = (lin & 7) * (total >> 3) + (lin >> 3);
    const long gxy = gx * gy;
    bz = (int)(lin / gxy);
    const int rem = (int)(lin - (long)bz * gxy);
    by = rem / (int)gx;
    bx = rem - by * (int)gx;
}

// ---------------------------------------------------------------------------
// bf16 MFMA GEMM: D[M][N] = (relu?)(X[M][K] . Y[N][K]^T), all bf16 (shorts).
// 128x128 tile, BK=32, 256 threads (4 waves, 2x2), 16x16x32 MFMA.
// ---------------------------------------------------------------------------
template <bool RELU>
__global__ __launch_bounds__(256) void bgemm_xyt(
    const short* __restrict__ X, long sX,
    const short* __restrict__ Y, long sY,
    short* __restrict__ D, long sD,
    int M, int N, int K)
{
    int bx, by, bz;
    xcd_block3(bx, by, bz);
    X += (long)bz * sX;
    Y += (long)bz * sY;
    D += (long)bz * sD;

    __shared__ short Xs[128 * 32];
    __shared__ short Ys[128 * 32];

    const int tid = threadIdx.x, wv = tid >> 6, ln = tid & 63;
    const int wr = wv >> 1, wc = wv & 1;
    const int m0 = by * 128, n0 = bx * 128;

    f32x4 acc[4][4] = {};

    const int srow = ln >> 2;
    const int sk8 = ln & 3;
    const int fr = ln & 15, fk = (ln >> 4) * 8;

    for (int k0 = 0; k0 < K; k0 += 32) {
#pragma unroll
        for (int i = wv; i < 8; i += 4) {
            gload_lds16(X + (long)(m0 + i * 16 + srow) * K + k0 + sk8 * 8,
                        Xs + i * 512);
            gload_lds16(Y + (long)(n0 + i * 16 + srow) * K + k0 + sk8 * 8,
                        Ys + i * 512);
        }
        __syncthreads();
        short8v a[4], b[4];
#pragma unroll
        for (int mi = 0; mi < 4; ++mi)
            a[mi] = *(const short8v*)(Xs + (wr * 64 + mi * 16 + fr) * 32 + fk);
#pragma unroll
        for (int ni = 0; ni < 4; ++ni)
            b[ni] = *(const short8v*)(Ys + (wc * 64 + ni * 16 + fr) * 32 + fk);
#pragma unroll
        for (int mi = 0; mi < 4; ++mi)
#pragma unroll
            for (int ni = 0; ni < 4; ++ni)
                acc[mi][ni] = __builtin_amdgcn_mfma_f32_16x16x32_bf16(
                    a[mi], b[ni], acc[mi][ni], 0, 0, 0);
        __syncthreads();
    }

    const int fv = (ln >> 4) * 4;
#pragma unroll
    for (int mi = 0; mi < 4; ++mi)
#pragma unroll
        for (int ni = 0; ni < 4; ++ni)
#pragma unroll
            for (int v = 0; v < 4; ++v) {
                const int row = m0 + wr * 64 + mi * 16 + fv + v;
                const int col = n0 + wc * 64 + ni * 16 + fr;
                float x = acc[mi][ni][v];
                if (RELU) x = fmaxf(x, 0.f);
                D[(long)row * N + col] = f2bf(x);
            }
}

// Same GEMM, fp32 output + per-column bias (for emlp).
__global__ __launch_bounds__(256) void bgemm_bias_f32(
    const short* __restrict__ X,
    const short* __restrict__ Y,
    float* __restrict__ D,
    const float* __restrict__ bias,
    int M, int N, int K)
{
    int bx, by, bz;
    xcd_block3(bx, by, bz);
    (void)bz;

    __shared__ short Xs[128 * 32];
    __shared__ short Ys[128 * 32];

    const int tid = threadIdx.x, wv = tid >> 6, ln = tid & 63;
    const int wr = wv >> 1, wc = wv & 1;
    const int m0 = by * 128, n0 = bx * 128;

    f32x4 acc[4][4] = {};

    const int srow = ln >> 2;
    const int sk8 = ln & 3;
    const int fr = ln & 15, fk = (ln >> 4) * 8;

    for (int k0 = 0; k0 < K; k0 += 32) {
#pragma unroll
        for (int i = wv; i < 8; i += 4) {
            gload_lds16(X + (long)(m0 + i * 16 + srow) * K + k0 + sk8 * 8,
                        Xs + i * 512);
            gload_lds16(Y + (long)(n0 + i * 16 + srow) * K + k0 + sk8 * 8,
                        Ys + i * 512);
        }
        __syncthreads();
        short8v a[4], b[4];
#pragma unroll
        for (int mi = 0; mi < 4; ++mi)
            a[mi] = *(const short8v*)(Xs + (wr * 64 + mi * 16 + fr) * 32 + fk);
#pragma unroll
        for (int ni = 0; ni < 4; ++ni)
            b[ni] = *(const short8v*)(Ys + (wc * 64 + ni * 16 + fr) * 32 + fk);
#pragma unroll
        for (int mi = 0; mi < 4; ++mi)
#pragma unroll
            for (int ni = 0; ni < 4; ++ni)
                acc[mi][ni] = __builtin_amdgcn_mfma_f32_16x16x32_bf16(
                    a[mi], b[ni], acc[mi][ni], 0, 0, 0);
        __syncthreads();
    }

    const int fv = (ln >> 4) * 4;
#pragma unroll
    for (int mi = 0; mi < 4; ++mi)
#pragma unroll
        for (int ni = 0; ni < 4; ++ni)
#pragma unroll
            for (int v = 0; v < 4; ++v) {
                const int row = m0 + wr * 64 + mi * 16 + fv + v;
                const int col = n0 + wc * 64 + ni * 16 + fr;
                D[(long)row * N + col] = acc[mi][ni][v] + bias[col];
            }
}

// ---------------------------------------------------------------------------
// conv3x3 main pass (ky-slab, 4 waves, XCD m-swizzle). Co-tile width is
// NI*32 (NI frags of 16 per n-wave, 2 n-waves). NI=2 -> 64-co tiles, 32 acc
// regs (occupancy); NI=4 -> 128-co tiles (required for FUSE_LN). FUSE_LN:
// stage t in LDS, per-row stats, linear coalesced short8 output stream.
// ---------------------------------------------------------------------------
template <int CINP, int CINW, int NI, int COUT, int OUTP, bool RELU, bool FUSE_LN>
__global__ __launch_bounds__(256) void conv_gemm(
    const short* __restrict__ img,
    const short* __restrict__ wflat,
    const float* __restrict__ bias,
    short* __restrict__ out,
    const short* __restrict__ res,
    const float* __restrict__ lng,
    const float* __restrict__ lnbv)
{
    constexpr int NCH = CINW / 32;
    constexpr int KW = 9 * CINW;
    constexpr int YS_OFF = 144 * 32;                 // X slab shorts
    constexpr int SM_GEMM = YS_OFF + NI * 3072;      // + 3 kx tiles
    constexpr int SM_SZ = (FUSE_LN && SM_GEMM < 15360) ? 15360 : SM_GEMM;

    __shared__ short SMEM[SM_SZ];
    short* Xs = SMEM;
    short* Ys = SMEM + YS_OFF;

    const int tid = threadIdx.x, wv = tid >> 6, ln = tid & 63;
    const int wr = wv >> 1, wc = wv & 1;
    const int bx = blockIdx.x;
    const int bsw = (bx & 7) * ((int)gridDim.x >> 3) + (bx >> 3);
    const int m0 = bsw * 128;
    const int n0 = blockIdx.y * (NI * 32);

    f32x4 acc[4][NI] = {};

    const int srow = ln >> 2;
    const int sk8 = ln & 3;
    const int fr = ln & 15, fk = (ln >> 4) * 8;

    for (int ky = 0; ky < 3; ++ky) {
        const int slab0 = m0 + (ky - 1) * 512 - 1;
        for (int cc = 0; cc < NCH; ++cc) {
            const int ci0 = cc * 32;
#pragma unroll
            for (int i = wv; i < 9; i += 4) {
                int rpx = slab0 + i * 16 + srow;
                rpx = rpx < 0 ? 0 : (rpx > (int)NNpix - 1 ? (int)NNpix - 1 : rpx);
                gload_lds16(img + (long)rpx * CINP + ci0 + sk8 * 8,
                            Xs + i * 512);
            }
#pragma unroll
            for (int kx = 0; kx < 3; ++kx) {
                const int wbase = (ky * 3 + kx) * CINW;
#pragma unroll
                for (int i = wv; i < NI * 2; i += 4)
                    gload_lds16(wflat + (long)(n0 + i * 16 + srow) * KW + wbase + ci0 + sk8 * 8,
                                Ys + kx * (NI * 1024) + i * 512);
            }
            __syncthreads();
#pragma unroll
            for (int kx = 0; kx < 3; ++kx) {
                short8v a[4], b[NI];
#pragma unroll
                for (int mi = 0; mi < 4; ++mi)
                    a[mi] = *(const short8v*)(Xs + (wr * 64 + mi * 16 + fr + kx) * 32 + fk);
#pragma unroll
                for (int ni = 0; ni < NI; ++ni)
                    b[ni] = *(const short8v*)(Ys + kx * (NI * 1024)
                        + (wc * (NI * 16) + ni * 16 + fr) * 32 + fk);
#pragma unroll
                for (int mi = 0; mi < 4; ++mi)
#pragma unroll
                    for (int ni = 0; ni < NI; ++ni)
                        acc[mi][ni] = __builtin_amdgcn_mfma_f32_16x16x32_bf16(
                            a[mi], b[ni], acc[mi][ni], 0, 0, 0);
            }
            __syncthreads();
        }
    }

    const int fv = (ln >> 4) * 4;
    if constexpr (!FUSE_LN) {
#pragma unroll
        for (int mi = 0; mi < 4; ++mi)
#pragma unroll
            for (int ni = 0; ni < NI; ++ni)
#pragma unroll
                for (int v = 0; v < 4; ++v) {
                    const int px = m0 + wr * 64 + mi * 16 + fv + v;
                    const int co = n0 + wc * (NI * 16) + ni * 16 + fr;
                    if (co < COUT) {
                        float x = acc[mi][ni][v] + bias[co];
                        if (RELU) x = fmaxf(x, 0.f);
                        out[(long)px * OUTP + co] = f2bf(x);
                    } else if (co < OUTP) {
                        out[(long)px * OUTP + co] = 0;
                    }
                }
    } else {
        __shared__ float rmean[128], rinv[128], gs[100], bs[100];
        short* lnbuf = SMEM;  // [128][120] = 15360 shorts <= SM_SZ
        __syncthreads();      // K-loop LDS reads complete
        if (tid < 100) { gs[tid] = lng[tid]; bs[tid] = lnbv[tid]; }
        // Phase A: t = bf16(conv+bias) + res
#pragma unroll
        for (int mi = 0; mi < 4; ++mi)
#pragma unroll
            for (int ni = 0; ni < NI; ++ni)
#pragma unroll
                for (int v = 0; v < 4; ++v) {
                    const int pl = wr * 64 + mi * 16 + fv + v;
                    const int co = wc * (NI * 16) + ni * 16 + fr;
                    if (co < 112) {
                        float t = 0.f;
                        if (co < COUT) {
                            const long gpx = (long)m0 + pl;
                            t = bf2f(f2bf(acc[mi][ni][v] + bias[co]))
                              + bf2f(res[gpx * 112 + co]);
                        }
                        lnbuf[pl * 120 + co] = f2bf(t);
                    }
                }
        __syncthreads();
        // Phase B: per-row stats from vectorized LDS reads
        if (tid < 128) {
            const short* lr = lnbuf + tid * 120;
            float s = 0.f, ss = 0.f;
#pragma unroll
            for (int q = 0; q < 13; ++q) {
                const short8v v8 = *(const short8v*)(lr + q * 8);
#pragma unroll
                for (int j = 0; j < 8; ++j) {
                    const int idx = q * 8 + j;
                    if (idx < 100) {
                        const float t = bf2f(v8[j]);
                        s += t; ss += t * t;
                    }
                }
            }
            const float mean = s * 0.01f;
            const float var = ss * 0.01f - mean * mean;
            rmean[tid] = mean;
            rinv[tid] = rsqrtf(var + 1e-5f);
        }
        __syncthreads();
        // Phase C: linear coalesced short8 output stream
        for (int c = tid; c < 128 * 14; c += 256) {
            const int row = c / 14, q = c - row * 14;
            const float mean = rmean[row], inv = rinv[row];
            const short8v v8 = *(const short8v*)(lnbuf + row * 120 + q * 8);
            short8v o;
#pragma unroll
            for (int j = 0; j < 8; ++j) {
                const int idx = q * 8 + j;
                o[j] = (idx < 100)
                    ? f2bf((bf2f(v8[j]) - mean) * inv * gs[idx] + bs[idx])
                    : (short)0;
            }
            *(short8v*)(out + ((long)m0 + row) * 112 + q * 8) = o;
        }
    }
}

// Edge path: gather 2044 border patches -> GEMM -> scatter (FUSE_LN for conv2).
template <int CINP, int CINW>
__global__ __launch_bounds__(256) void edge_gather(
    const short* __restrict__ img, short* __restrict__ EP)
{
    constexpr int KW = 9 * CINW;
    const int e = blockIdx.x;
    int y, x;
    bool real = true;
    if (e < 512)       { y = 0;   x = e; }
    else if (e < 1024) { y = 511; x = e - 512; }
    else if (e < 1534) { x = 0;   y = 1 + (e - 1024); }
    else if (e < 2044) { x = 511; y = 1 + (e - 1534); }
    else               { y = 0; x = 0; real = false; }

    const int tid = threadIdx.x;
    for (int idx = tid; idx < KW / 8; idx += 256) {
        const int tap = idx / (CINW / 8);
        const int c = (idx - tap * (CINW / 8)) * 8;
        short8v v = {0, 0, 0, 0, 0, 0, 0, 0};
        if (real && c < CINP) {
            const int yy = y + tap / 3 - 1, xx = x + tap % 3 - 1;
            if ((unsigned)yy < 512u && (unsigned)xx < 512u)
                v = *(const short8v*)(img + ((long)yy * 512 + xx) * CINP + c);
        }
        *(short8v*)(EP + (long)e * KW + idx * 8) = v;
    }
}

__device__ inline void edge_yx(int e, int& y, int& x) {
    if (e < 512)       { y = 0;   x = e; }
    else if (e < 1024) { y = 511; x = e - 512; }
    else if (e < 1534) { x = 0;   y = 1 + (e - 1024); }
    else               { x = 511; y = 1 + (e - 1534); }
}

template <int COUT, int OUTP, bool RELU, bool FUSE_LN>
__global__ __launch_bounds__(256) void conv_edge_gemm(
    const short* __restrict__ EP,
    const short* __restrict__ wflat,
    const float* __restrict__ bias,
    short* __restrict__ out, int K,
    const short* __restrict__ res,
    const float* __restrict__ lng,
    const float* __restrict__ lnbv)
{
    __shared__ short SMEM[128 * 120];  // >= 8192 staging; = lnbuf size
    short* Xs = SMEM;
    short* Ys = SMEM + 128 * 32;

    const int tid = threadIdx.x, wv = tid >> 6, ln = tid & 63;
    const int wr = wv >> 1, wc = wv & 1;
    const int m0 = blockIdx.x * 128, n0 = blockIdx.y * 128;

    f32x4 acc[4][4] = {};

    const int srow = ln >> 2;
    const int sk8 = ln & 3;
    const int fr = ln & 15, fk = (ln >> 4) * 8;

    for (int k0 = 0; k0 < K; k0 += 32) {
#pragma unroll
        for (int i = wv; i < 8; i += 4) {
            gload_lds16(EP + (long)(m0 + i * 16 + srow) * K + k0 + sk8 * 8,
                        Xs + i * 512);
            gload_lds16(wflat + (long)(n0 + i * 16 + srow) * K + k0 + sk8 * 8,
                        Ys + i * 512);
        }
        __syncthreads();
        short8v a[4], b[4];
#pragma unroll
        for (int mi = 0; mi < 4; ++mi)
            a[mi] = *(const short8v*)(Xs + (wr * 64 + mi * 16 + fr) * 32 + fk);
#pragma unroll
        for (int ni = 0; ni < 4; ++ni)
            b[ni] = *(const short8v*)(Ys + (wc * 64 + ni * 16 + fr) * 32 + fk);
#pragma unroll
        for (int mi = 0; mi < 4; ++mi)
#pragma unroll
            for (int ni = 0; ni < 4; ++ni)
                acc[mi][ni] = __builtin_amdgcn_mfma_f32_16x16x32_bf16(
                    a[mi], b[ni], acc[mi][ni], 0, 0, 0);
        __syncthreads();
    }

    const int fv = (ln >> 4) * 4;
    if constexpr (!FUSE_LN) {
#pragma unroll
        for (int mi = 0; mi < 4; ++mi)
#pragma unroll
            for (int ni = 0; ni < 4; ++ni)
#pragma unroll
                for (int v = 0; v < 4; ++v) {
                    const int e = m0 + wr * 64 + mi * 16 + fv + v;
                    const int co = n0 + wc * 64 + ni * 16 + fr;
                    if (e >= 2044 || co >= COUT) continue;
                    int y, x;
                    edge_yx(e, y, x);
                    float v2 = acc[mi][ni][v] + bias[co];
                    if (RELU) v2 = fmaxf(v2, 0.f);
                    out[((long)y * 512 + x) * OUTP + co] = f2bf(v2);
                }
    } else {
        __shared__ float rmean[128], rinv[128], gs[100], bs[100];
        short* lnbuf = SMEM;
        __syncthreads();
        if (tid < 100) { gs[tid] = lng[tid]; bs[tid] = lnbv[tid]; }
        // Phase A: t = bf16(conv+bias) + res
#pragma unroll
        for (int mi = 0; mi < 4; ++mi)
#pragma unroll
            for (int ni = 0; ni < 4; ++ni)
#pragma unroll
                for (int v = 0; v < 4; ++v) {
                    const int pl = wr * 64 + mi * 16 + fv + v;
                    const int co = wc * 64 + ni * 16 + fr;
                    if (co < 112) {
                        const int e = m0 + pl;
                        float t = 0.f;
                        if (co < COUT && e < 2044) {
                            int y, x;
                            edge_yx(e, y, x);
                            t = bf2f(f2bf(acc[mi][ni][v] + bias[co]))
                              + bf2f(res[((long)y * 512 + x) * 112 + co]);
                        }
                        lnbuf[pl * 120 + co] = f2bf(t);
                    }
                }
        __syncthreads();
        // Phase B: per-row stats
        if (tid < 128) {
            const short* lr = lnbuf + tid * 120;
            float s = 0.f, ss = 0.f;
#pragma unroll
            for (int q = 0; q < 13; ++q) {
                const short8v v8 = *(const short8v*)(lr + q * 8);
#pragma unroll
                for (int j = 0; j < 8; ++j) {
                    const int idx = q * 8 + j;
                    if (idx < 100) {
                        const float t = bf2f(v8[j]);
                        s += t; ss += t * t;
                    }
                }
            }
            const float mean = s * 0.01f;
            const float var = ss * 0.01f - mean * mean;
            rmean[tid] = mean;
            rinv[tid] = rsqrtf(var + 1e-5f);
        }
        __syncthreads();
        // Phase C: vectorized stores (rows scattered; 16B chunks per store)
        for (int c = tid; c < 128 * 14; c += 256) {
            const int row = c / 14, q = c - row * 14;
            const int e = m0 + row;
            if (e >= 2044) continue;
            int y, x;
            edge_yx(e, y, x);
            const float mean = rmean[row], inv = rinv[row];
            const short8v v8 = *(const short8v*)(lnbuf + row * 120 + q * 8);
            short8v o;
#pragma unroll
            for (int j = 0; j < 8; ++j) {
                const int idx = q * 8 + j;
                o[j] = (idx < 100)
                    ? f2bf((bf2f(v8[j]) - mean) * inv * gs[idx] + bs[idx])
                    : (short)0;
            }
            *(short8v*)(out + ((long)y * 512 + x) * 112 + q * 8) = o;
        }
    }
}

// ---------------------------------------------------------------------------
// Transposes / conversions
// ---------------------------------------------------------------------------
__global__ __launch_bounds__(256) void r_transpose(
    const float* __restrict__ R, short* __restrict__ Rt)
{
    __shared__ float Ts[64][65];
    const int tid = threadIdx.x;
    const long base = (long)blockIdx.z * 589824;
    const int d0 = blockIdx.y * 64, e0 = blockIdx.x * 64;
    const int c = tid & 63, rbase = tid >> 6;
#pragma unroll
    for (int j = 0; j < 16; ++j) {
        const int r = rbase + j * 4;
        Ts[r][c] = R[base + (long)(d0 + r) * 768 + e0 + c];
    }
    __syncthreads();
#pragma unroll
    for (int j = 0; j < 16; ++j) {
        const int e = rbase + j * 4;
        Rt[base + (long)(e0 + e) * 768 + d0 + c] = f2bf(Ts[c][e]);
    }
}

// mh_w{f,b}[l] [8][768][96] f32 -> WFBT [16][128][768] bf16 (o-major, padded).
__global__ __launch_bounds__(256) void wfb_transpose(
    const float* __restrict__ wf, const float* __restrict__ wb,
    short* __restrict__ dst)
{
    __shared__ float Ts[64][65];
    const int tid = threadIdx.x;
    const int z = blockIdx.z;
    const float* src = (z < 8) ? wf + (long)z * 73728 : wb + (long)(z - 8) * 73728;
    const int d0 = blockIdx.x * 64, o0 = blockIdx.y * 64;
    const int c = tid & 63, rbase = tid >> 6;
#pragma unroll
    for (int j = 0; j < 16; ++j) {
        const int r = rbase + j * 4;
        Ts[r][c] = (o0 + c < 96) ? src[(long)(d0 + r) * 96 + o0 + c] : 0.f;
    }
    __syncthreads();
#pragma unroll
    for (int j = 0; j < 16; ++j) {
        const int e = rbase + j * 4;
        dst[(long)z * 98304 + (long)(o0 + e) * 768 + d0 + c] = f2bf(Ts[c][e]);
    }
}

// Laplace-normalize bf16 Ahat (deterministic 2-partial rowsums) -> A and A^T.
__global__ __launch_bounds__(256) void a_laplace_t(
    const short* __restrict__ Ahat, const float* __restrict__ psum,
    short* __restrict__ ABF, short* __restrict__ ABFT)
{
    __shared__ float Ts[64][65];
    const int tid = threadIdx.x;
    const int r8 = blockIdx.z;
    const long ra = (long)r8 * 262144;
    const int i0 = blockIdx.y * 64, j0 = blockIdx.x * 64;
    const int c = tid & 63, rbase = tid >> 6;
    const float sj = psum[r8 * 1024 + (j0 + c) * 2] + psum[r8 * 1024 + (j0 + c) * 2 + 1];
    const float dj = rsqrtf(sj);
#pragma unroll
    for (int j = 0; j < 16; ++j) {
        const int r = rbase + j * 4;
        const float si = psum[r8 * 1024 + (i0 + r) * 2] + psum[r8 * 1024 + (i0 + r) * 2 + 1];
        const float di = rsqrtf(si);
        const float v = bf2f(Ahat[ra + (long)(i0 + r) * 512 + j0 + c]) * di * dj;
        Ts[r][c] = v;
        ABF[ra + (long)(i0 + r) * 512 + j0 + c] = f2bf(v);
    }
    __syncthreads();
#pragma unroll
    for (int j = 0; j < 16; ++j) {
        const int e = rbase + j * 4;
        ABFT[ra + (long)(j0 + e) * 512 + i0 + c] = f2bf(Ts[c][e]);
    }
}

// e[m][r*96+o] = bf16(relu(O1[r][m][o] + O2[r][m][o] + mh_b[r*96+o]))
__global__ __launch_bounds__(256) void gcn_combine(
    const short* __restrict__ O1, const short* __restrict__ O2,
    const float* __restrict__ mhb, short* __restrict__ e)
{
    const int idx = blockIdx.x * 256 + threadIdx.x;  // 393216
    const int m = idx / 768, c = idx - m * 768;
    const int r = c / 96, o = c - r * 96;
    const long oi = (long)r * 65536 + (long)m * 128 + o;
    float v = bf2f(O1[oi]) + bf2f(O2[oi]) + mhb[c];
    e[idx] = f2bf(fmaxf(v, 0.f));
}

// ---------------------------------------------------------------------------
// Channel-major -> pixel-major transpose of the rel tensor, full-channel
// blocks (64 px x 112 ch in LDS). DO_LN=true additionally applies the
// channel-LN against `res` (layer-1 rel_ln). Linear coalesced writes.
// ---------------------------------------------------------------------------
template <bool DO_LN>
__global__ __launch_bounds__(256) void rel_transpose_ln(
    const short* __restrict__ relc,   // [100][512][512]
    short* __restrict__ relp,         // [262144][112]
    const short* __restrict__ res,    // [262144][112] (DO_LN only)
    const float* __restrict__ g, const float* __restrict__ b)
{
    __shared__ short Ts[64][112];
    __shared__ float rmean[64], rinv[64], gs[100], bs[100];
    const int tid = threadIdx.x;
    const long p0 = (long)blockIdx.x * 64;

    if (DO_LN && tid < 100) { gs[tid] = g[tid]; bs[tid] = b[tid]; }

    const int ch = tid >> 3, pxo = (tid & 7) * 8;
#pragma unroll
    for (int r0 = 0; r0 < 128; r0 += 32) {
        const int c = r0 + ch;
        short8v v = {0, 0, 0, 0, 0, 0, 0, 0};
        if (c < 100)
            v = *(const short8v*)(relc + (long)c * NNpix + p0 + pxo);
        if (c < 112)
#pragma unroll
            for (int j = 0; j < 8; ++j) Ts[pxo + j][c] = v[j];
    }
    __syncthreads();

    if constexpr (DO_LN) {
        for (int cix = tid; cix < 64 * 14; cix += 256) {
            const int row = cix / 14, q = cix - row * 14;
            short8v tv = *(const short8v*)(&Ts[row][q * 8]);
            const short8v rv = *(const short8v*)(res + (p0 + row) * 112 + q * 8);
#pragma unroll
            for (int j = 0; j < 8; ++j) {
                const int idx = q * 8 + j;
                const float t = (idx < 100) ? bf2f(tv[j]) + bf2f(rv[j]) : 0.f;
                tv[j] = f2bf(t);
            }
            *(short8v*)(&Ts[row][q * 8]) = tv;
        }
        __syncthreads();
        if (tid < 64) {
            float s = 0.f, ss = 0.f;
#pragma unroll
            for (int q = 0; q < 13; ++q) {
                const short8v v8 = *(const short8v*)(&Ts[tid][q * 8]);
#pragma unroll
                for (int j = 0; j < 8; ++j) {
                    const int idx = q * 8 + j;
                    if (idx < 100) {
                        const float t = bf2f(v8[j]);
                        s += t; ss += t * t;
                    }
                }
            }
            const float mean = s * 0.01f;
            rmean[tid] = mean;
            rinv[tid] = rsqrtf(ss * 0.01f - mean * mean + 1e-5f);
        }
        __syncthreads();
    }

    for (int cix = tid; cix < 64 * 14; cix += 256) {
        const int row = cix / 14, q = cix - row * 14;
        short8v v8 = *(const short8v*)(&Ts[row][q * 8]);
        if constexpr (DO_LN) {
            const float mean = rmean[row], inv = rinv[row];
            short8v o;
#pragma unroll
            for (int j = 0; j < 8; ++j) {
                const int idx = q * 8 + j;
                o[j] = (idx < 100)
                    ? f2bf((bf2f(v8[j]) - mean) * inv * gs[idx] + bs[idx])
                    : (short)0;
            }
            v8 = o;
        }
        *(short8v*)(relp + (p0 + row) * 112 + q * 8) = v8;
    }
}

__global__ __launch_bounds__(256) void conv_w_flat(
    const float* __restrict__ src, short* __restrict__ dst,
    int COUT, int CIN, int COUTP, int CINW)
{
    const int idx = blockIdx.x * 256 + threadIdx.x;
    const int KW = 9 * CINW;
    const int total = COUTP * KW;
    if (idx >= total) return;
    const int co = idx / KW;
    const int rem = idx - co * KW;
    const int tap = rem / CINW, ci = rem - tap * CINW;
    short v = 0;
    if (co < COUT && ci < CIN)
        v = f2bf(src[((long)co * CIN + ci) * 9 + tap]);
    dst[idx] = v;
}

__global__ __launch_bounds__(256) void f32_to_bf16k(
    const float* __restrict__ src, short* __restrict__ dst, long n)
{
    const long i = (long)blockIdx.x * 256 + threadIdx.x;
    if (i < n) dst[i] = f2bf(src[i]);
}

// ---------------------------------------------------------------------------
// softmax over 8 relation logits + bf16 A_hat + deterministic rowsum partials.
// EMIT_LOGITS=true (layer 1): also streams the pre-softmax logits (the final
// rels output) to `logits_out` via an LDS stage + fully linear float4 writes.
// ---------------------------------------------------------------------------
template <bool EMIT_LOGITS>
__global__ __launch_bounds__(256) void rel_softmax_laplace(
    const short* __restrict__ relp,
    const float* __restrict__ w,
    const float* __restrict__ bvec,
    short* __restrict__ Ahat,
    float* __restrict__ psum,
    float* __restrict__ logits_out)
{
    __shared__ float ws[800];
    __shared__ float wred[8][4];
    __shared__ float lout[2048];          // 256 px x 8 logits (EMIT only)
    const int tid = threadIdx.x;
    for (int i = tid; i < 800; i += 256) ws[i] = w[i];
    __syncthreads();

    const int i = blockIdx.y;
    const int j = blockIdx.x * 256 + tid;
    const long p = (long)i * 512 + j;
    const short* row = relp + p * 112;

    float acc[8];
#pragma unroll
    for (int r8 = 0; r8 < 8; ++r8) acc[r8] = bvec[r8];
#pragma unroll
    for (int q = 0; q < 13; ++q) {
        const short8v v = *(const short8v*)(row + q * 8);
#pragma unroll
        for (int jj = 0; jj < 8; ++jj) {
            const int r = q * 8 + jj;
            if (r < 100) {
                const float x = bf2f(v[jj]);
#pragma unroll
                for (int r8 = 0; r8 < 8; ++r8)
                    acc[r8] = fmaf(x, ws[r8 * 100 + r], acc[r8]);
            }
        }
    }
    if constexpr (EMIT_LOGITS) {
#pragma unroll
        for (int r8 = 0; r8 < 8; ++r8) lout[tid * 8 + r8] = acc[r8];
    }
    float m = acc[0];
#pragma unroll
    for (int r8 = 1; r8 < 8; ++r8) m = fmaxf(m, acc[r8]);
    float s = 0.f;
#pragma unroll
    for (int r8 = 0; r8 < 8; ++r8) { acc[r8] = expf(acc[r8] - m); s += acc[r8]; }
    const float inv = 1.f / s;
#pragma unroll
    for (int r8 = 0; r8 < 8; ++r8) {
        const float a = acc[r8] * inv + (i == j ? 1.f : 0.f);
        acc[r8] = a;
        Ahat[(long)r8 * NNpix + p] = f2bf(a);
    }
    const int lane = tid & 63, wvv = tid >> 6;
#pragma unroll
    for (int r8 = 0; r8 < 8; ++r8) {
        float v = acc[r8];
        for (int off = 32; off > 0; off >>= 1) v += __shfl_down(v, off);
        if (lane == 0) wred[r8][wvv] = v;
    }
    __syncthreads();
    if (tid < 8) {
        const float v = wred[tid][0] + wred[tid][1] + wred[tid][2] + wred[tid][3];
        psum[tid * 1024 + i * 2 + blockIdx.x] = v;
    }
    if constexpr (EMIT_LOGITS) {
        const long pbase = (long)i * 512 + blockIdx.x * 256;
        float4* dst = (float4*)(logits_out + pbase * 8);
        const float4* src4 = (const float4*)lout;
#pragma unroll
        for (int c = tid; c < 512; c += 256)
            dst[c] = src4[c];
    }
}

// Row LN over D=768 with fused bf16 emit of the normalized ents.
__global__ __launch_bounds__(256) void ln_row768(
    const float* __restrict__ x, const float* __restrict__ res,
    const float* __restrict__ g, const float* __restrict__ b,
    float* __restrict__ outf, short* __restrict__ outbf)
{
    const int n = blockIdx.x;
    const int tid = threadIdx.x;
    float v[3];
    float s = 0.f, ss = 0.f;
#pragma unroll
    for (int i = 0; i < 3; ++i) {
        const int c = tid + 256 * i;
        v[i] = x[(long)n * 768 + c] + res[(long)n * 768 + c];
        s += v[i]; ss += v[i] * v[i];
    }
    const int lane = tid & 63, wv = tid >> 6;
    for (int off = 32; off > 0; off >>= 1) {
        s += __shfl_down(s, off);
        ss += __shfl_down(ss, off);
    }
    __shared__ float rs[4], rss[4];
    if (lane == 0) { rs[wv] = s; rss[wv] = ss; }
    __syncthreads();
    s = rs[0] + rs[1] + rs[2] + rs[3];
    ss = rss[0] + rss[1] + rss[2] + rss[3];
    const float mean = s * (1.f / 768.f);
    const float var = ss * (1.f / 768.f) - mean * mean;
    const float inv = rsqrtf(var + 1e-5f);
#pragma unroll
    for (int i = 0; i < 3; ++i) {
        const int c = tid + 256 * i;
        const float o = (v[i] - mean) * inv * g[c] + b[c];
        outf[(long)n * 768 + c] = o;
        outbf[(long)n * 768 + c] = f2bf(o);
    }
}

__global__ __launch_bounds__(256) void zero_f32(float* __restrict__ p, long n)
{
    const long i = (long)blockIdx.x * 256 + threadIdx.x;
    if (i < n) p[i] = 0.f;
}

// ---------------------------------------------------------------------------
extern "C" void kernel_launch(void* const* d_in, const int* in_sizes, int n_in,
                              void* d_out, int out_size, void* d_ws, size_t ws_size,
                              hipStream_t stream)
{
    (void)in_sizes; (void)n_in; (void)out_size; (void)ws_size;

    const float* ents_in   = (const float*)d_in[0];
    const float* R_local   = (const float*)d_in[1];
    const float* rel_mlp_w = (const float*)d_in[2];
    const float* rel_mlp_b = (const float*)d_in[3];
    const float* conv1_w   = (const float*)d_in[4];
    const float* conv1_b   = (const float*)d_in[5];
    const float* conv2_w   = (const float*)d_in[6];
    const float* conv2_b   = (const float*)d_in[7];
    const float* pffn_g    = (const float*)d_in[8];
    const float* pffn_b    = (const float*)d_in[9];
    const float* rln_g     = (const float*)d_in[10];
    const float* rln_b     = (const float*)d_in[11];
    const float* mh_wf     = (const float*)d_in[12];
    const float* mh_wb     = (const float*)d_in[13];
    const float* mh_b      = (const float*)d_in[14];
    const float* emlp_w    = (const float*)d_in[15];
    const float* emlp_b    = (const float*)d_in[16];
    const float* eln_g     = (const float*)d_in[17];
    const float* eln_b     = (const float*)d_in[18];
    float* out = (float*)d_out;

    // ---- workspace layout (1 KiB aligned) ----
    char* base = (char*)d_ws;
    size_t off = 0;
    auto alloc = [&](size_t bytes) {
        char* p = base + off;
        off += (bytes + 1023) & ~(size_t)1023;
        return p;
    };
    char* U1 = alloc(117964800 + 4096);              // RTL / H1T union
    short* RTL = (short*)U1;                         // [100][768][768] bf16
    short* H1T = (short*)U1;                         // [262144][208] bf16
    char* U2 = alloc(78643200 + 4096);               // TB union
    short* TB  = (short*)U2;                         // [100][512][768] bf16
    short* RELC   = (short*)alloc(52428800 + 4096);  // [100][512][512] bf16
    short* RELP_A = (short*)alloc(58720256 + 4096);  // [262144][112] bf16
    short* RELP_B = (short*)alloc(58720256 + 4096);
    short* RELP_C = (short*)alloc(58720256 + 4096);  // fused-LN output (l0)
    short* W1P = (short*)alloc(294912 * 2);          // [256][9*128] bf16
    short* W2P = (short*)alloc(258048 * 2);          // [128][9*224] bf16
    short* EPB = (short*)alloc(2048L * 2016 * 2 + 4096); // edge patch matrix
    // ---- TAIL region: zeroed at the start of EVERY call ----
    const size_t tail0 = off;
    short* EBF  = (short*)alloc(393216L * 2);        // ents bf16 [512][768]
    short* ABUF = (short*)alloc(2097152L * 2);       // Ahat bf16 [8][512][512]
    float* PSUM = (float*)alloc(8192L * 4);          // [8][512][2] partials
    short* ABF  = (short*)alloc(2097152L * 2);       // A bf16
    short* ABFT = (short*)alloc(2097152L * 2);       // A^T bf16 (contig)
    short* WFBT = (short*)alloc(1572864L * 2);       // [16][128][768] bf16
    short* HFBT = (short*)alloc(1048576L * 2);       // [16][128][512] bf16
    short* O1B  = (short*)alloc(524288L * 2);        // [8][512][128] bf16
    short* O2B  = (short*)alloc(524288L * 2);        // (contig after O1B)
    short* EB2  = (short*)alloc(393216L * 2);        // e bf16 [512][768]
    short* EWB  = (short*)alloc(589824L * 2);        // emlp_w bf16 [768][768]
    float* E2   = (float*)alloc(393216L * 4);
    float* ENTS1 = (float*)alloc(393216L * 4);       // layer-0 output ents
    const long tailN = (long)((off - tail0) / 4);
    (void)O2B;

    zero_f32<<<(int)((tailN + 255) / 256), 256, 0, stream>>>(
        (float*)(base + tail0), tailN);

    for (int l = 0; l < 2; ++l) {
        // RELP_res: pre-posFFN rel tensor (residual). RELP_out: post-LN rel.
        short* RELP_res = (l == 0) ? RELP_A : RELP_B;
        short* RELP_out = (l == 0) ? RELP_C : RELP_A;
        const float* ents_cur = (l == 0) ? ents_in : ENTS1;
        float* ents_next = (l == 0) ? ENTS1 : out;

        if (l == 0)
            f32_to_bf16k<<<1536, 256, 0, stream>>>(ents_in, EBF, 393216);

        r_transpose<<<dim3(12, 12, 100), 256, 0, stream>>>(
            R_local + (long)l * 58982400, RTL);

        // t[r] = ents @ R[r] ; rel[r] = relu(t[r] @ ents^T)
        bgemm_xyt<false><<<dim3(6, 4, 100), 256, 0, stream>>>(
            EBF, 0, RTL, 589824L, TB, 393216L, 512, 768, 768);
        bgemm_xyt<true><<<dim3(4, 4, 100), 256, 0, stream>>>(
            TB, 393216L, EBF, 0, RELC, 262144L, 512, 512, 768);
        // transpose to pixel-major; l1 fuses the rel_ln against RELP_C
        if (l == 0)
            rel_transpose_ln<false><<<4096, 256, 0, stream>>>(
                RELC, RELP_res, nullptr, nullptr, nullptr);
        else
            rel_transpose_ln<true><<<4096, 256, 0, stream>>>(
                RELC, RELP_res, RELP_C, rln_g + 100, rln_b + 100);

        // posFFN convs: ky-slab MFMA main pass (XCD-swizzled) + edge fix;
        // conv1 uses 64-co tiles (occupancy); conv2 (fused LN) keeps 128.
        conv_w_flat<<<1152, 256, 0, stream>>>(
            conv1_w + (long)l * 180000, W1P, 200, 100, 256, 128);
        conv_w_flat<<<1008, 256, 0, stream>>>(
            conv2_w + (long)l * 180000, W2P, 100, 200, 128, 224);

        conv_gemm<112, 128, 2, 200, 208, true, false>
            <<<dim3(2048, 4), 256, 0, stream>>>(
            RELP_res, W1P, conv1_b + l * 200, H1T, nullptr, nullptr, nullptr);
        edge_gather<112, 128><<<2048, 256, 0, stream>>>(RELP_res, EPB);
        conv_edge_gemm<200, 208, true, false>
            <<<dim3(16, 2), 256, 0, stream>>>(
            EPB, W1P, conv1_b + l * 200, H1T, 1152, nullptr, nullptr, nullptr);

        conv_gemm<208, 224, 4, 100, 112, false, true>
            <<<dim3(2048, 1), 256, 0, stream>>>(
            H1T, W2P, conv2_b + l * 100, RELP_out,
            RELP_res, pffn_g + l * 100, pffn_b + l * 100);
        edge_gather<208, 224><<<2048, 256, 0, stream>>>(H1T, EPB);
        conv_edge_gemm<100, 112, false, true>
            <<<dim3(16, 1), 256, 0, stream>>>(
            EPB, W2P, conv2_b + l * 100, RELP_out, 2016,
            RELP_res, pffn_g + l * 100, pffn_b + l * 100);

        // softmax + deterministic rowsum partials; Laplace into bf16 A, A^T.
        // Layer 1 also emits the final rels logits directly into d_out.
        if (l == 0)
            rel_softmax_laplace<false><<<dim3(2, 512), 256, 0, stream>>>(
                RELP_out, rel_mlp_w, rel_mlp_b, ABUF, PSUM, nullptr);
        else
            rel_softmax_laplace<true><<<dim3(2, 512), 256, 0, stream>>>(
                RELP_out, rel_mlp_w, rel_mlp_b, ABUF, PSUM, out + 393216);
        a_laplace_t<<<dim3(8, 8, 8), 256, 0, stream>>>(ABUF, PSUM, ABF, ABFT);

        // GCN via MFMA: HFT/HBT = h^T; merged O-GEMM (z<8: A.hf, z>=8: A^T.hb)
        wfb_transpose<<<dim3(12, 2, 16), 256, 0, stream>>>(
            mh_wf + (long)l * 589824, mh_wb + (long)l * 589824, WFBT);
        bgemm_xyt<false><<<dim3(4, 1, 16), 256, 0, stream>>>(
            WFBT, 98304L, EBF, 0, HFBT, 65536L, 128, 512, 768);
        bgemm_xyt<false><<<dim3(1, 4, 16), 256, 0, stream>>>(
            ABF, 262144L, HFBT, 65536L, O1B, 65536L, 512, 128, 512);
        gcn_combine<<<1536, 256, 0, stream>>>(O1B, O1B + 8L * 65536,
                                              mh_b + l * 768, EB2);

        // ent_mlp (MFMA) + residual LN (out-of-place; fused bf16 emit)
        f32_to_bf16k<<<2304, 256, 0, stream>>>(
            emlp_w + (long)l * 589824, EWB, 589824);
        bgemm_bias_f32<<<dim3(6, 4), 256, 0, stream>>>(
            EB2, EWB, E2, emlp_b + l * 768, 512, 768, 768);
        ln_row768<<<512, 256, 0, stream>>>(E2, ents_cur,
            eln_g + l * 768, eln_b + l * 768, ents_next, EBF);
    }
}